// Round 1
// baseline (26821.124 us; speedup 1.0000x reference)
//
#include <hip/hip_runtime.h>
#include <hip/hip_bf16.h>
#include <hip/hip_cooperative_groups.h>
#include <math.h>

namespace cg = cooperative_groups;

#define BB 64      // batch
#define TT 512     // encoder time
#define NS 128     // decode steps
#define SD 512     // lstm hidden
#define ATT 128
#define NC 64      // num classes
#define KA 1152    // augmented K: 512 ctx/in + 512 rec + 64 onehot + 1 bias + 63 pad

typedef __attribute__((ext_vector_type(8))) short bf8;   // 8 bf16 (4 VGPRs)
typedef __attribute__((ext_vector_type(4))) float f4;

__device__ __forceinline__ float sigm(float x) { return 1.0f / (1.0f + expf(-x)); }
__device__ __forceinline__ float b2f(short s) {
    union { unsigned u; float f; } c; c.u = ((unsigned)(unsigned short)s) << 16; return c.f;
}
#define MFMA16(a, b, c) __builtin_amdgcn_mfma_f32_16x16x32_bf16((a), (b), (c), 0, 0, 0)

// ---------------- fp32 -> bf16 convert (vec4) ----------------
__global__ void f2b_kernel(const float* __restrict__ src, __hip_bfloat16* __restrict__ dst, int n)
{
    int i = (blockIdx.x * blockDim.x + threadIdx.x) * 4;
    if (i < n) {
        float4 v = *(const float4*)(src + i);
        dst[i]     = __hip_bfloat16(v.x);
        dst[i + 1] = __hip_bfloat16(v.y);
        dst[i + 2] = __hip_bfloat16(v.z);
        dst[i + 3] = __hip_bfloat16(v.w);
    }
}

// ---------------- transpose h: [b][t][d] f32 -> hT [b][d][t] bf16 ----------------
__global__ __launch_bounds__(256) void transpose_h_kernel(const float* __restrict__ h,
                                                          __hip_bfloat16* __restrict__ hT)
{
    // grid: 64 b * 8 t-tiles * 8 d-tiles; 64x64 tiles
    int bidx = blockIdx.x;
    int b = bidx >> 6, tt0 = ((bidx >> 3) & 7) * 64, dd0 = (bidx & 7) * 64;
    __shared__ __hip_bfloat16 tile[64][65];
    int dd = threadIdx.x & 63, r4 = threadIdx.x >> 6;
#pragma unroll
    for (int i = 0; i < 64; i += 4) {
        int tl = i + r4;
        tile[tl][dd] = __hip_bfloat16(h[((size_t)b * TT + tt0 + tl) * SD + dd0 + dd]);
    }
    __syncthreads();
#pragma unroll
    for (int i = 0; i < 64; i += 4) {
        int dl = i + r4;
        hT[((size_t)b * SD + dd0 + dl) * TT + tt0 + dd] = tile[dd][dl];
    }
}

// ---------------- build augmented LSTM0 weights, gate-interleaved ----------------
__global__ void prep_w1_kernel(const float* __restrict__ Wih, const float* __restrict__ Whh,
                               const float* __restrict__ bih, const float* __restrict__ bhh,
                               __hip_bfloat16* __restrict__ W)
{
    int idx = blockIdx.x * blockDim.x + threadIdx.x;   // 2048*1152
    if (idx >= 2048 * KA) return;
    int np = idx / KA, kk = idx - np * KA;
    int q = np & 3, d = np >> 2, j = q * 512 + d;
    float v = 0.f;
    if (kk < 512)        v = Wih[j * 576 + 64 + kk];        // ctx part of Wih0
    else if (kk < 1024)  v = Whh[j * 512 + kk - 512];       // Whh0
    else if (kk < 1088)  v = Wih[j * 576 + kk - 1024];      // onehot part
    else if (kk == 1088) v = bih[j] + bhh[j];               // bias via ones column
    W[idx] = __hip_bfloat16(v);
}

// ---------------- build augmented LSTM1 weights ----------------
__global__ void prep_w2_kernel(const float* __restrict__ Wih, const float* __restrict__ Whh,
                               const float* __restrict__ bih, const float* __restrict__ bhh,
                               __hip_bfloat16* __restrict__ W)
{
    int idx = blockIdx.x * blockDim.x + threadIdx.x;
    if (idx >= 2048 * KA) return;
    int np = idx / KA, kk = idx - np * KA;
    int q = np & 3, d = np >> 2, j = q * 512 + d;
    float v = 0.f;
    if (kk < 512)        v = Wih[j * 512 + kk];
    else if (kk < 1024)  v = Whh[j * 512 + kk - 512];
    else if (kk == 1088) v = bih[j] + bhh[j];
    W[idx] = __hip_bfloat16(v);
}

// ---------------- init: X buffers, c states ----------------
__global__ void init_kernel(const float* __restrict__ h, const int* __restrict__ x,
                            __hip_bfloat16* __restrict__ X1a, __hip_bfloat16* __restrict__ X1b,
                            __hip_bfloat16* __restrict__ X2a, __hip_bfloat16* __restrict__ X2b,
                            float* __restrict__ c1, float* __restrict__ c2)
{
    int idx = blockIdx.x * blockDim.x + threadIdx.x;   // 64*1152
    if (idx >= 64 * KA) return;
    int b = idx / KA, col = idx - b * KA;
    __hip_bfloat16 zero(0.0f), one(1.0f);
    __hip_bfloat16 v1a = zero, vo = zero;
    if (col < 512)        v1a = __hip_bfloat16(h[(size_t)b * TT * SD + col]);  // ctx0 = h[:,0,:]
    else if (col >= 1024 && col < 1088) v1a = (x[b * NS] == col - 1024) ? one : zero;
    if (col == 1088) { v1a = one; vo = one; }
    X1a[idx] = v1a; X1b[idx] = vo; X2a[idx] = vo; X2b[idx] = vo;
    if (idx < 512 * 64) { c1[idx] = 0.f; c2[idx] = 0.f; }
}

// ---------------- shared attention body (persistent + fallback) ----------------
__device__ __forceinline__ void attn_body(
    const __hip_bfloat16* X2n, const __hip_bfloat16* __restrict__ Wphib,
    const float* __restrict__ bphi, const __hip_bfloat16* __restrict__ psib,
    const __hip_bfloat16* __restrict__ hT,
    __hip_bfloat16* X1n, __hip_bfloat16* scb, const int* __restrict__ xtok, int t,
    float* h2s, float* phis, float* es, float* red)
{
    int b = blockIdx.x >> 2, dch = blockIdx.x & 3;
    int tid = threadIdx.x;

    h2s[tid]       = b2f(((const short*)X2n)[b * KA + 512 + tid]);
    h2s[256 + tid] = b2f(((const short*)X2n)[b * KA + 768 + tid]);
    __syncthreads();

    // phi[a] = h2 . Wphi[a] + bphi[a];  4 lanes/row
    {
        int al = tid & 3;
#pragma unroll
        for (int pass = 0; pass < 2; ++pass) {
            int a = pass * 64 + (tid >> 2);
            const bf8* wr = (const bf8*)(Wphib + (size_t)a * 512) + al;
            float acc = 0.f;
#pragma unroll
            for (int i = 0; i < 16; ++i) {
                bf8 wv = wr[i * 4];
                const float* hp2 = h2s + i * 32 + al * 8;
#pragma unroll
                for (int j = 0; j < 8; ++j) acc += hp2[j] * b2f(wv[j]);
            }
            acc += __shfl_xor(acc, 1);
            acc += __shfl_xor(acc, 2);
            if (al == 0) phis[a] = acc + bphi[a];
        }
    }
    __syncthreads();

    // e[t'] = phi . psi[b][t'];  4 lanes/row
    {
        int al = tid & 3;
#pragma unroll
        for (int pass = 0; pass < 8; ++pass) {
            int tt = pass * 64 + (tid >> 2);
            const bf8* pr = (const bf8*)(psib + ((size_t)b * TT + tt) * 128) + al;
            float acc = 0.f;
#pragma unroll
            for (int i = 0; i < 4; ++i) {
                bf8 pv = pr[i * 4];
                const float* ph = phis + i * 32 + al * 8;
#pragma unroll
                for (int j = 0; j < 8; ++j) acc += ph[j] * b2f(pv[j]);
            }
            acc += __shfl_xor(acc, 1);
            acc += __shfl_xor(acc, 2);
            if (al == 0) es[tt] = acc;
        }
    }
    __syncthreads();

    // softmax (unnormalized; fold 1/sum into ctx)
    red[tid] = fmaxf(es[tid], es[tid + 256]);
    __syncthreads();
    for (int st = 128; st > 0; st >>= 1) {
        if (tid < st) red[tid] = fmaxf(red[tid], red[tid + st]);
        __syncthreads();
    }
    float mx = red[0];
    __syncthreads();
    float e0 = expf(es[tid] - mx), e1 = expf(es[tid + 256] - mx);
    es[tid] = e0; es[tid + 256] = e1;
    red[tid] = e0 + e1;
    __syncthreads();
    for (int st = 128; st > 0; st >>= 1) {
        if (tid < st) red[tid] += red[tid + st];
        __syncthreads();
    }
    float inv = 1.0f / red[0];
    __syncthreads();

    // ctx[d] = inv * sum_t es[t] * hT[b][d][t]  — contiguous 16B loads
    {
        int d = dch * 128 + (tid & 127), th = tid >> 7;
        const bf8* hp = (const bf8*)hT + ((size_t)b * SD + d) * 64 + th * 32;
        const float* ep = es + th * 256;
        float a0 = 0.f, a1 = 0.f, a2 = 0.f, a3 = 0.f;
#pragma unroll
        for (int i = 0; i < 32; i += 4) {
            bf8 v0 = hp[i], v1 = hp[i + 1], v2 = hp[i + 2], v3 = hp[i + 3];
#pragma unroll
            for (int j = 0; j < 8; ++j) {
                a0 += ep[i * 8 + j]      * b2f(v0[j]);
                a1 += ep[i * 8 + 8 + j]  * b2f(v1[j]);
                a2 += ep[i * 8 + 16 + j] * b2f(v2[j]);
                a3 += ep[i * 8 + 24 + j] * b2f(v3[j]);
            }
        }
        float acc = (a0 + a1) + (a2 + a3);
        red[tid] = acc;
        __syncthreads();
        if (th == 0) {
            float v = (acc + red[tid + 128]) * inv;
            __hip_bfloat16 vb(v);
            X1n[(size_t)b * KA + d] = vb;
            scb[((size_t)b * NS + t) * 1024 + 512 + d] = vb;
        }
    }
    // onehot for step t+1 (redundant identical writes across d-chunks are benign)
    if (tid < 64) {
        float v = (t + 1 < NS && xtok[(size_t)b * NS + t + 1] == tid) ? 1.0f : 0.0f;
        X1n[(size_t)b * KA + 1024 + tid] = __hip_bfloat16(v);
    }
}

// ---------------- persistent cooperative decode kernel ----------------
// 256 blocks x 256 threads. Blocks 0..127 own 4 LSTM0 gate-rows (d = bid*4+quad),
// blocks 128..255 own LSTM1 rows. W tiles cached in LDS for all 128 steps; cell
// state c lives in one register per thread. 3 grid.sync() per step (structural
// minimum: ctx -> h1 -> h2 -> ctx). Recurrent-half GEMM partials are computed in
// the otherwise-idle slot to halve critical-path K per barrier.
__global__ __launch_bounds__(256) void decode_kernel(
    const __hip_bfloat16* __restrict__ W1, const __hip_bfloat16* __restrict__ W2,
    const __hip_bfloat16* __restrict__ Wphib, const float* __restrict__ bphi,
    const __hip_bfloat16* __restrict__ psib, const __hip_bfloat16* __restrict__ hT,
    __hip_bfloat16* X1a, __hip_bfloat16* X1b,
    __hip_bfloat16* X2a, __hip_bfloat16* X2b,
    __hip_bfloat16* scb, const int* __restrict__ xtok)
{
    cg::grid_group grid = cg::this_grid();
    __shared__ __hip_bfloat16 Wlds[36 * 512];            // 36 K-chunks x 64 lanes x 8 bf16
    __shared__ float h2s[512], phis[128], es[512], red[256];

    const int bid = blockIdx.x, tid = threadIdx.x;
    const int lane = tid & 63, w = tid >> 6;
    const int mr = lane & 15, quad = lane >> 4;
    const bool isA = bid < 128;

    // load this block's 16 W rows into LDS, MFMA-fragment-ordered
    {
        const __hip_bfloat16* Wg = isA ? W1 : W2;
        const int m0 = (bid & 127) * 16;
        const bf8* src = (const bf8*)(Wg + (size_t)(m0 + mr) * KA) + quad;
        bf8* dstl = (bf8*)Wlds;
        for (int ko = w; ko < 36; ko += 4)
            dstl[ko * 64 + lane] = src[ko * 4];
    }
    __syncthreads();

    const bf8* Wl = (const bf8*)Wlds + lane;
    const int dl = (bid & 127) * 4 + quad;   // this thread's hidden index d
    const int bb = w * 16 + mr;              // this thread's batch
    const size_t xoff = (size_t)bb * 144 + quad;

    float cr = 0.f;                          // persistent cell state
    f4 accP = {0, 0, 0, 0};                  // carried GEMM partial

    __hip_bfloat16 *X1c = X1a, *X1n = X1b, *X2c = X2a, *X2n = X2b;

    // prologue: gates0(0) partial over h1(-1)=0 + bias column of X1a
    if (isA) {
        const bf8* Bp = (const bf8*)X1c + xoff;
#pragma unroll
        for (int ko = 16; ko < 32; ++ko) accP = MFMA16(Wl[ko * 64], Bp[ko * 4], accP);
        accP = MFMA16(Wl[34 * 64], Bp[34 * 4], accP);
    }

    for (int t = 0; t < NS; ++t) {
        // ---- slot 1 ----
        if (isA) {
            // finish gates0: ctx (ko 0-15) + onehot (ko 32,33); cell -> h1
            const bf8* Bp = (const bf8*)X1c + xoff;
            f4 acc = accP;
#pragma unroll
            for (int ko = 0; ko < 16; ++ko) acc = MFMA16(Wl[ko * 64], Bp[ko * 4], acc);
            acc = MFMA16(Wl[32 * 64], Bp[32 * 4], acc);
            acc = MFMA16(Wl[33 * 64], Bp[33 * 4], acc);
            float cn = sigm(acc.y) * cr + sigm(acc.x) * tanhf(acc.z);
            float hn = sigm(acc.w) * tanhf(cn);
            cr = cn;
            __hip_bfloat16 hb(hn);
            X2c[(size_t)bb * KA + dl] = hb;          // h1 -> LSTM1 input
            X1n[(size_t)bb * KA + 512 + dl] = hb;    // h1 -> next-step recurrent
        } else {
            // gates1 partial: h2(t-1) (ko 16-31) + bias (ko 34)
            const bf8* Bp = (const bf8*)X2c + xoff;
            f4 acc = {0, 0, 0, 0};
#pragma unroll
            for (int ko = 16; ko < 32; ++ko) acc = MFMA16(Wl[ko * 64], Bp[ko * 4], acc);
            acc = MFMA16(Wl[34 * 64], Bp[34 * 4], acc);
            accP = acc;
        }
        grid.sync();

        // ---- slot 2 ----
        if (isA) {
            // gates0(t+1) partial: h1(t) (ko 16-31) + bias (ko 34) over X1n
            const bf8* Bp = (const bf8*)X1n + xoff;
            f4 acc = {0, 0, 0, 0};
#pragma unroll
            for (int ko = 16; ko < 32; ++ko) acc = MFMA16(Wl[ko * 64], Bp[ko * 4], acc);
            acc = MFMA16(Wl[34 * 64], Bp[34 * 4], acc);
            accP = acc;
        } else {
            // finish gates1: h1(t) (ko 0-15); cell -> h2
            const bf8* Bp = (const bf8*)X2c + xoff;
            f4 acc = accP;
#pragma unroll
            for (int ko = 0; ko < 16; ++ko) acc = MFMA16(Wl[ko * 64], Bp[ko * 4], acc);
            float cn = sigm(acc.y) * cr + sigm(acc.x) * tanhf(acc.z);
            float hn = sigm(acc.w) * tanhf(cn);
            cr = cn;
            __hip_bfloat16 hb(hn);
            X2n[(size_t)bb * KA + 512 + dl] = hb;                 // h2 recurrent
            scb[((size_t)bb * NS + t) * 1024 + dl] = hb;          // h2 -> projection input
        }
        grid.sync();

        // ---- slot 3: attention (all 256 blocks) ----
        attn_body(X2n, Wphib, bphi, psib, hT, X1n, scb, xtok, t, h2s, phis, es, red);
        grid.sync();

        __hip_bfloat16* tp;
        tp = X1c; X1c = X1n; X1n = tp;
        tp = X2c; X2c = X2n; X2n = tp;
    }
}

// ---------------- fallback: per-step LSTM kernel (as before) ----------------
__global__ __launch_bounds__(64) void lstm_step_kernel(
    const __hip_bfloat16* __restrict__ X,    // [64][1152]
    const __hip_bfloat16* __restrict__ W,    // [2048][1152]
    float* __restrict__ c,                   // [512][64] in-place
    __hip_bfloat16* __restrict__ dst1, int rs1,
    __hip_bfloat16* __restrict__ dst2, int rs2)
{
    int lane = threadIdx.x;
    int m0 = blockIdx.x * 16;
    int mr = lane & 15, quad = lane >> 4;
    const bf8* Ar = (const bf8*)(W + (size_t)(m0 + mr) * KA + quad * 8);
    const bf8* B0 = (const bf8*)(X + (size_t)(mr)      * KA + quad * 8);
    const bf8* B1 = (const bf8*)(X + (size_t)(16 + mr) * KA + quad * 8);
    const bf8* B2 = (const bf8*)(X + (size_t)(32 + mr) * KA + quad * 8);
    const bf8* B3 = (const bf8*)(X + (size_t)(48 + mr) * KA + quad * 8);
    f4 acc0 = {0,0,0,0}, acc1 = {0,0,0,0}, acc2 = {0,0,0,0}, acc3 = {0,0,0,0};
#pragma unroll 6
    for (int k0 = 0; k0 < KA; k0 += 32) {
        int ko = k0 >> 3;
        bf8 a  = Ar[ko];
        bf8 b0 = B0[ko], b1 = B1[ko], b2 = B2[ko], b3 = B3[ko];
        acc0 = MFMA16(a, b0, acc0);
        acc1 = MFMA16(a, b1, acc1);
        acc2 = MFMA16(a, b2, acc2);
        acc3 = MFMA16(a, b3, acc3);
    }
    int d = (m0 >> 2) + quad;
    f4 accs[4] = {acc0, acc1, acc2, acc3};
#pragma unroll
    for (int nf = 0; nf < 4; ++nf) {
        int b = nf * 16 + mr;
        f4 g = accs[nf];
        int ci = d * 64 + b;
        float cn = sigm(g.y) * c[ci] + sigm(g.x) * tanhf(g.z);
        float hn = sigm(g.w) * tanhf(cn);
        c[ci] = cn;
        __hip_bfloat16 hb(hn);
        dst1[(size_t)b * rs1 + d] = hb;
        dst2[(size_t)b * rs2 + d] = hb;
    }
}

// ---------------- fallback: per-step attention kernel ----------------
__global__ __launch_bounds__(256) void attn_step_kernel(
    const __hip_bfloat16* X2n, const __hip_bfloat16* __restrict__ Wphib,
    const float* __restrict__ bphi, const __hip_bfloat16* __restrict__ psib,
    const __hip_bfloat16* __restrict__ hT,
    __hip_bfloat16* X1n, __hip_bfloat16* scb, const int* __restrict__ xtok, int t)
{
    __shared__ float h2s[512], phis[128], es[512], red[256];
    attn_body(X2n, Wphib, bphi, psib, hT, X1n, scb, xtok, t, h2s, phis, es, red);
}

// ---------------- psi GEMM: psibf[b*512+t][128] = hbf @ Wpsi^T + bpsi ----------------
__global__ __launch_bounds__(256) void psi_gemm_kernel(
    const __hip_bfloat16* __restrict__ A,   // hbf [32768][512]
    const __hip_bfloat16* __restrict__ Bw,  // Wpsibf [128][512]
    const float* __restrict__ bias,
    __hip_bfloat16* __restrict__ C)         // [32768][128]
{
    int lane = threadIdx.x & 63, wave = threadIdx.x >> 6;
    int m0 = (blockIdx.x * 4 + wave) * 16;
    int mr = lane & 15, quad = lane >> 4;
    const bf8* Ar = (const bf8*)(A + (size_t)(m0 + mr) * 512 + quad * 8);
    f4 acc[8] = {};
    for (int k0 = 0; k0 < 512; k0 += 32) {
        int ko = k0 >> 3;
        bf8 a = Ar[ko];
#pragma unroll
        for (int nf = 0; nf < 8; ++nf) {
            const bf8* Br = (const bf8*)(Bw + (size_t)(nf * 16 + mr) * 512 + quad * 8);
            acc[nf] = MFMA16(a, Br[ko], acc[nf]);
        }
    }
#pragma unroll
    for (int nf = 0; nf < 8; ++nf) {
        int n = nf * 16 + mr;
        float bs = bias[n];
#pragma unroll
        for (int r = 0; r < 4; ++r) {
            int m = m0 + quad * 4 + r;
            C[(size_t)m * 128 + n] = __hip_bfloat16(acc[nf][r] + bs);
        }
    }
}

// ---------------- final projection: out[b*128+t][64] = scbf @ Wcd^T + bcd ----------------
__global__ __launch_bounds__(256) void out_gemm_kernel(
    const __hip_bfloat16* __restrict__ A,   // scbf [8192][1024]
    const __hip_bfloat16* __restrict__ Bw,  // Wcdbf [64][1024]
    const float* __restrict__ bias,
    float* __restrict__ C)                  // [8192][64]
{
    int lane = threadIdx.x & 63, wave = threadIdx.x >> 6;
    int m0 = (blockIdx.x * 4 + wave) * 16;
    int mr = lane & 15, quad = lane >> 4;
    const bf8* Ar = (const bf8*)(A + (size_t)(m0 + mr) * 1024 + quad * 8);
    f4 acc[4] = {};
    for (int k0 = 0; k0 < 1024; k0 += 32) {
        int ko = k0 >> 3;
        bf8 a = Ar[ko];
#pragma unroll
        for (int nf = 0; nf < 4; ++nf) {
            const bf8* Br = (const bf8*)(Bw + (size_t)(nf * 16 + mr) * 1024 + quad * 8);
            acc[nf] = MFMA16(a, Br[ko], acc[nf]);
        }
    }
#pragma unroll
    for (int nf = 0; nf < 4; ++nf) {
        int n = nf * 16 + mr;
        float bs = bias[n];
#pragma unroll
        for (int r = 0; r < 4; ++r) {
            int m = m0 + quad * 4 + r;
            C[(size_t)m * 64 + n] = acc[nf][r] + bs;
        }
    }
}

extern "C" void kernel_launch(void* const* d_in, const int* in_sizes, int n_in,
                              void* d_out, int out_size, void* d_ws, size_t ws_size,
                              hipStream_t stream)
{
    const int*   x    = (const int*)  d_in[0];
    const float* h    = (const float*)d_in[1];
    const float* Wih0 = (const float*)d_in[2];
    const float* Whh0 = (const float*)d_in[3];
    const float* bih0 = (const float*)d_in[4];
    const float* bhh0 = (const float*)d_in[5];
    const float* Wih1 = (const float*)d_in[6];
    const float* Whh1 = (const float*)d_in[7];
    const float* bih1 = (const float*)d_in[8];
    const float* bhh1 = (const float*)d_in[9];
    const float* Wphi = (const float*)d_in[10];
    const float* bphi = (const float*)d_in[11];
    const float* Wpsi = (const float*)d_in[12];
    const float* bpsi = (const float*)d_in[13];
    const float* Wcd  = (const float*)d_in[14];
    const float* bcd  = (const float*)d_in[15];
    float* out = (float*)d_out;

    char* p = (char*)d_ws;
    __hip_bfloat16* hbf    = (__hip_bfloat16*)p; p += (size_t)BB * TT * SD * 2;   // 32 MB (hbf, then hT)
    __hip_bfloat16* psibf  = (__hip_bfloat16*)p; p += (size_t)BB * TT * ATT * 2;  // 8 MB
    __hip_bfloat16* scbf   = (__hip_bfloat16*)p; p += (size_t)BB * NS * 1024 * 2; // 16 MB
    __hip_bfloat16* W1aug  = (__hip_bfloat16*)p; p += (size_t)2048 * KA * 2;      // 4.5 MB
    __hip_bfloat16* W2aug  = (__hip_bfloat16*)p; p += (size_t)2048 * KA * 2;      // 4.5 MB
    __hip_bfloat16* Wphib  = (__hip_bfloat16*)p; p += (size_t)ATT * SD * 2;
    __hip_bfloat16* Wpsib  = (__hip_bfloat16*)p; p += (size_t)ATT * SD * 2;
    __hip_bfloat16* Wcdb   = (__hip_bfloat16*)p; p += (size_t)NC * 1024 * 2;
    __hip_bfloat16* X1[2]; X1[0] = (__hip_bfloat16*)p; p += (size_t)BB * KA * 2;
    X1[1] = (__hip_bfloat16*)p; p += (size_t)BB * KA * 2;
    __hip_bfloat16* X2[2]; X2[0] = (__hip_bfloat16*)p; p += (size_t)BB * KA * 2;
    X2[1] = (__hip_bfloat16*)p; p += (size_t)BB * KA * 2;
    float* c1 = (float*)p; p += (size_t)SD * BB * 4;
    float* c2 = (float*)p; p += (size_t)SD * BB * 4;

    // ---- one-time prep ----
    f2b_kernel<<<16384, 256, 0, stream>>>(h, hbf, BB * TT * SD);
    f2b_kernel<<<64, 256, 0, stream>>>(Wphi, Wphib, ATT * SD);
    f2b_kernel<<<64, 256, 0, stream>>>(Wpsi, Wpsib, ATT * SD);
    f2b_kernel<<<64, 256, 0, stream>>>(Wcd, Wcdb, NC * 1024);
    prep_w1_kernel<<<(2048 * KA + 255) / 256, 256, 0, stream>>>(Wih0, Whh0, bih0, bhh0, W1aug);
    prep_w2_kernel<<<(2048 * KA + 255) / 256, 256, 0, stream>>>(Wih1, Whh1, bih1, bhh1, W2aug);
    init_kernel<<<(64 * KA + 255) / 256, 256, 0, stream>>>(h, x, X1[0], X1[1], X2[0], X2[1], c1, c2);
    psi_gemm_kernel<<<512, 256, 0, stream>>>(hbf, Wpsib, bpsi, psibf);
    // after psi_gemm no longer needs row-major hbf, overwrite the region with hT [b][d][t]
    transpose_h_kernel<<<4096, 256, 0, stream>>>(h, hbf);
    __hip_bfloat16* hT = hbf;

    // ---- persistent cooperative decode (3 grid syncs/step instead of 3 launches) ----
    const __hip_bfloat16 *a0 = W1aug, *a1 = W2aug, *a2 = Wphib;
    const float* a3 = bphi;
    const __hip_bfloat16 *a4 = psibf, *a5 = hT;
    __hip_bfloat16 *a6 = X1[0], *a7 = X1[1], *a8 = X2[0], *a9 = X2[1], *a10 = scbf;
    const int* a11 = x;
    void* args[12] = {&a0, &a1, &a2, &a3, &a4, &a5, &a6, &a7, &a8, &a9, &a10, &a11};
    hipError_t ce = hipLaunchCooperativeKernel((const void*)decode_kernel,
                                               dim3(256), dim3(256), args, 0, stream);
    if (ce != hipSuccess) {
        // fallback: per-step kernel loop (correct, previous-version speed)
        (void)hipGetLastError();
        for (int t = 0; t < NS; ++t) {
            __hip_bfloat16* X1c = X1[t & 1], *X1n = X1[(t + 1) & 1];
            __hip_bfloat16* X2c = X2[t & 1], *X2n = X2[(t + 1) & 1];
            lstm_step_kernel<<<128, 64, 0, stream>>>(X1c, W1aug, c1,
                                                     X2c, KA, X1n + 512, KA);
            lstm_step_kernel<<<128, 64, 0, stream>>>(X2c, W2aug, c2,
                                                     X2n + 512, KA, scbf + (size_t)t * 1024, NS * 1024);
            attn_step_kernel<<<256, 256, 0, stream>>>(X2n, Wphib, bphi, psibf, hT,
                                                      X1n, scbf, x, t);
        }
    }
    // output projection
    out_gemm_kernel<<<128, 256, 0, stream>>>(scbf, Wcdb, bcd, out);
}

// Round 2
// 5344.333 us; speedup vs baseline: 5.0186x; 5.0186x over previous
//
#include <hip/hip_runtime.h>
#include <hip/hip_bf16.h>
#include <math.h>

#define BB 64      // batch
#define TT 512     // encoder time
#define NS 128     // decode steps
#define SD 512     // lstm hidden
#define ATT 128
#define NC 64      // num classes
#define KX 1024    // X row: 512 ctx/h1 + 512 rec

typedef __attribute__((ext_vector_type(8))) short bf8;   // 8 bf16 (4 VGPRs)
typedef __attribute__((ext_vector_type(4))) float f4;

__device__ __forceinline__ float sigm(float x) { return 1.0f / (1.0f + expf(-x)); }
__device__ __forceinline__ float b2f(short s) {
    union { unsigned u; float f; } c; c.u = ((unsigned)(unsigned short)s) << 16; return c.f;
}
#define MFMA16(a, b, c) __builtin_amdgcn_mfma_f32_16x16x32_bf16((a), (b), (c), 0, 0, 0)

// ---- coherent (L3-point) access helpers: sc0 sc1 = bypass L1/L2, no invalidates ----
__device__ __forceinline__ bf8 ld_sc_wait(const __hip_bfloat16* p) {
    bf8 v;
    asm volatile("global_load_dwordx4 %0, %1, off sc0 sc1\ns_waitcnt vmcnt(0)"
                 : "=v"(v) : "v"(p) : "memory");
    return v;
}
__device__ __forceinline__ void st_sc(__hip_bfloat16* p, float val) {
    __hip_bfloat16 hb(val);
    unsigned short bits; __builtin_memcpy(&bits, &hb, 2);
    unsigned v = bits;
    asm volatile("global_store_short %0, %1, off sc0 sc1" :: "v"(p), "v"(v) : "memory");
}
__device__ __forceinline__ unsigned ld_u32_sc(const unsigned* p) {
    unsigned v;
    asm volatile("global_load_dword %0, %1, off sc0 sc1\ns_waitcnt vmcnt(0)"
                 : "=v"(v) : "v"(p) : "memory");
    return v;
}

// grid barrier WITHOUT L2 invalidation: monotonic counter, device-scope atomic
// arrive (m20: atomicAdd is device-scope coherent), sc1 spin load.
// __syncthreads() drains each thread's vmcnt (incl. sc1 write-through acks) first.
__device__ __forceinline__ void gsync(unsigned* bar, unsigned target)
{
    __syncthreads();
    if (threadIdx.x == 0) {
        atomicAdd(bar, 1u);
        while (ld_u32_sc(bar) < target) __builtin_amdgcn_s_sleep(2);
    }
    __syncthreads();
}

// 16-chunk MFMA GEMM over one X row via sc1 loads (chunks BASE..BASE+15)
template<int BASE>
__device__ __forceinline__ f4 gemm16(const __hip_bfloat16* Xrow, int quad, const bf8* Wl, f4 acc)
{
    const bf8* Bq = (const bf8*)Xrow + quad;
    bf8 r0, r1, r2, r3, r4, r5, r6, r7, r8, r9, r10, r11, r12, r13, r14, r15;
#define LD1(i) asm volatile("global_load_dwordx4 %0, %1, off offset:%2 sc0 sc1" \
                            : "=v"(r##i) : "v"(Bq), "i"((BASE + i) * 64))
    LD1(0); LD1(1); LD1(2); LD1(3); LD1(4); LD1(5); LD1(6); LD1(7);
    LD1(8); LD1(9); LD1(10); LD1(11); LD1(12); LD1(13); LD1(14); LD1(15);
#undef LD1
    asm volatile("s_waitcnt vmcnt(0)"
                 : "+v"(r0), "+v"(r1), "+v"(r2), "+v"(r3),
                   "+v"(r4), "+v"(r5), "+v"(r6), "+v"(r7),
                   "+v"(r8), "+v"(r9), "+v"(r10), "+v"(r11),
                   "+v"(r12), "+v"(r13), "+v"(r14), "+v"(r15));
    __builtin_amdgcn_sched_barrier(0);
#define MM(i) acc = MFMA16(Wl[(BASE + i) * 64], r##i, acc)
    MM(0); MM(1); MM(2); MM(3); MM(4); MM(5); MM(6); MM(7);
    MM(8); MM(9); MM(10); MM(11); MM(12); MM(13); MM(14); MM(15);
#undef MM
    return acc;
}

// ---------------- fp32 -> bf16 convert (vec4) ----------------
__global__ void f2b_kernel(const float* __restrict__ src, __hip_bfloat16* __restrict__ dst, int n)
{
    int i = (blockIdx.x * blockDim.x + threadIdx.x) * 4;
    if (i < n) {
        float4 v = *(const float4*)(src + i);
        dst[i]     = __hip_bfloat16(v.x);
        dst[i + 1] = __hip_bfloat16(v.y);
        dst[i + 2] = __hip_bfloat16(v.z);
        dst[i + 3] = __hip_bfloat16(v.w);
    }
}

// ---------------- transpose h: [b][t][d] f32 -> hT [b][d][t] bf16 ----------------
__global__ __launch_bounds__(256) void transpose_h_kernel(const float* __restrict__ h,
                                                          __hip_bfloat16* __restrict__ hT)
{
    int bidx = blockIdx.x;
    int b = bidx >> 6, tt0 = ((bidx >> 3) & 7) * 64, dd0 = (bidx & 7) * 64;
    __shared__ __hip_bfloat16 tile[64][65];
    int dd = threadIdx.x & 63, r4 = threadIdx.x >> 6;
#pragma unroll
    for (int i = 0; i < 64; i += 4) {
        int tl = i + r4;
        tile[tl][dd] = __hip_bfloat16(h[((size_t)b * TT + tt0 + tl) * SD + dd0 + dd]);
    }
    __syncthreads();
#pragma unroll
    for (int i = 0; i < 64; i += 4) {
        int dl = i + r4;
        hT[((size_t)b * SD + dd0 + dl) * TT + tt0 + dd] = tile[dd][dl];
    }
}

// ---------------- LSTM0 weights [2048][1024]: ctx cols | rec cols ----------------
__global__ void prep_w1_kernel(const float* __restrict__ Wih, const float* __restrict__ Whh,
                               __hip_bfloat16* __restrict__ W)
{
    int idx = blockIdx.x * blockDim.x + threadIdx.x;   // 2048*1024
    if (idx >= 2048 * KX) return;
    int np = idx >> 10, kk = idx & 1023;
    int q = np & 3, d = np >> 2, j = q * 512 + d;
    float v = (kk < 512) ? Wih[j * 576 + 64 + kk] : Whh[j * 512 + kk - 512];
    W[idx] = __hip_bfloat16(v);
}

// ---------------- LSTM1 weights [2048][1024] ----------------
__global__ void prep_w2_kernel(const float* __restrict__ Wih, const float* __restrict__ Whh,
                               __hip_bfloat16* __restrict__ W)
{
    int idx = blockIdx.x * blockDim.x + threadIdx.x;
    if (idx >= 2048 * KX) return;
    int np = idx >> 10, kk = idx & 1023;
    int q = np & 3, d = np >> 2, j = q * 512 + d;
    float v = (kk < 512) ? Wih[j * 512 + kk] : Whh[j * 512 + kk - 512];
    W[idx] = __hip_bfloat16(v);
}

// ---------------- biases (gate-interleaved f4) + per-token Wih0 column gather ----------------
__global__ void prep_misc_kernel(const float* __restrict__ Wih0,
                                 const float* __restrict__ bih0, const float* __restrict__ bhh0,
                                 const float* __restrict__ bih1, const float* __restrict__ bhh1,
                                 float* __restrict__ b1v, float* __restrict__ b2v,
                                 float* __restrict__ woh)   // [64 tok][512 d] f4
{
    int idx = blockIdx.x * blockDim.x + threadIdx.x;   // 64*512
    if (idx >= 64 * 512) return;
    int tok = idx >> 9, d = idx & 511;
    float4 w;
    w.x = Wih0[(0 * 512 + d) * 576 + tok];
    w.y = Wih0[(1 * 512 + d) * 576 + tok];
    w.z = Wih0[(2 * 512 + d) * 576 + tok];
    w.w = Wih0[(3 * 512 + d) * 576 + tok];
    ((float4*)woh)[idx] = w;
    if (tok == 0) {
        float4 b1, b2;
        b1.x = bih0[d] + bhh0[d];             b1.y = bih0[512 + d] + bhh0[512 + d];
        b1.z = bih0[1024 + d] + bhh0[1024 + d]; b1.w = bih0[1536 + d] + bhh0[1536 + d];
        b2.x = bih1[d] + bhh1[d];             b2.y = bih1[512 + d] + bhh1[512 + d];
        b2.z = bih1[1024 + d] + bhh1[1024 + d]; b2.w = bih1[1536 + d] + bhh1[1536 + d];
        ((float4*)b1v)[d] = b1;
        ((float4*)b2v)[d] = b2;
    }
}

// ---------------- init: X buffers [64][1024], c states, barrier ----------------
__global__ void init_kernel(const float* __restrict__ h,
                            __hip_bfloat16* __restrict__ X1a, __hip_bfloat16* __restrict__ X1b,
                            __hip_bfloat16* __restrict__ X2a, __hip_bfloat16* __restrict__ X2b,
                            float* __restrict__ c1, float* __restrict__ c2,
                            unsigned* __restrict__ bar)
{
    int idx = blockIdx.x * blockDim.x + threadIdx.x;   // 64*1024
    if (idx >= 64 * KX) return;
    int b = idx >> 10, col = idx & 1023;
    __hip_bfloat16 z(0.0f);
    X1a[idx] = (col < 512) ? __hip_bfloat16(h[(size_t)b * TT * SD + col]) : z;  // ctx0 = h[:,0,:]
    X1b[idx] = z; X2a[idx] = z; X2b[idx] = z;
    if (idx < 512 * 64) { c1[idx] = 0.f; c2[idx] = 0.f; }
    if (idx < 16) bar[idx] = 0u;
}

// ---------------- shared attention body ----------------
__device__ __forceinline__ void attn_body2(
    const __hip_bfloat16* X2n, const __hip_bfloat16* __restrict__ Wphib,
    const float* __restrict__ bphi, const __hip_bfloat16* __restrict__ psib,
    const __hip_bfloat16* __restrict__ hT,
    __hip_bfloat16* X1n, __hip_bfloat16* scb, int t,
    float* h2s, float* phis, float* es, float* red)
{
    int b = blockIdx.x >> 2, dch = blockIdx.x & 3;
    int tid = threadIdx.x;

    if (tid < 64) {                         // h2 via coherent load (written by slot2, sc1)
        bf8 v = ld_sc_wait(X2n + (size_t)b * KX + 512 + tid * 8);
#pragma unroll
        for (int j = 0; j < 8; ++j) h2s[tid * 8 + j] = b2f(v[j]);
    }
    __syncthreads();

    // phi[a] = h2 . Wphi[a] + bphi[a];  4 lanes/row (normal cached loads, read-only data)
    {
        int al = tid & 3;
#pragma unroll
        for (int pass = 0; pass < 2; ++pass) {
            int a = pass * 64 + (tid >> 2);
            const bf8* wr = (const bf8*)(Wphib + (size_t)a * 512) + al;
            float acc = 0.f;
#pragma unroll
            for (int i = 0; i < 16; ++i) {
                bf8 wv = wr[i * 4];
                const float* hp2 = h2s + i * 32 + al * 8;
#pragma unroll
                for (int j = 0; j < 8; ++j) acc += hp2[j] * b2f(wv[j]);
            }
            acc += __shfl_xor(acc, 1);
            acc += __shfl_xor(acc, 2);
            if (al == 0) phis[a] = acc + bphi[a];
        }
    }
    __syncthreads();

    // e[t'] = phi . psi[b][t']
    {
        int al = tid & 3;
#pragma unroll
        for (int pass = 0; pass < 8; ++pass) {
            int tt = pass * 64 + (tid >> 2);
            const bf8* pr = (const bf8*)(psib + ((size_t)b * TT + tt) * 128) + al;
            float acc = 0.f;
#pragma unroll
            for (int i = 0; i < 4; ++i) {
                bf8 pv = pr[i * 4];
                const float* ph = phis + i * 32 + al * 8;
#pragma unroll
                for (int j = 0; j < 8; ++j) acc += ph[j] * b2f(pv[j]);
            }
            acc += __shfl_xor(acc, 1);
            acc += __shfl_xor(acc, 2);
            if (al == 0) es[tt] = acc;
        }
    }
    __syncthreads();

    // softmax (unnormalized; fold 1/sum into ctx)
    red[tid] = fmaxf(es[tid], es[tid + 256]);
    __syncthreads();
    for (int st = 128; st > 0; st >>= 1) {
        if (tid < st) red[tid] = fmaxf(red[tid], red[tid + st]);
        __syncthreads();
    }
    float mx = red[0];
    __syncthreads();
    float e0 = expf(es[tid] - mx), e1 = expf(es[tid + 256] - mx);
    es[tid] = e0; es[tid + 256] = e1;
    red[tid] = e0 + e1;
    __syncthreads();
    for (int st = 128; st > 0; st >>= 1) {
        if (tid < st) red[tid] += red[tid + st];
        __syncthreads();
    }
    float inv = 1.0f / red[0];
    __syncthreads();

    // ctx[d] = inv * sum_t es[t] * hT[b][d][t]  (normal cached loads)
    {
        int d = dch * 128 + (tid & 127), th = tid >> 7;
        const bf8* hp = (const bf8*)hT + ((size_t)b * SD + d) * 64 + th * 32;
        const float* ep = es + th * 256;
        float a0 = 0.f, a1 = 0.f, a2 = 0.f, a3 = 0.f;
#pragma unroll
        for (int i = 0; i < 32; i += 4) {
            bf8 v0 = hp[i], v1 = hp[i + 1], v2 = hp[i + 2], v3 = hp[i + 3];
#pragma unroll
            for (int j = 0; j < 8; ++j) {
                a0 += ep[i * 8 + j]      * b2f(v0[j]);
                a1 += ep[i * 8 + 8 + j]  * b2f(v1[j]);
                a2 += ep[i * 8 + 16 + j] * b2f(v2[j]);
                a3 += ep[i * 8 + 24 + j] * b2f(v3[j]);
            }
        }
        float acc = (a0 + a1) + (a2 + a3);
        red[tid] = acc;
        __syncthreads();
        if (th == 0) {
            float v = (acc + red[tid + 128]) * inv;
            st_sc(X1n + (size_t)b * KX + d, v);                        // coherent: ctx
            scb[((size_t)b * NS + t) * 1024 + 512 + d] = __hip_bfloat16(v);  // normal
        }
    }
}

// ---------------- persistent decode kernel (custom barrier, no L2 invalidation) ----------------
__global__ __launch_bounds__(256) void decode_kernel(
    const __hip_bfloat16* __restrict__ W1, const __hip_bfloat16* __restrict__ W2,
    const __hip_bfloat16* __restrict__ Wphib, const float* __restrict__ bphi,
    const __hip_bfloat16* __restrict__ psib, const __hip_bfloat16* __restrict__ hT,
    __hip_bfloat16* X1a, __hip_bfloat16* X1b,
    __hip_bfloat16* X2a, __hip_bfloat16* X2b,
    __hip_bfloat16* scb, const int* __restrict__ xtok,
    const float* __restrict__ b1v, const float* __restrict__ b2v,
    const float* __restrict__ woh, unsigned* __restrict__ bar)
{
    __shared__ __hip_bfloat16 Wlds[32 * 512];            // 32 K-chunks x 64 lanes x 8 bf16
    __shared__ float h2s[512], phis[128], es[512], red[256];

    const int bid = blockIdx.x, tid = threadIdx.x;
    const int lane = tid & 63, w = tid >> 6;
    const int mr = lane & 15, quad = lane >> 4;
    const bool isA = bid < 128;

    // stage this block's 16 W rows (chunks 0..31) into LDS, fragment-ordered
    {
        const __hip_bfloat16* Wg = isA ? W1 : W2;
        const int m0 = (bid & 127) * 16;
        const bf8* src = (const bf8*)(Wg + (size_t)(m0 + mr) * KX) + quad;
        bf8* dstl = (bf8*)Wlds;
        for (int ko = w; ko < 32; ko += 4)
            dstl[ko * 64 + lane] = src[ko * 4];
    }
    __syncthreads();

    const bf8* Wl = (const bf8*)Wlds + lane;
    const int dl = (bid & 127) * 4 + quad;   // this thread's hidden index d
    const int bb = w * 16 + mr;              // this thread's batch
    const f4 biasv = isA ? ((const f4*)b1v)[dl] : ((const f4*)b2v)[dl];
    const int* xrow = xtok + bb * NS;

    float cr = 0.f;                          // persistent cell state (register)
    f4 accP = {0, 0, 0, 0};                  // carried recurrent partial (h(-1)=0)
    unsigned bt = 0;

    __hip_bfloat16 *X1c = X1a, *X1n = X1b, *X2c = X2a, *X2n = X2b;

    for (int t = 0; t < NS; ++t) {
        // ---- slot 1: LSTM0 finish / LSTM1 recurrent prefetch ----
        if (isA) {
            f4 acc = gemm16<0>(X1c + (size_t)bb * KX, quad, Wl, accP);  // ctx chunks
            f4 wo = ((const f4*)woh)[(size_t)xrow[t] * 512 + dl];       // onehot column gather
            acc.x += biasv.x + wo.x; acc.y += biasv.y + wo.y;
            acc.z += biasv.z + wo.z; acc.w += biasv.w + wo.w;
            float cn = sigm(acc.y) * cr + sigm(acc.x) * tanhf(acc.z);
            float hn = sigm(acc.w) * tanhf(cn);
            cr = cn;
            st_sc(X2c + (size_t)bb * KX + dl, hn);          // h1 -> LSTM1 input
            st_sc(X1n + (size_t)bb * KX + 512 + dl, hn);    // h1 -> next-step recurrent
        } else {
            f4 z = {0, 0, 0, 0};
            accP = gemm16<16>(X2c + (size_t)bb * KX, quad, Wl, z);      // h2(t-1) partial
        }
        gsync(bar, bt += 256);

        // ---- slot 2: LSTM1 finish / LSTM0 recurrent prefetch ----
        if (isA) {
            f4 z = {0, 0, 0, 0};
            accP = gemm16<16>(X1n + (size_t)bb * KX, quad, Wl, z);      // h1(t) partial for t+1
        } else {
            f4 acc = gemm16<0>(X2c + (size_t)bb * KX, quad, Wl, accP);  // h1(t) chunks
            acc.x += biasv.x; acc.y += biasv.y; acc.z += biasv.z; acc.w += biasv.w;
            float cn = sigm(acc.y) * cr + sigm(acc.x) * tanhf(acc.z);
            float hn = sigm(acc.w) * tanhf(cn);
            cr = cn;
            st_sc(X2n + (size_t)bb * KX + 512 + dl, hn);                // h2 recurrent
            scb[((size_t)bb * NS + t) * 1024 + dl] = __hip_bfloat16(hn); // normal: projection in
        }
        gsync(bar, bt += 256);

        // ---- slot 3: attention (all 256 blocks) ----
        attn_body2(X2n, Wphib, bphi, psib, hT, X1n, scb, t, h2s, phis, es, red);
        gsync(bar, bt += 256);

        __hip_bfloat16* tp;
        tp = X1c; X1c = X1n; X1n = tp;
        tp = X2c; X2c = X2n; X2n = tp;
    }
}

// ---------------- fallback per-step kernels (only if coop launch rejected) ----------------
__global__ __launch_bounds__(256) void fb_lstm0_kernel(
    const __hip_bfloat16* __restrict__ W1, const __hip_bfloat16* X1c,
    __hip_bfloat16* X1n, __hip_bfloat16* X2c, float* __restrict__ c1,
    const float* __restrict__ b1v, const float* __restrict__ woh,
    const int* __restrict__ xtok, int t)
{
    __shared__ __hip_bfloat16 Wlds[32 * 512];
    const int bid = blockIdx.x, tid = threadIdx.x;
    const int lane = tid & 63, w = tid >> 6;
    const int mr = lane & 15, quad = lane >> 4;
    {
        const bf8* src = (const bf8*)(W1 + (size_t)(bid * 16 + mr) * KX) + quad;
        bf8* dstl = (bf8*)Wlds;
        for (int ko = w; ko < 32; ko += 4) dstl[ko * 64 + lane] = src[ko * 4];
    }
    __syncthreads();
    const bf8* Wl = (const bf8*)Wlds + lane;
    const int dl = bid * 4 + quad, bb = w * 16 + mr;
    f4 acc = {0, 0, 0, 0};
    acc = gemm16<0>(X1c + (size_t)bb * KX, quad, Wl, acc);
    acc = gemm16<16>(X1c + (size_t)bb * KX, quad, Wl, acc);
    f4 bv = ((const f4*)b1v)[dl];
    f4 wo = ((const f4*)woh)[(size_t)xtok[bb * NS + t] * 512 + dl];
    acc.x += bv.x + wo.x; acc.y += bv.y + wo.y; acc.z += bv.z + wo.z; acc.w += bv.w + wo.w;
    int ci = dl * 64 + bb;
    float cn = sigm(acc.y) * c1[ci] + sigm(acc.x) * tanhf(acc.z);
    float hn = sigm(acc.w) * tanhf(cn);
    c1[ci] = cn;
    st_sc(X2c + (size_t)bb * KX + dl, hn);
    st_sc(X1n + (size_t)bb * KX + 512 + dl, hn);
}

__global__ __launch_bounds__(256) void fb_lstm1_kernel(
    const __hip_bfloat16* __restrict__ W2, const __hip_bfloat16* X2c,
    __hip_bfloat16* X2n, __hip_bfloat16* scb, float* __restrict__ c2,
    const float* __restrict__ b2v, int t)
{
    __shared__ __hip_bfloat16 Wlds[32 * 512];
    const int bid = blockIdx.x, tid = threadIdx.x;
    const int lane = tid & 63, w = tid >> 6;
    const int mr = lane & 15, quad = lane >> 4;
    {
        const bf8* src = (const bf8*)(W2 + (size_t)(bid * 16 + mr) * KX) + quad;
        bf8* dstl = (bf8*)Wlds;
        for (int ko = w; ko < 32; ko += 4) dstl[ko * 64 + lane] = src[ko * 4];
    }
    __syncthreads();
    const bf8* Wl = (const bf8*)Wlds + lane;
    const int dl = bid * 4 + quad, bb = w * 16 + mr;
    f4 acc = {0, 0, 0, 0};
    acc = gemm16<0>(X2c + (size_t)bb * KX, quad, Wl, acc);
    acc = gemm16<16>(X2c + (size_t)bb * KX, quad, Wl, acc);
    f4 bv = ((const f4*)b2v)[dl];
    acc.x += bv.x; acc.y += bv.y; acc.z += bv.z; acc.w += bv.w;
    int ci = dl * 64 + bb;
    float cn = sigm(acc.y) * c2[ci] + sigm(acc.x) * tanhf(acc.z);
    float hn = sigm(acc.w) * tanhf(cn);
    c2[ci] = cn;
    st_sc(X2n + (size_t)bb * KX + 512 + dl, hn);
    scb[((size_t)bb * NS + t) * 1024 + dl] = __hip_bfloat16(hn);
}

__global__ __launch_bounds__(256) void fb_attn_kernel(
    const __hip_bfloat16* X2n, const __hip_bfloat16* __restrict__ Wphib,
    const float* __restrict__ bphi, const __hip_bfloat16* __restrict__ psib,
    const __hip_bfloat16* __restrict__ hT,
    __hip_bfloat16* X1n, __hip_bfloat16* scb, int t)
{
    __shared__ float h2s[512], phis[128], es[512], red[256];
    attn_body2(X2n, Wphib, bphi, psib, hT, X1n, scb, t, h2s, phis, es, red);
}

// ---------------- psi GEMM: psibf[b*512+t][128] = hbf @ Wpsi^T + bpsi ----------------
__global__ __launch_bounds__(256) void psi_gemm_kernel(
    const __hip_bfloat16* __restrict__ A,   // hbf [32768][512]
    const __hip_bfloat16* __restrict__ Bw,  // Wpsibf [128][512]
    const float* __restrict__ bias,
    __hip_bfloat16* __restrict__ C)         // [32768][128]
{
    int lane = threadIdx.x & 63, wave = threadIdx.x >> 6;
    int m0 = (blockIdx.x * 4 + wave) * 16;
    int mr = lane & 15, quad = lane >> 4;
    const bf8* Ar = (const bf8*)(A + (size_t)(m0 + mr) * 512 + quad * 8);
    f4 acc[8] = {};
    for (int k0 = 0; k0 < 512; k0 += 32) {
        int ko = k0 >> 3;
        bf8 a = Ar[ko];
#pragma unroll
        for (int nf = 0; nf < 8; ++nf) {
            const bf8* Br = (const bf8*)(Bw + (size_t)(nf * 16 + mr) * 512 + quad * 8);
            acc[nf] = MFMA16(a, Br[ko], acc[nf]);
        }
    }
#pragma unroll
    for (int nf = 0; nf < 8; ++nf) {
        int n = nf * 16 + mr;
        float bs = bias[n];
#pragma unroll
        for (int r = 0; r < 4; ++r) {
            int m = m0 + quad * 4 + r;
            C[(size_t)m * 128 + n] = __hip_bfloat16(acc[nf][r] + bs);
        }
    }
}

// ---------------- final projection: out[b*128+t][64] = scbf @ Wcd^T + bcd ----------------
__global__ __launch_bounds__(256) void out_gemm_kernel(
    const __hip_bfloat16* __restrict__ A,   // scbf [8192][1024]
    const __hip_bfloat16* __restrict__ Bw,  // Wcdbf [64][1024]
    const float* __restrict__ bias,
    float* __restrict__ C)                  // [8192][64]
{
    int lane = threadIdx.x & 63, wave = threadIdx.x >> 6;
    int m0 = (blockIdx.x * 4 + wave) * 16;
    int mr = lane & 15, quad = lane >> 4;
    const bf8* Ar = (const bf8*)(A + (size_t)(m0 + mr) * 1024 + quad * 8);
    f4 acc[4] = {};
    for (int k0 = 0; k0 < 1024; k0 += 32) {
        int ko = k0 >> 3;
        bf8 a = Ar[ko];
#pragma unroll
        for (int nf = 0; nf < 4; ++nf) {
            const bf8* Br = (const bf8*)(Bw + (size_t)(nf * 16 + mr) * 1024 + quad * 8);
            acc[nf] = MFMA16(a, Br[ko], acc[nf]);
        }
    }
#pragma unroll
    for (int nf = 0; nf < 4; ++nf) {
        int n = nf * 16 + mr;
        float bs = bias[n];
#pragma unroll
        for (int r = 0; r < 4; ++r) {
            int m = m0 + quad * 4 + r;
            C[(size_t)m * 64 + n] = acc[nf][r] + bs;
        }
    }
}

extern "C" void kernel_launch(void* const* d_in, const int* in_sizes, int n_in,
                              void* d_out, int out_size, void* d_ws, size_t ws_size,
                              hipStream_t stream)
{
    const int*   x    = (const int*)  d_in[0];
    const float* h    = (const float*)d_in[1];
    const float* Wih0 = (const float*)d_in[2];
    const float* Whh0 = (const float*)d_in[3];
    const float* bih0 = (const float*)d_in[4];
    const float* bhh0 = (const float*)d_in[5];
    const float* Wih1 = (const float*)d_in[6];
    const float* Whh1 = (const float*)d_in[7];
    const float* bih1 = (const float*)d_in[8];
    const float* bhh1 = (const float*)d_in[9];
    const float* Wphi = (const float*)d_in[10];
    const float* bphi = (const float*)d_in[11];
    const float* Wpsi = (const float*)d_in[12];
    const float* bpsi = (const float*)d_in[13];
    const float* Wcd  = (const float*)d_in[14];
    const float* bcd  = (const float*)d_in[15];
    float* out = (float*)d_out;

    char* p = (char*)d_ws;
    __hip_bfloat16* hbf    = (__hip_bfloat16*)p; p += (size_t)BB * TT * SD * 2;   // 32 MB (hbf, then hT)
    __hip_bfloat16* psibf  = (__hip_bfloat16*)p; p += (size_t)BB * TT * ATT * 2;  // 8 MB
    __hip_bfloat16* scbf   = (__hip_bfloat16*)p; p += (size_t)BB * NS * 1024 * 2; // 16 MB
    __hip_bfloat16* W1aug  = (__hip_bfloat16*)p; p += (size_t)2048 * KX * 2;      // 4 MB
    __hip_bfloat16* W2aug  = (__hip_bfloat16*)p; p += (size_t)2048 * KX * 2;      // 4 MB
    __hip_bfloat16* Wphib  = (__hip_bfloat16*)p; p += (size_t)ATT * SD * 2;
    __hip_bfloat16* Wpsib  = (__hip_bfloat16*)p; p += (size_t)ATT * SD * 2;
    __hip_bfloat16* Wcdb   = (__hip_bfloat16*)p; p += (size_t)NC * 1024 * 2;
    __hip_bfloat16* X1[2]; X1[0] = (__hip_bfloat16*)p; p += (size_t)BB * KX * 2;
    X1[1] = (__hip_bfloat16*)p; p += (size_t)BB * KX * 2;
    __hip_bfloat16* X2[2]; X2[0] = (__hip_bfloat16*)p; p += (size_t)BB * KX * 2;
    X2[1] = (__hip_bfloat16*)p; p += (size_t)BB * KX * 2;
    float* b1v = (float*)p; p += 512 * 4 * 4;
    float* b2v = (float*)p; p += 512 * 4 * 4;
    float* woh = (float*)p; p += (size_t)64 * 512 * 4 * 4;   // 512 KB
    float* c1  = (float*)p; p += (size_t)SD * BB * 4;
    float* c2  = (float*)p; p += (size_t)SD * BB * 4;
    unsigned* bar = (unsigned*)p; p += 64;

    // ---- one-time prep ----
    f2b_kernel<<<16384, 256, 0, stream>>>(h, hbf, BB * TT * SD);
    f2b_kernel<<<64, 256, 0, stream>>>(Wphi, Wphib, ATT * SD);
    f2b_kernel<<<64, 256, 0, stream>>>(Wpsi, Wpsib, ATT * SD);
    f2b_kernel<<<64, 256, 0, stream>>>(Wcd, Wcdb, NC * 1024);
    prep_w1_kernel<<<(2048 * KX + 255) / 256, 256, 0, stream>>>(Wih0, Whh0, W1aug);
    prep_w2_kernel<<<(2048 * KX + 255) / 256, 256, 0, stream>>>(Wih1, Whh1, W2aug);
    prep_misc_kernel<<<(64 * 512 + 255) / 256, 256, 0, stream>>>(Wih0, bih0, bhh0, bih1, bhh1,
                                                                 b1v, b2v, woh);
    init_kernel<<<(64 * KX + 255) / 256, 256, 0, stream>>>(h, X1[0], X1[1], X2[0], X2[1],
                                                           c1, c2, bar);
    psi_gemm_kernel<<<512, 256, 0, stream>>>(hbf, Wpsib, bpsi, psibf);
    transpose_h_kernel<<<4096, 256, 0, stream>>>(h, hbf);   // overwrite hbf with hT [b][d][t]
    __hip_bfloat16* hT = hbf;

    // ---- persistent decode: custom no-invalidate barrier, 3 syncs/step ----
    const __hip_bfloat16 *a0 = W1aug, *a1 = W2aug, *a2 = Wphib;
    const float* a3 = bphi;
    const __hip_bfloat16 *a4 = psibf, *a5 = hT;
    __hip_bfloat16 *a6 = X1[0], *a7 = X1[1], *a8 = X2[0], *a9 = X2[1], *a10 = scbf;
    const int* a11 = x;
    const float *a12 = b1v, *a13 = b2v, *a14 = woh;
    unsigned* a15 = bar;
    void* args[16] = {&a0, &a1, &a2, &a3, &a4, &a5, &a6, &a7,
                      &a8, &a9, &a10, &a11, &a12, &a13, &a14, &a15};
    hipError_t ce = hipLaunchCooperativeKernel((const void*)decode_kernel,
                                               dim3(256), dim3(256), args, 0, stream);
    if (ce != hipSuccess) {
        (void)hipGetLastError();
        for (int t = 0; t < NS; ++t) {
            __hip_bfloat16* X1c = X1[t & 1], *X1n = X1[(t + 1) & 1];
            __hip_bfloat16* X2c = X2[t & 1], *X2n = X2[(t + 1) & 1];
            fb_lstm0_kernel<<<128, 256, 0, stream>>>(W1aug, X1c, X1n, X2c, c1, b1v, woh, x, t);
            fb_lstm1_kernel<<<128, 256, 0, stream>>>(W2aug, X2c, X2n, scbf, c2, b2v, t);
            fb_attn_kernel<<<256, 256, 0, stream>>>(X2n, Wphib, bphi, psibf, hT, X1n, scbf, t);
        }
    }
    // output projection
    out_gemm_kernel<<<128, 256, 0, stream>>>(scbf, Wcdb, bcd, out);
}

// Round 3
// 4330.100 us; speedup vs baseline: 6.1941x; 1.2342x over previous
//
#include <hip/hip_runtime.h>
#include <hip/hip_bf16.h>
#include <math.h>

#define BB 64      // batch
#define TT 512     // encoder time
#define NS 128     // decode steps
#define SD 512     // lstm hidden
#define ATT 128
#define NC 64      // num classes
#define KX 1024    // X row: 512 ctx/h1 + 512 rec

typedef __attribute__((ext_vector_type(8))) short bf8;   // 8 bf16 (4 VGPRs)
typedef __attribute__((ext_vector_type(4))) float f4;

__device__ __forceinline__ float sigm(float x) { return 1.0f / (1.0f + expf(-x)); }
__device__ __forceinline__ float b2f(short s) {
    union { unsigned u; float f; } c; c.u = ((unsigned)(unsigned short)s) << 16; return c.f;
}
#define MFMA16(a, b, c) __builtin_amdgcn_mfma_f32_16x16x32_bf16((a), (b), (c), 0, 0, 0)

// ---- coherent (L3-point) access helpers: sc0 sc1 = bypass L1/L2, no invalidates ----
__device__ __forceinline__ bf8 ld_sc_wait(const __hip_bfloat16* p) {
    bf8 v;
    asm volatile("global_load_dwordx4 %0, %1, off sc0 sc1\ns_waitcnt vmcnt(0)"
                 : "=v"(v) : "v"(p) : "memory");
    return v;
}
__device__ __forceinline__ void st_sc(__hip_bfloat16* p, float val) {
    __hip_bfloat16 hb(val);
    unsigned short bits; __builtin_memcpy(&bits, &hb, 2);
    unsigned v = bits;
    asm volatile("global_store_short %0, %1, off sc0 sc1" :: "v"(p), "v"(v) : "memory");
}
__device__ __forceinline__ unsigned ld_u32_sc(const unsigned* p) {
    unsigned v;
    asm volatile("global_load_dword %0, %1, off sc0 sc1\ns_waitcnt vmcnt(0)"
                 : "=v"(v) : "v"(p) : "memory");
    return v;
}

// grid barrier WITHOUT L2 invalidation. Arrivals striped over 8 cache lines
// (atomicAdd is device-scope coherent, m20); 8-lane parallel poll + wave reduce.
__device__ __forceinline__ void gsync(unsigned* bar, unsigned target)
{
    __syncthreads();
    if (threadIdx.x < 8) {
        if (threadIdx.x == 0)
            atomicAdd(bar + (blockIdx.x & 7) * 64, 1u);
        unsigned sum;
        do {
            unsigned v = ld_u32_sc(bar + threadIdx.x * 64);
            sum = v;
            sum += __shfl_xor(sum, 1);
            sum += __shfl_xor(sum, 2);
            sum += __shfl_xor(sum, 4);
        } while (sum < target);
    }
    __syncthreads();
}

// 16-chunk MFMA GEMM over one X row via sc loads; W fragments from REGISTERS
template<int BASE>
__device__ __forceinline__ f4 gemm16r(const __hip_bfloat16* Xrow, int quad,
                                      const bf8 (&wreg)[32], f4 acc)
{
    const bf8* Bq = (const bf8*)Xrow + quad;
    bf8 r0, r1, r2, r3, r4, r5, r6, r7, r8, r9, r10, r11, r12, r13, r14, r15;
#define LD1(i) asm volatile("global_load_dwordx4 %0, %1, off offset:%2 sc0 sc1" \
                            : "=v"(r##i) : "v"(Bq), "i"((BASE + i) * 64))
    LD1(0); LD1(1); LD1(2); LD1(3); LD1(4); LD1(5); LD1(6); LD1(7);
    LD1(8); LD1(9); LD1(10); LD1(11); LD1(12); LD1(13); LD1(14); LD1(15);
#undef LD1
    asm volatile("s_waitcnt vmcnt(0)"
                 : "+v"(r0), "+v"(r1), "+v"(r2), "+v"(r3),
                   "+v"(r4), "+v"(r5), "+v"(r6), "+v"(r7),
                   "+v"(r8), "+v"(r9), "+v"(r10), "+v"(r11),
                   "+v"(r12), "+v"(r13), "+v"(r14), "+v"(r15));
    __builtin_amdgcn_sched_barrier(0);
#define MM(i) acc = MFMA16(wreg[BASE + i], r##i, acc)
    MM(0); MM(1); MM(2); MM(3); MM(4); MM(5); MM(6); MM(7);
    MM(8); MM(9); MM(10); MM(11); MM(12); MM(13); MM(14); MM(15);
#undef MM
    return acc;
}

// legacy LDS-W variant (fallback path only)
template<int BASE>
__device__ __forceinline__ f4 gemm16(const __hip_bfloat16* Xrow, int quad, const bf8* Wl, f4 acc)
{
    const bf8* Bq = (const bf8*)Xrow + quad;
    bf8 r0, r1, r2, r3, r4, r5, r6, r7, r8, r9, r10, r11, r12, r13, r14, r15;
#define LD1(i) asm volatile("global_load_dwordx4 %0, %1, off offset:%2 sc0 sc1" \
                            : "=v"(r##i) : "v"(Bq), "i"((BASE + i) * 64))
    LD1(0); LD1(1); LD1(2); LD1(3); LD1(4); LD1(5); LD1(6); LD1(7);
    LD1(8); LD1(9); LD1(10); LD1(11); LD1(12); LD1(13); LD1(14); LD1(15);
#undef LD1
    asm volatile("s_waitcnt vmcnt(0)"
                 : "+v"(r0), "+v"(r1), "+v"(r2), "+v"(r3),
                   "+v"(r4), "+v"(r5), "+v"(r6), "+v"(r7),
                   "+v"(r8), "+v"(r9), "+v"(r10), "+v"(r11),
                   "+v"(r12), "+v"(r13), "+v"(r14), "+v"(r15));
    __builtin_amdgcn_sched_barrier(0);
#define MM(i) acc = MFMA16(Wl[(BASE + i) * 64], r##i, acc)
    MM(0); MM(1); MM(2); MM(3); MM(4); MM(5); MM(6); MM(7);
    MM(8); MM(9); MM(10); MM(11); MM(12); MM(13); MM(14); MM(15);
#undef MM
    return acc;
}

// ---------------- fp32 -> bf16 convert (vec4) ----------------
__global__ void f2b_kernel(const float* __restrict__ src, __hip_bfloat16* __restrict__ dst, int n)
{
    int i = (blockIdx.x * blockDim.x + threadIdx.x) * 4;
    if (i < n) {
        float4 v = *(const float4*)(src + i);
        dst[i]     = __hip_bfloat16(v.x);
        dst[i + 1] = __hip_bfloat16(v.y);
        dst[i + 2] = __hip_bfloat16(v.z);
        dst[i + 3] = __hip_bfloat16(v.w);
    }
}

// ---------------- transpose h: [b][t][d] f32 -> hT [b][d][t] bf16 ----------------
__global__ __launch_bounds__(256) void transpose_h_kernel(const float* __restrict__ h,
                                                          __hip_bfloat16* __restrict__ hT)
{
    int bidx = blockIdx.x;
    int b = bidx >> 6, tt0 = ((bidx >> 3) & 7) * 64, dd0 = (bidx & 7) * 64;
    __shared__ __hip_bfloat16 tile[64][65];
    int dd = threadIdx.x & 63, r4 = threadIdx.x >> 6;
#pragma unroll
    for (int i = 0; i < 64; i += 4) {
        int tl = i + r4;
        tile[tl][dd] = __hip_bfloat16(h[((size_t)b * TT + tt0 + tl) * SD + dd0 + dd]);
    }
    __syncthreads();
#pragma unroll
    for (int i = 0; i < 64; i += 4) {
        int dl = i + r4;
        hT[((size_t)b * SD + dd0 + dl) * TT + tt0 + dd] = tile[dd][dl];
    }
}

// ---------------- LSTM0 weights [2048][1024]: ctx cols | rec cols ----------------
__global__ void prep_w1_kernel(const float* __restrict__ Wih, const float* __restrict__ Whh,
                               __hip_bfloat16* __restrict__ W)
{
    int idx = blockIdx.x * blockDim.x + threadIdx.x;   // 2048*1024
    if (idx >= 2048 * KX) return;
    int np = idx >> 10, kk = idx & 1023;
    int q = np & 3, d = np >> 2, j = q * 512 + d;
    float v = (kk < 512) ? Wih[j * 576 + 64 + kk] : Whh[j * 512 + kk - 512];
    W[idx] = __hip_bfloat16(v);
}

// ---------------- LSTM1 weights [2048][1024] ----------------
__global__ void prep_w2_kernel(const float* __restrict__ Wih, const float* __restrict__ Whh,
                               __hip_bfloat16* __restrict__ W)
{
    int idx = blockIdx.x * blockDim.x + threadIdx.x;
    if (idx >= 2048 * KX) return;
    int np = idx >> 10, kk = idx & 1023;
    int q = np & 3, d = np >> 2, j = q * 512 + d;
    float v = (kk < 512) ? Wih[j * 512 + kk] : Whh[j * 512 + kk - 512];
    W[idx] = __hip_bfloat16(v);
}

// ---------------- biases (gate-interleaved f4) + per-token Wih0 column gather ----------------
__global__ void prep_misc_kernel(const float* __restrict__ Wih0,
                                 const float* __restrict__ bih0, const float* __restrict__ bhh0,
                                 const float* __restrict__ bih1, const float* __restrict__ bhh1,
                                 float* __restrict__ b1v, float* __restrict__ b2v,
                                 float* __restrict__ woh)   // [64 tok][512 d] f4
{
    int idx = blockIdx.x * blockDim.x + threadIdx.x;   // 64*512
    if (idx >= 64 * 512) return;
    int tok = idx >> 9, d = idx & 511;
    float4 w;
    w.x = Wih0[(0 * 512 + d) * 576 + tok];
    w.y = Wih0[(1 * 512 + d) * 576 + tok];
    w.z = Wih0[(2 * 512 + d) * 576 + tok];
    w.w = Wih0[(3 * 512 + d) * 576 + tok];
    ((float4*)woh)[idx] = w;
    if (tok == 0) {
        float4 b1, b2;
        b1.x = bih0[d] + bhh0[d];             b1.y = bih0[512 + d] + bhh0[512 + d];
        b1.z = bih0[1024 + d] + bhh0[1024 + d]; b1.w = bih0[1536 + d] + bhh0[1536 + d];
        b2.x = bih1[d] + bhh1[d];             b2.y = bih1[512 + d] + bhh1[512 + d];
        b2.z = bih1[1024 + d] + bhh1[1024 + d]; b2.w = bih1[1536 + d] + bhh1[1536 + d];
        ((float4*)b1v)[d] = b1;
        ((float4*)b2v)[d] = b2;
    }
}

// ---------------- init: X buffers [64][1024], c states, barrier ----------------
__global__ void init_kernel(const float* __restrict__ h,
                            __hip_bfloat16* __restrict__ X1a, __hip_bfloat16* __restrict__ X1b,
                            __hip_bfloat16* __restrict__ X2a, __hip_bfloat16* __restrict__ X2b,
                            float* __restrict__ c1, float* __restrict__ c2,
                            unsigned* __restrict__ bar)
{
    int idx = blockIdx.x * blockDim.x + threadIdx.x;   // 64*1024
    if (idx >= 64 * KX) return;
    int b = idx >> 10, col = idx & 1023;
    __hip_bfloat16 z(0.0f);
    X1a[idx] = (col < 512) ? __hip_bfloat16(h[(size_t)b * TT * SD + col]) : z;  // ctx0 = h[:,0,:]
    X1b[idx] = z; X2a[idx] = z; X2b[idx] = z;
    if (idx < 512 * 64) { c1[idx] = 0.f; c2[idx] = 0.f; }
    if (idx < 512) bar[idx] = 0u;
}

// ---------------- persistent decode kernel ----------------
// 256 blocks x 256 threads, 1 block/CU. Blocks 0..127: LSTM0 rows; 128..255: LSTM1.
// W tile in REGISTERS (32 x bf8). hT slice (b,dch): 128 d x 512 t bf16 = 128 KB
// LDS-resident for all 128 steps, XOR-swizzled (granule ^= d&7) for conflict-free
// ds_read_b128. Cell state in registers. 3 striped-barrier syncs/step.
__global__ __launch_bounds__(256, 1) void decode_kernel(
    const __hip_bfloat16* __restrict__ W1, const __hip_bfloat16* __restrict__ W2,
    const __hip_bfloat16* __restrict__ Wphib, const float* __restrict__ bphi,
    const __hip_bfloat16* __restrict__ psib, const __hip_bfloat16* __restrict__ hT,
    __hip_bfloat16* X1a, __hip_bfloat16* X1b,
    __hip_bfloat16* X2a, __hip_bfloat16* X2b,
    __hip_bfloat16* scb, const int* __restrict__ xtok,
    const float* __restrict__ b1v, const float* __restrict__ b2v,
    const float* __restrict__ woh, unsigned* __restrict__ bar)
{
    __shared__ bf8 hTl[128 * 64];                        // 128 KB swizzled hT slice
    __shared__ float h2s[512], phis[128], es[512], red[256];

    const int bid = blockIdx.x, tid = threadIdx.x;
    const int lane = tid & 63, w = tid >> 6;
    const int mr = lane & 15, quad = lane >> 4;
    const bool isA = bid < 128;
    const int ab = bid >> 2, dch = bid & 3;              // attention role (b, d-chunk)

    // ---- prologue: W rows -> registers ----
    bf8 wreg[32];
    {
        const __hip_bfloat16* Wg = isA ? W1 : W2;
        const int m0 = (bid & 127) * 16;
        const bf8* src = (const bf8*)(Wg + (size_t)(m0 + mr) * KX) + quad;
#pragma unroll
        for (int ko = 0; ko < 32; ++ko) wreg[ko] = src[ko * 4];
    }
    // ---- prologue: hT slice -> LDS (swizzled) ----
    {
        const bf8* src = (const bf8*)hT + ((size_t)ab * SD + dch * 128) * 64;
        for (int it = 0; it < 32; ++it) {
            int gidx = it * 256 + tid;                   // 0..8191
            int d = gidx >> 6, g = gidx & 63;
            hTl[d * 64 + (g ^ (d & 7))] = src[gidx];
        }
    }
    __syncthreads();

    const int dl = (bid & 127) * 4 + quad;   // this thread's hidden index d
    const int bb = w * 16 + mr;              // this thread's batch
    const f4 biasv = isA ? ((const f4*)b1v)[dl] : ((const f4*)b2v)[dl];
    const int* xrow = xtok + bb * NS;

    float cr = 0.f;                          // persistent cell state
    f4 accP = {0, 0, 0, 0};                  // carried recurrent partial (h(-1)=0)
    unsigned bt = 0;

    __hip_bfloat16 *X1c = X1a, *X1n = X1b, *X2c = X2a, *X2n = X2b;

    for (int t = 0; t < NS; ++t) {
        // ---- slot 1: LSTM0 finish / LSTM1 recurrent prefetch ----
        if (isA) {
            f4 wo = ((const f4*)woh)[(size_t)xrow[t] * 512 + dl];       // issue early
            f4 acc = gemm16r<0>(X1c + (size_t)bb * KX, quad, wreg, accP);
            acc.x += biasv.x + wo.x; acc.y += biasv.y + wo.y;
            acc.z += biasv.z + wo.z; acc.w += biasv.w + wo.w;
            float cn = sigm(acc.y) * cr + sigm(acc.x) * tanhf(acc.z);
            float hn = sigm(acc.w) * tanhf(cn);
            cr = cn;
            st_sc(X2c + (size_t)bb * KX + dl, hn);          // h1 -> LSTM1 input
            st_sc(X1n + (size_t)bb * KX + 512 + dl, hn);    // h1 -> next-step recurrent
        } else {
            f4 z = {0, 0, 0, 0};
            accP = gemm16r<16>(X2c + (size_t)bb * KX, quad, wreg, z);   // h2(t-1) partial
        }
        gsync(bar, bt += 256);

        // ---- slot 2: LSTM1 finish / LSTM0 recurrent prefetch ----
        if (isA) {
            f4 z = {0, 0, 0, 0};
            accP = gemm16r<16>(X1n + (size_t)bb * KX, quad, wreg, z);   // h1(t) for t+1
        } else {
            f4 acc = gemm16r<0>(X2c + (size_t)bb * KX, quad, wreg, accP);
            acc.x += biasv.x; acc.y += biasv.y; acc.z += biasv.z; acc.w += biasv.w;
            float cn = sigm(acc.y) * cr + sigm(acc.x) * tanhf(acc.z);
            float hn = sigm(acc.w) * tanhf(cn);
            cr = cn;
            st_sc(X2n + (size_t)bb * KX + 512 + dl, hn);                // h2 recurrent
            scb[((size_t)bb * NS + t) * 1024 + dl] = __hip_bfloat16(hn); // projection in
        }
        gsync(bar, bt += 256);

        // ---- slot 3: attention (all 256 blocks as (ab, dch)) ----
        {
            if (tid < 64) {                 // h2 via coherent load
                bf8 v = ld_sc_wait(X2n + (size_t)ab * KX + 512 + tid * 8);
#pragma unroll
                for (int j = 0; j < 8; ++j) h2s[tid * 8 + j] = b2f(v[j]);
            }
            __syncthreads();

            // phi[a] = h2 . Wphi[a] + bphi[a];  4 lanes/row (L2-hot read-only)
            {
                int al = tid & 3;
#pragma unroll
                for (int pass = 0; pass < 2; ++pass) {
                    int a = pass * 64 + (tid >> 2);
                    const bf8* wr = (const bf8*)(Wphib + (size_t)a * 512) + al;
                    float acc = 0.f;
#pragma unroll
                    for (int i = 0; i < 16; ++i) {
                        bf8 wv = wr[i * 4];
                        const float* hp2 = h2s + i * 32 + al * 8;
#pragma unroll
                        for (int j = 0; j < 8; ++j) acc += hp2[j] * b2f(wv[j]);
                    }
                    acc += __shfl_xor(acc, 1);
                    acc += __shfl_xor(acc, 2);
                    if (al == 0) phis[a] = acc + bphi[a];
                }
            }
            __syncthreads();

            // e[t'] = phi . psi[b][t']
            {
                int al = tid & 3;
#pragma unroll
                for (int pass = 0; pass < 8; ++pass) {
                    int tt = pass * 64 + (tid >> 2);
                    const bf8* pr = (const bf8*)(psib + ((size_t)ab * TT + tt) * 128) + al;
                    float acc = 0.f;
#pragma unroll
                    for (int i = 0; i < 4; ++i) {
                        bf8 pv = pr[i * 4];
                        const float* ph = phis + i * 32 + al * 8;
#pragma unroll
                        for (int j = 0; j < 8; ++j) acc += ph[j] * b2f(pv[j]);
                    }
                    acc += __shfl_xor(acc, 1);
                    acc += __shfl_xor(acc, 2);
                    if (al == 0) es[tt] = acc;
                }
            }
            __syncthreads();

            // softmax (unnormalized; fold 1/sum into ctx)
            red[tid] = fmaxf(es[tid], es[tid + 256]);
            __syncthreads();
            for (int st = 128; st > 0; st >>= 1) {
                if (tid < st) red[tid] = fmaxf(red[tid], red[tid + st]);
                __syncthreads();
            }
            float mx = red[0];
            __syncthreads();
            float e0 = expf(es[tid] - mx), e1 = expf(es[tid + 256] - mx);
            es[tid] = e0; es[tid + 256] = e1;
            red[tid] = e0 + e1;
            __syncthreads();
            for (int st = 128; st > 0; st >>= 1) {
                if (tid < st) red[tid] += red[tid + st];
                __syncthreads();
            }
            float inv = 1.0f / red[0];
            __syncthreads();

            // ctx[d] from LDS-resident hT slice (swizzled reads)
            {
                int d = tid & 127, th = tid >> 7;
                const float* ep = es + th * 256;
                const int rb = d * 64, g0 = th * 32, sw = d & 7;
                float a0 = 0.f, a1 = 0.f, a2 = 0.f, a3 = 0.f;
#pragma unroll
                for (int i = 0; i < 32; i += 4) {
                    bf8 v0 = hTl[rb + ((g0 + i)     ^ sw)];
                    bf8 v1 = hTl[rb + ((g0 + i + 1) ^ sw)];
                    bf8 v2 = hTl[rb + ((g0 + i + 2) ^ sw)];
                    bf8 v3 = hTl[rb + ((g0 + i + 3) ^ sw)];
#pragma unroll
                    for (int j = 0; j < 8; ++j) {
                        a0 += ep[i * 8 + j]      * b2f(v0[j]);
                        a1 += ep[i * 8 + 8 + j]  * b2f(v1[j]);
                        a2 += ep[i * 8 + 16 + j] * b2f(v2[j]);
                        a3 += ep[i * 8 + 24 + j] * b2f(v3[j]);
                    }
                }
                float acc = (a0 + a1) + (a2 + a3);
                red[tid] = acc;
                __syncthreads();
                if (th == 0) {
                    float v = (acc + red[tid + 128]) * inv;
                    st_sc(X1n + (size_t)ab * KX + dch * 128 + d, v);
                    scb[((size_t)ab * NS + t) * 1024 + 512 + dch * 128 + d] = __hip_bfloat16(v);
                }
            }
        }
        gsync(bar, bt += 256);

        __hip_bfloat16* tp;
        tp = X1c; X1c = X1n; X1n = tp;
        tp = X2c; X2c = X2n; X2n = tp;
    }
}

// ---------------- fallback per-step kernels (only if coop launch rejected) ----------------
__device__ __forceinline__ void attn_body_fb(
    const __hip_bfloat16* X2n, const __hip_bfloat16* __restrict__ Wphib,
    const float* __restrict__ bphi, const __hip_bfloat16* __restrict__ psib,
    const __hip_bfloat16* __restrict__ hT,
    __hip_bfloat16* X1n, __hip_bfloat16* scb, int t,
    float* h2s, float* phis, float* es, float* red)
{
    int b = blockIdx.x >> 2, dch = blockIdx.x & 3;
    int tid = threadIdx.x;
    if (tid < 64) {
        bf8 v = ld_sc_wait(X2n + (size_t)b * KX + 512 + tid * 8);
#pragma unroll
        for (int j = 0; j < 8; ++j) h2s[tid * 8 + j] = b2f(v[j]);
    }
    __syncthreads();
    {
        int al = tid & 3;
#pragma unroll
        for (int pass = 0; pass < 2; ++pass) {
            int a = pass * 64 + (tid >> 2);
            const bf8* wr = (const bf8*)(Wphib + (size_t)a * 512) + al;
            float acc = 0.f;
#pragma unroll
            for (int i = 0; i < 16; ++i) {
                bf8 wv = wr[i * 4];
                const float* hp2 = h2s + i * 32 + al * 8;
#pragma unroll
                for (int j = 0; j < 8; ++j) acc += hp2[j] * b2f(wv[j]);
            }
            acc += __shfl_xor(acc, 1);
            acc += __shfl_xor(acc, 2);
            if (al == 0) phis[a] = acc + bphi[a];
        }
    }
    __syncthreads();
    {
        int al = tid & 3;
#pragma unroll
        for (int pass = 0; pass < 8; ++pass) {
            int tt = pass * 64 + (tid >> 2);
            const bf8* pr = (const bf8*)(psib + ((size_t)b * TT + tt) * 128) + al;
            float acc = 0.f;
#pragma unroll
            for (int i = 0; i < 4; ++i) {
                bf8 pv = pr[i * 4];
                const float* ph = phis + i * 32 + al * 8;
#pragma unroll
                for (int j = 0; j < 8; ++j) acc += ph[j] * b2f(pv[j]);
            }
            acc += __shfl_xor(acc, 1);
            acc += __shfl_xor(acc, 2);
            if (al == 0) es[tt] = acc;
        }
    }
    __syncthreads();
    red[tid] = fmaxf(es[tid], es[tid + 256]);
    __syncthreads();
    for (int st = 128; st > 0; st >>= 1) {
        if (tid < st) red[tid] = fmaxf(red[tid], red[tid + st]);
        __syncthreads();
    }
    float mx = red[0];
    __syncthreads();
    float e0 = expf(es[tid] - mx), e1 = expf(es[tid + 256] - mx);
    es[tid] = e0; es[tid + 256] = e1;
    red[tid] = e0 + e1;
    __syncthreads();
    for (int st = 128; st > 0; st >>= 1) {
        if (tid < st) red[tid] += red[tid + st];
        __syncthreads();
    }
    float inv = 1.0f / red[0];
    __syncthreads();
    {
        int d = dch * 128 + (tid & 127), th = tid >> 7;
        const bf8* hp = (const bf8*)hT + ((size_t)b * SD + d) * 64 + th * 32;
        const float* ep = es + th * 256;
        float a0 = 0.f, a1 = 0.f, a2 = 0.f, a3 = 0.f;
#pragma unroll
        for (int i = 0; i < 32; i += 4) {
            bf8 v0 = hp[i], v1 = hp[i + 1], v2 = hp[i + 2], v3 = hp[i + 3];
#pragma unroll
            for (int j = 0; j < 8; ++j) {
                a0 += ep[i * 8 + j]      * b2f(v0[j]);
                a1 += ep[i * 8 + 8 + j]  * b2f(v1[j]);
                a2 += ep[i * 8 + 16 + j] * b2f(v2[j]);
                a3 += ep[i * 8 + 24 + j] * b2f(v3[j]);
            }
        }
        float acc = (a0 + a1) + (a2 + a3);
        red[tid] = acc;
        __syncthreads();
        if (th == 0) {
            float v = (acc + red[tid + 128]) * inv;
            st_sc(X1n + (size_t)b * KX + d, v);
            scb[((size_t)b * NS + t) * 1024 + 512 + d] = __hip_bfloat16(v);
        }
    }
}

__global__ __launch_bounds__(256) void fb_lstm0_kernel(
    const __hip_bfloat16* __restrict__ W1, const __hip_bfloat16* X1c,
    __hip_bfloat16* X1n, __hip_bfloat16* X2c, float* __restrict__ c1,
    const float* __restrict__ b1v, const float* __restrict__ woh,
    const int* __restrict__ xtok, int t)
{
    __shared__ __hip_bfloat16 Wlds[32 * 512];
    const int bid = blockIdx.x, tid = threadIdx.x;
    const int lane = tid & 63, w = tid >> 6;
    const int mr = lane & 15, quad = lane >> 4;
    {
        const bf8* src = (const bf8*)(W1 + (size_t)(bid * 16 + mr) * KX) + quad;
        bf8* dstl = (bf8*)Wlds;
        for (int ko = w; ko < 32; ko += 4) dstl[ko * 64 + lane] = src[ko * 4];
    }
    __syncthreads();
    const bf8* Wl = (const bf8*)Wlds + lane;
    const int dl = bid * 4 + quad, bb = w * 16 + mr;
    f4 acc = {0, 0, 0, 0};
    acc = gemm16<0>(X1c + (size_t)bb * KX, quad, Wl, acc);
    acc = gemm16<16>(X1c + (size_t)bb * KX, quad, Wl, acc);
    f4 bv = ((const f4*)b1v)[dl];
    f4 wo = ((const f4*)woh)[(size_t)xtok[bb * NS + t] * 512 + dl];
    acc.x += bv.x + wo.x; acc.y += bv.y + wo.y; acc.z += bv.z + wo.z; acc.w += bv.w + wo.w;
    int ci = dl * 64 + bb;
    float cn = sigm(acc.y) * c1[ci] + sigm(acc.x) * tanhf(acc.z);
    float hn = sigm(acc.w) * tanhf(cn);
    c1[ci] = cn;
    st_sc(X2c + (size_t)bb * KX + dl, hn);
    st_sc(X1n + (size_t)bb * KX + 512 + dl, hn);
}

__global__ __launch_bounds__(256) void fb_lstm1_kernel(
    const __hip_bfloat16* __restrict__ W2, const __hip_bfloat16* X2c,
    __hip_bfloat16* X2n, __hip_bfloat16* scb, float* __restrict__ c2,
    const float* __restrict__ b2v, int t)
{
    __shared__ __hip_bfloat16 Wlds[32 * 512];
    const int bid = blockIdx.x, tid = threadIdx.x;
    const int lane = tid & 63, w = tid >> 6;
    const int mr = lane & 15, quad = lane >> 4;
    {
        const bf8* src = (const bf8*)(W2 + (size_t)(bid * 16 + mr) * KX) + quad;
        bf8* dstl = (bf8*)Wlds;
        for (int ko = w; ko < 32; ko += 4) dstl[ko * 64 + lane] = src[ko * 4];
    }
    __syncthreads();
    const bf8* Wl = (const bf8*)Wlds + lane;
    const int dl = bid * 4 + quad, bb = w * 16 + mr;
    f4 acc = {0, 0, 0, 0};
    acc = gemm16<0>(X2c + (size_t)bb * KX, quad, Wl, acc);
    acc = gemm16<16>(X2c + (size_t)bb * KX, quad, Wl, acc);
    f4 bv = ((const f4*)b2v)[dl];
    acc.x += bv.x; acc.y += bv.y; acc.z += bv.z; acc.w += bv.w;
    int ci = dl * 64 + bb;
    float cn = sigm(acc.y) * c2[ci] + sigm(acc.x) * tanhf(acc.z);
    float hn = sigm(acc.w) * tanhf(cn);
    c2[ci] = cn;
    st_sc(X2n + (size_t)bb * KX + 512 + dl, hn);
    scb[((size_t)bb * NS + t) * 1024 + dl] = __hip_bfloat16(hn);
}

__global__ __launch_bounds__(256) void fb_attn_kernel(
    const __hip_bfloat16* X2n, const __hip_bfloat16* __restrict__ Wphib,
    const float* __restrict__ bphi, const __hip_bfloat16* __restrict__ psib,
    const __hip_bfloat16* __restrict__ hT,
    __hip_bfloat16* X1n, __hip_bfloat16* scb, int t)
{
    __shared__ float h2s[512], phis[128], es[512], red[256];
    attn_body_fb(X2n, Wphib, bphi, psib, hT, X1n, scb, t, h2s, phis, es, red);
}

// ---------------- psi GEMM: psibf[b*512+t][128] = hbf @ Wpsi^T + bpsi ----------------
__global__ __launch_bounds__(256) void psi_gemm_kernel(
    const __hip_bfloat16* __restrict__ A,   // hbf [32768][512]
    const __hip_bfloat16* __restrict__ Bw,  // Wpsibf [128][512]
    const float* __restrict__ bias,
    __hip_bfloat16* __restrict__ C)         // [32768][128]
{
    int lane = threadIdx.x & 63, wave = threadIdx.x >> 6;
    int m0 = (blockIdx.x * 4 + wave) * 16;
    int mr = lane & 15, quad = lane >> 4;
    const bf8* Ar = (const bf8*)(A + (size_t)(m0 + mr) * 512 + quad * 8);
    f4 acc[8] = {};
    for (int k0 = 0; k0 < 512; k0 += 32) {
        int ko = k0 >> 3;
        bf8 a = Ar[ko];
#pragma unroll
        for (int nf = 0; nf < 8; ++nf) {
            const bf8* Br = (const bf8*)(Bw + (size_t)(nf * 16 + mr) * 512 + quad * 8);
            acc[nf] = MFMA16(a, Br[ko], acc[nf]);
        }
    }
#pragma unroll
    for (int nf = 0; nf < 8; ++nf) {
        int n = nf * 16 + mr;
        float bs = bias[n];
#pragma unroll
        for (int r = 0; r < 4; ++r) {
            int m = m0 + quad * 4 + r;
            C[(size_t)m * 128 + n] = __hip_bfloat16(acc[nf][r] + bs);
        }
    }
}

// ---------------- final projection: out[b*128+t][64] = scbf @ Wcd^T + bcd ----------------
__global__ __launch_bounds__(256) void out_gemm_kernel(
    const __hip_bfloat16* __restrict__ A,   // scbf [8192][1024]
    const __hip_bfloat16* __restrict__ Bw,  // Wcdbf [64][1024]
    const float* __restrict__ bias,
    float* __restrict__ C)                  // [8192][64]
{
    int lane = threadIdx.x & 63, wave = threadIdx.x >> 6;
    int m0 = (blockIdx.x * 4 + wave) * 16;
    int mr = lane & 15, quad = lane >> 4;
    const bf8* Ar = (const bf8*)(A + (size_t)(m0 + mr) * 1024 + quad * 8);
    f4 acc[4] = {};
    for (int k0 = 0; k0 < 1024; k0 += 32) {
        int ko = k0 >> 3;
        bf8 a = Ar[ko];
#pragma unroll
        for (int nf = 0; nf < 4; ++nf) {
            const bf8* Br = (const bf8*)(Bw + (size_t)(nf * 16 + mr) * 1024 + quad * 8);
            acc[nf] = MFMA16(a, Br[ko], acc[nf]);
        }
    }
#pragma unroll
    for (int nf = 0; nf < 4; ++nf) {
        int n = nf * 16 + mr;
        float bs = bias[n];
#pragma unroll
        for (int r = 0; r < 4; ++r) {
            int m = m0 + quad * 4 + r;
            C[(size_t)m * 64 + n] = acc[nf][r] + bs;
        }
    }
}

extern "C" void kernel_launch(void* const* d_in, const int* in_sizes, int n_in,
                              void* d_out, int out_size, void* d_ws, size_t ws_size,
                              hipStream_t stream)
{
    const int*   x    = (const int*)  d_in[0];
    const float* h    = (const float*)d_in[1];
    const float* Wih0 = (const float*)d_in[2];
    const float* Whh0 = (const float*)d_in[3];
    const float* bih0 = (const float*)d_in[4];
    const float* bhh0 = (const float*)d_in[5];
    const float* Wih1 = (const float*)d_in[6];
    const float* Whh1 = (const float*)d_in[7];
    const float* bih1 = (const float*)d_in[8];
    const float* bhh1 = (const float*)d_in[9];
    const float* Wphi = (const float*)d_in[10];
    const float* bphi = (const float*)d_in[11];
    const float* Wpsi = (const float*)d_in[12];
    const float* bpsi = (const float*)d_in[13];
    const float* Wcd  = (const float*)d_in[14];
    const float* bcd  = (const float*)d_in[15];
    float* out = (float*)d_out;

    char* p = (char*)d_ws;
    __hip_bfloat16* hbf    = (__hip_bfloat16*)p; p += (size_t)BB * TT * SD * 2;   // 32 MB (hbf, then hT)
    __hip_bfloat16* psibf  = (__hip_bfloat16*)p; p += (size_t)BB * TT * ATT * 2;  // 8 MB
    __hip_bfloat16* scbf   = (__hip_bfloat16*)p; p += (size_t)BB * NS * 1024 * 2; // 16 MB
    __hip_bfloat16* W1aug  = (__hip_bfloat16*)p; p += (size_t)2048 * KX * 2;      // 4 MB
    __hip_bfloat16* W2aug  = (__hip_bfloat16*)p; p += (size_t)2048 * KX * 2;      // 4 MB
    __hip_bfloat16* Wphib  = (__hip_bfloat16*)p; p += (size_t)ATT * SD * 2;
    __hip_bfloat16* Wpsib  = (__hip_bfloat16*)p; p += (size_t)ATT * SD * 2;
    __hip_bfloat16* Wcdb   = (__hip_bfloat16*)p; p += (size_t)NC * 1024 * 2;
    __hip_bfloat16* X1[2]; X1[0] = (__hip_bfloat16*)p; p += (size_t)BB * KX * 2;
    X1[1] = (__hip_bfloat16*)p; p += (size_t)BB * KX * 2;
    __hip_bfloat16* X2[2]; X2[0] = (__hip_bfloat16*)p; p += (size_t)BB * KX * 2;
    X2[1] = (__hip_bfloat16*)p; p += (size_t)BB * KX * 2;
    float* b1v = (float*)p; p += 512 * 4 * 4;
    float* b2v = (float*)p; p += 512 * 4 * 4;
    float* woh = (float*)p; p += (size_t)64 * 512 * 4 * 4;   // 512 KB
    float* c1  = (float*)p; p += (size_t)SD * BB * 4;
    float* c2  = (float*)p; p += (size_t)SD * BB * 4;
    unsigned* bar = (unsigned*)p; p += 512 * 4;              // 8 striped counters

    // ---- one-time prep ----
    f2b_kernel<<<16384, 256, 0, stream>>>(h, hbf, BB * TT * SD);
    f2b_kernel<<<64, 256, 0, stream>>>(Wphi, Wphib, ATT * SD);
    f2b_kernel<<<64, 256, 0, stream>>>(Wpsi, Wpsib, ATT * SD);
    f2b_kernel<<<64, 256, 0, stream>>>(Wcd, Wcdb, NC * 1024);
    prep_w1_kernel<<<(2048 * KX + 255) / 256, 256, 0, stream>>>(Wih0, Whh0, W1aug);
    prep_w2_kernel<<<(2048 * KX + 255) / 256, 256, 0, stream>>>(Wih1, Whh1, W2aug);
    prep_misc_kernel<<<(64 * 512 + 255) / 256, 256, 0, stream>>>(Wih0, bih0, bhh0, bih1, bhh1,
                                                                 b1v, b2v, woh);
    init_kernel<<<(64 * KX + 255) / 256, 256, 0, stream>>>(h, X1[0], X1[1], X2[0], X2[1],
                                                           c1, c2, bar);
    psi_gemm_kernel<<<512, 256, 0, stream>>>(hbf, Wpsib, bpsi, psibf);
    transpose_h_kernel<<<4096, 256, 0, stream>>>(h, hbf);   // overwrite hbf with hT [b][d][t]
    __hip_bfloat16* hT = hbf;

    // ---- persistent decode ----
    const __hip_bfloat16 *a0 = W1aug, *a1 = W2aug, *a2 = Wphib;
    const float* a3 = bphi;
    const __hip_bfloat16 *a4 = psibf, *a5 = hT;
    __hip_bfloat16 *a6 = X1[0], *a7 = X1[1], *a8 = X2[0], *a9 = X2[1], *a10 = scbf;
    const int* a11 = x;
    const float *a12 = b1v, *a13 = b2v, *a14 = woh;
    unsigned* a15 = bar;
    void* args[16] = {&a0, &a1, &a2, &a3, &a4, &a5, &a6, &a7,
                      &a8, &a9, &a10, &a11, &a12, &a13, &a14, &a15};
    hipError_t ce = hipLaunchCooperativeKernel((const void*)decode_kernel,
                                               dim3(256), dim3(256), args, 0, stream);
    if (ce != hipSuccess) {
        (void)hipGetLastError();
        for (int t = 0; t < NS; ++t) {
            __hip_bfloat16* X1c = X1[t & 1], *X1n = X1[(t + 1) & 1];
            __hip_bfloat16* X2c = X2[t & 1], *X2n = X2[(t + 1) & 1];
            fb_lstm0_kernel<<<128, 256, 0, stream>>>(W1aug, X1c, X1n, X2c, c1, b1v, woh, x, t);
            fb_lstm1_kernel<<<128, 256, 0, stream>>>(W2aug, X2c, X2n, scbf, c2, b2v, t);
            fb_attn_kernel<<<256, 256, 0, stream>>>(X2n, Wphib, bphi, psibf, hT, X1n, scbf, t);
        }
    }
    // output projection
    out_gemm_kernel<<<128, 256, 0, stream>>>(scbf, Wcdb, bcd, out);
}

// Round 4
// 3875.408 us; speedup vs baseline: 6.9209x; 1.1173x over previous
//
#include <hip/hip_runtime.h>
#include <hip/hip_bf16.h>
#include <math.h>

#define BB 64      // batch
#define TT 512     // encoder time
#define NS 128     // decode steps
#define SD 512     // lstm hidden
#define ATT 128
#define NC 64      // num classes
#define KX 1024    // X row: 512 ctx/h1 + 512 rec

typedef __attribute__((ext_vector_type(8))) short bf8;   // 8 bf16 (4 VGPRs)
typedef __attribute__((ext_vector_type(4))) float f4;

__device__ __forceinline__ float sigm(float x) { return 1.0f / (1.0f + expf(-x)); }
__device__ __forceinline__ float b2f(short s) {
    union { unsigned u; float f; } c; c.u = ((unsigned)(unsigned short)s) << 16; return c.f;
}
#define MFMA16(a, b, c) __builtin_amdgcn_mfma_f32_16x16x32_bf16((a), (b), (c), 0, 0, 0)

// ---- coherent (L3-point) helpers. Stores write-through (sc0 sc1) so that
// readers' L2-miss fetches from L3 observe them; reads of MUTABLE-REUSED
// addresses (barrier counters) also bypass caches. X data uses per-step
// fresh buffers, so X READS are normal cached loads (L2-shareable). ----
__device__ __forceinline__ void st_sc(__hip_bfloat16* p, float val) {
    __hip_bfloat16 hb(val);
    unsigned short bits; __builtin_memcpy(&bits, &hb, 2);
    unsigned v = bits;
    asm volatile("global_store_short %0, %1, off sc0 sc1" :: "v"(p), "v"(v) : "memory");
}
__device__ __forceinline__ unsigned ld_u32_sc(const unsigned* p) {
    unsigned v;
    asm volatile("global_load_dword %0, %1, off sc0 sc1\ns_waitcnt vmcnt(0)"
                 : "=v"(v) : "v"(p) : "memory");
    return v;
}

// grid barrier WITHOUT L2 invalidation. Arrivals striped over 8 cache lines
// (atomicAdd is device-scope coherent); 8-lane parallel poll + wave reduce.
// __syncthreads() at entry drains vmcnt (incl. sc write-through acks).
__device__ __forceinline__ void gsync(unsigned* bar, unsigned target)
{
    __syncthreads();
    if (threadIdx.x < 8) {
        if (threadIdx.x == 0)
            atomicAdd(bar + (blockIdx.x & 7) * 64, 1u);
        unsigned sum;
        do {
            unsigned v = ld_u32_sc(bar + threadIdx.x * 64);
            sum = v;
            sum += __shfl_xor(sum, 1);
            sum += __shfl_xor(sum, 2);
            sum += __shfl_xor(sum, 4);
        } while (sum < target);
    }
    __syncthreads();
}

// 16-chunk MFMA GEMM over one X row; NORMAL cached loads (per-step-fresh
// addresses guarantee coherence); W fragments from registers.
template<int BASE>
__device__ __forceinline__ f4 gemm16r(const __hip_bfloat16* Xrow, int quad,
                                      const bf8 (&wreg)[32], f4 acc)
{
    const bf8* Bq = (const bf8*)Xrow + quad;
    bf8 r[16];
#pragma unroll
    for (int i = 0; i < 16; ++i) r[i] = Bq[(BASE + i) * 4];
#pragma unroll
    for (int i = 0; i < 16; ++i) acc = MFMA16(wreg[BASE + i], r[i], acc);
    return acc;
}

// ---------------- fp32 -> bf16 convert (vec4) ----------------
__global__ void f2b_kernel(const float* __restrict__ src, __hip_bfloat16* __restrict__ dst, int n)
{
    int i = (blockIdx.x * blockDim.x + threadIdx.x) * 4;
    if (i < n) {
        float4 v = *(const float4*)(src + i);
        dst[i]     = __hip_bfloat16(v.x);
        dst[i + 1] = __hip_bfloat16(v.y);
        dst[i + 2] = __hip_bfloat16(v.z);
        dst[i + 3] = __hip_bfloat16(v.w);
    }
}

// ---------------- transpose h: [b][t][d] f32 -> hT [b][d][t] bf16 ----------------
__global__ __launch_bounds__(256) void transpose_h_kernel(const float* __restrict__ h,
                                                          __hip_bfloat16* __restrict__ hT)
{
    int bidx = blockIdx.x;
    int b = bidx >> 6, tt0 = ((bidx >> 3) & 7) * 64, dd0 = (bidx & 7) * 64;
    __shared__ __hip_bfloat16 tile[64][65];
    int dd = threadIdx.x & 63, r4 = threadIdx.x >> 6;
#pragma unroll
    for (int i = 0; i < 64; i += 4) {
        int tl = i + r4;
        tile[tl][dd] = __hip_bfloat16(h[((size_t)b * TT + tt0 + tl) * SD + dd0 + dd]);
    }
    __syncthreads();
#pragma unroll
    for (int i = 0; i < 64; i += 4) {
        int dl = i + r4;
        hT[((size_t)b * SD + dd0 + dl) * TT + tt0 + dd] = tile[dd][dl];
    }
}

// ---------------- LSTM0 weights [2048][1024]: ctx cols | rec cols ----------------
__global__ void prep_w1_kernel(const float* __restrict__ Wih, const float* __restrict__ Whh,
                               __hip_bfloat16* __restrict__ W)
{
    int idx = blockIdx.x * blockDim.x + threadIdx.x;   // 2048*1024
    if (idx >= 2048 * KX) return;
    int np = idx >> 10, kk = idx & 1023;
    int q = np & 3, d = np >> 2, j = q * 512 + d;
    float v = (kk < 512) ? Wih[j * 576 + 64 + kk] : Whh[j * 512 + kk - 512];
    W[idx] = __hip_bfloat16(v);
}

// ---------------- LSTM1 weights [2048][1024] ----------------
__global__ void prep_w2_kernel(const float* __restrict__ Wih, const float* __restrict__ Whh,
                               __hip_bfloat16* __restrict__ W)
{
    int idx = blockIdx.x * blockDim.x + threadIdx.x;
    if (idx >= 2048 * KX) return;
    int np = idx >> 10, kk = idx & 1023;
    int q = np & 3, d = np >> 2, j = q * 512 + d;
    float v = (kk < 512) ? Wih[j * 512 + kk] : Whh[j * 512 + kk - 512];
    W[idx] = __hip_bfloat16(v);
}

// ---------------- biases (gate-interleaved f4) + per-token Wih0 column gather ----------------
__global__ void prep_misc_kernel(const float* __restrict__ Wih0,
                                 const float* __restrict__ bih0, const float* __restrict__ bhh0,
                                 const float* __restrict__ bih1, const float* __restrict__ bhh1,
                                 float* __restrict__ b1v, float* __restrict__ b2v,
                                 float* __restrict__ woh)   // [64 tok][512 d] f4
{
    int idx = blockIdx.x * blockDim.x + threadIdx.x;   // 64*512
    if (idx >= 64 * 512) return;
    int tok = idx >> 9, d = idx & 511;
    float4 w;
    w.x = Wih0[(0 * 512 + d) * 576 + tok];
    w.y = Wih0[(1 * 512 + d) * 576 + tok];
    w.z = Wih0[(2 * 512 + d) * 576 + tok];
    w.w = Wih0[(3 * 512 + d) * 576 + tok];
    ((float4*)woh)[idx] = w;
    if (tok == 0) {
        float4 b1, b2;
        b1.x = bih0[d] + bhh0[d];             b1.y = bih0[512 + d] + bhh0[512 + d];
        b1.z = bih0[1024 + d] + bhh0[1024 + d]; b1.w = bih0[1536 + d] + bhh0[1536 + d];
        b2.x = bih1[d] + bhh1[d];             b2.y = bih1[512 + d] + bhh1[512 + d];
        b2.z = bih1[1024 + d] + bhh1[1024 + d]; b2.w = bih1[1536 + d] + bhh1[1536 + d];
        ((float4*)b1v)[d] = b1;
        ((float4*)b2v)[d] = b2;
    }
}

// ---------------- init: step-0 X buffers, c states, barrier ----------------
__global__ void init_kernel(const float* __restrict__ h,
                            __hip_bfloat16* __restrict__ X1_0,
                            __hip_bfloat16* __restrict__ X2_0,
                            float* __restrict__ c1, float* __restrict__ c2,
                            unsigned* __restrict__ bar)
{
    int idx = blockIdx.x * blockDim.x + threadIdx.x;   // 64*1024
    if (idx >= 64 * KX) return;
    int b = idx >> 10, col = idx & 1023;
    __hip_bfloat16 z(0.0f);
    X1_0[idx] = (col < 512) ? __hip_bfloat16(h[(size_t)b * TT * SD + col]) : z;  // ctx0 | h1(-1)=0
    X2_0[idx] = z;                                                               // h2(-1)=0
    if (idx < 512 * 64) { c1[idx] = 0.f; c2[idx] = 0.f; }
    if (idx < 512) bar[idx] = 0u;
}

// ---------------- persistent decode kernel ----------------
// 256 blocks x 256 threads, 1 block/CU. Blocks 0..127: LSTM0 rows; 128..255: LSTM1.
// W tile in REGISTERS (32 x bf8). hT slice (ab,dch): 128 KB LDS-resident, swizzled.
// Per-step X buffers => X reads are L2-cacheable (fresh addresses). 3 syncs/step.
__global__ __launch_bounds__(256, 1) void decode_kernel(
    const __hip_bfloat16* __restrict__ W1, const __hip_bfloat16* __restrict__ W2,
    const __hip_bfloat16* __restrict__ Wphib, const float* __restrict__ bphi,
    const __hip_bfloat16* __restrict__ psib, const __hip_bfloat16* __restrict__ hT,
    __hip_bfloat16* X1base, __hip_bfloat16* X2base,
    __hip_bfloat16* scb, const int* __restrict__ xtok,
    const float* __restrict__ b1v, const float* __restrict__ b2v,
    const float* __restrict__ woh, unsigned* __restrict__ bar)
{
    __shared__ bf8 hTl[128 * 64];                        // 128 KB swizzled hT slice
    __shared__ float h2s[512], phis[128], es[512], red[256];

    const int bid = blockIdx.x, tid = threadIdx.x;
    const int lane = tid & 63, w = tid >> 6;
    const int mr = lane & 15, quad = lane >> 4;
    const bool isA = bid < 128;
    // attention role: co-locate the 4 dch blocks of one ab on one XCD (bid%8)
    const int ab = (bid & 7) * 8 + ((bid >> 3) & 7), dch = bid >> 6;

    // ---- prologue: W rows -> registers ----
    bf8 wreg[32];
    {
        const __hip_bfloat16* Wg = isA ? W1 : W2;
        const int m0 = (bid & 127) * 16;
        const bf8* src = (const bf8*)(Wg + (size_t)(m0 + mr) * KX) + quad;
#pragma unroll
        for (int ko = 0; ko < 32; ++ko) wreg[ko] = src[ko * 4];
    }
    // ---- prologue: hT slice -> LDS (swizzled) ----
    {
        const bf8* src = (const bf8*)hT + ((size_t)ab * SD + dch * 128) * 64;
        for (int it = 0; it < 32; ++it) {
            int gidx = it * 256 + tid;                   // 0..8191
            int d = gidx >> 6, g = gidx & 63;
            hTl[d * 64 + (g ^ (d & 7))] = src[gidx];
        }
    }
    __syncthreads();

    const int dl = (bid & 127) * 4 + quad;   // this thread's hidden index d
    const int bb = w * 16 + mr;              // this thread's batch
    const f4 biasv = isA ? ((const f4*)b1v)[dl] : ((const f4*)b2v)[dl];
    const int* xrow = xtok + bb * NS;

    float cr = 0.f;                          // persistent cell state
    f4 accP = {0, 0, 0, 0};                  // recurrent partial; h1(-1)=0 => 0
    unsigned bt = 0;

    for (int t = 0; t < NS; ++t) {
        __hip_bfloat16* X1c = X1base + (size_t)t * BB * KX;
        __hip_bfloat16* X1n = X1c + (size_t)BB * KX;
        __hip_bfloat16* X2c = X2base + (size_t)t * BB * KX;
        __hip_bfloat16* X2n = X2c + (size_t)BB * KX;

        // ---- slot 1: LSTM0 finish / LSTM1 recurrent prefetch ----
        if (isA) {
            f4 wo = ((const f4*)woh)[(size_t)xrow[t] * 512 + dl];       // onehot column
            f4 acc = gemm16r<0>(X1c + (size_t)bb * KX, quad, wreg, accP);
            acc.x += biasv.x + wo.x; acc.y += biasv.y + wo.y;
            acc.z += biasv.z + wo.z; acc.w += biasv.w + wo.w;
            float cn = sigm(acc.y) * cr + sigm(acc.x) * tanhf(acc.z);
            float hn = sigm(acc.w) * tanhf(cn);
            cr = cn;
            st_sc(X2c + (size_t)bb * KX + dl, hn);          // h1 -> LSTM1 input
            st_sc(X1n + (size_t)bb * KX + 512 + dl, hn);    // h1 -> next-step recurrent
        } else {
            f4 z = {0, 0, 0, 0};
            accP = gemm16r<16>(X2c + (size_t)bb * KX, quad, wreg, z);   // h2(t-1) partial
        }
        gsync(bar, bt += 256);

        // ---- slot 2: LSTM1 finish / LSTM0 recurrent prefetch ----
        if (isA) {
            f4 z = {0, 0, 0, 0};
            accP = gemm16r<16>(X1n + (size_t)bb * KX, quad, wreg, z);   // h1(t) for t+1
        } else {
            f4 acc = gemm16r<0>(X2c + (size_t)bb * KX, quad, wreg, accP);
            acc.x += biasv.x; acc.y += biasv.y; acc.z += biasv.z; acc.w += biasv.w;
            float cn = sigm(acc.y) * cr + sigm(acc.x) * tanhf(acc.z);
            float hn = sigm(acc.w) * tanhf(cn);
            cr = cn;
            st_sc(X2n + (size_t)bb * KX + 512 + dl, hn);                // h2 recurrent
            scb[((size_t)bb * NS + t) * 1024 + dl] = __hip_bfloat16(hn); // projection in
        }
        gsync(bar, bt += 256);

        // ---- slot 3: attention (all 256 blocks as (ab, dch)) ----
        {
            if (tid < 64) {                 // h2(t): fresh-address normal load
                bf8 v = *((const bf8*)(X2n + (size_t)ab * KX + 512) + tid);
#pragma unroll
                for (int j = 0; j < 8; ++j) h2s[tid * 8 + j] = b2f(v[j]);
            }
            __syncthreads();

            // phi[a] = h2 . Wphi[a] + bphi[a];  4 lanes/row (L2-hot read-only)
            {
                int al = tid & 3;
#pragma unroll
                for (int pass = 0; pass < 2; ++pass) {
                    int a = pass * 64 + (tid >> 2);
                    const bf8* wr = (const bf8*)(Wphib + (size_t)a * 512) + al;
                    float acc = 0.f;
#pragma unroll
                    for (int i = 0; i < 16; ++i) {
                        bf8 wv = wr[i * 4];
                        const float* hp2 = h2s + i * 32 + al * 8;
#pragma unroll
                        for (int j = 0; j < 8; ++j) acc += hp2[j] * b2f(wv[j]);
                    }
                    acc += __shfl_xor(acc, 1);
                    acc += __shfl_xor(acc, 2);
                    if (al == 0) phis[a] = acc + bphi[a];
                }
            }
            __syncthreads();

            // e[t'] = phi . psi[b][t']
            {
                int al = tid & 3;
#pragma unroll
                for (int pass = 0; pass < 8; ++pass) {
                    int tt = pass * 64 + (tid >> 2);
                    const bf8* pr = (const bf8*)(psib + ((size_t)ab * TT + tt) * 128) + al;
                    float acc = 0.f;
#pragma unroll
                    for (int i = 0; i < 4; ++i) {
                        bf8 pv = pr[i * 4];
                        const float* ph = phis + i * 32 + al * 8;
#pragma unroll
                        for (int j = 0; j < 8; ++j) acc += ph[j] * b2f(pv[j]);
                    }
                    acc += __shfl_xor(acc, 1);
                    acc += __shfl_xor(acc, 2);
                    if (al == 0) es[tt] = acc;
                }
            }
            __syncthreads();

            // softmax (unnormalized; fold 1/sum into ctx)
            red[tid] = fmaxf(es[tid], es[tid + 256]);
            __syncthreads();
            for (int st = 128; st > 0; st >>= 1) {
                if (tid < st) red[tid] = fmaxf(red[tid], red[tid + st]);
                __syncthreads();
            }
            float mx = red[0];
            __syncthreads();
            float e0 = expf(es[tid] - mx), e1 = expf(es[tid + 256] - mx);
            es[tid] = e0; es[tid + 256] = e1;
            red[tid] = e0 + e1;
            __syncthreads();
            for (int st = 128; st > 0; st >>= 1) {
                if (tid < st) red[tid] += red[tid + st];
                __syncthreads();
            }
            float inv = 1.0f / red[0];
            __syncthreads();

            // ctx[d] from LDS-resident hT slice (swizzled reads)
            {
                int d = tid & 127, th = tid >> 7;
                const float* ep = es + th * 256;
                const int rb = d * 64, g0 = th * 32, sw = d & 7;
                float a0 = 0.f, a1 = 0.f, a2 = 0.f, a3 = 0.f;
#pragma unroll
                for (int i = 0; i < 32; i += 4) {
                    bf8 v0 = hTl[rb + ((g0 + i)     ^ sw)];
                    bf8 v1 = hTl[rb + ((g0 + i + 1) ^ sw)];
                    bf8 v2 = hTl[rb + ((g0 + i + 2) ^ sw)];
                    bf8 v3 = hTl[rb + ((g0 + i + 3) ^ sw)];
#pragma unroll
                    for (int j = 0; j < 8; ++j) {
                        a0 += ep[i * 8 + j]      * b2f(v0[j]);
                        a1 += ep[i * 8 + 8 + j]  * b2f(v1[j]);
                        a2 += ep[i * 8 + 16 + j] * b2f(v2[j]);
                        a3 += ep[i * 8 + 24 + j] * b2f(v3[j]);
                    }
                }
                float acc = (a0 + a1) + (a2 + a3);
                red[tid] = acc;
                __syncthreads();
                if (th == 0) {
                    float v = (acc + red[tid + 128]) * inv;
                    st_sc(X1n + (size_t)ab * KX + dch * 128 + d, v);
                    scb[((size_t)ab * NS + t) * 1024 + 512 + dch * 128 + d] = __hip_bfloat16(v);
                }
            }
        }
        gsync(bar, bt += 256);
    }
}

// ---------------- fallback per-step kernels (plain mem ops; kernel-boundary
// coherence). Only used if cooperative launch is rejected. ----------------
__global__ __launch_bounds__(256) void fb_lstm0_kernel(
    const __hip_bfloat16* __restrict__ W1, const __hip_bfloat16* __restrict__ X1c,
    __hip_bfloat16* X1n, __hip_bfloat16* X2c, float* __restrict__ c1,
    const float* __restrict__ b1v, const float* __restrict__ woh,
    const int* __restrict__ xtok, int t)
{
    __shared__ __hip_bfloat16 Wlds[32 * 512];
    const int bid = blockIdx.x, tid = threadIdx.x;
    const int lane = tid & 63, w = tid >> 6;
    const int mr = lane & 15, quad = lane >> 4;
    {
        const bf8* src = (const bf8*)(W1 + (size_t)(bid * 16 + mr) * KX) + quad;
        bf8* dstl = (bf8*)Wlds;
        for (int ko = w; ko < 32; ko += 4) dstl[ko * 64 + lane] = src[ko * 4];
    }
    __syncthreads();
    const bf8* Wl = (const bf8*)Wlds + lane;
    const int dl = bid * 4 + quad, bb = w * 16 + mr;
    const bf8* Bq = (const bf8*)(X1c + (size_t)bb * KX) + quad;
    f4 acc = {0, 0, 0, 0};
#pragma unroll
    for (int ko = 0; ko < 32; ++ko) acc = MFMA16(Wl[ko * 64], Bq[ko * 4], acc);
    f4 bv = ((const f4*)b1v)[dl];
    f4 wo = ((const f4*)woh)[(size_t)xtok[bb * NS + t] * 512 + dl];
    acc.x += bv.x + wo.x; acc.y += bv.y + wo.y; acc.z += bv.z + wo.z; acc.w += bv.w + wo.w;
    int ci = dl * 64 + bb;
    float cn = sigm(acc.y) * c1[ci] + sigm(acc.x) * tanhf(acc.z);
    float hn = sigm(acc.w) * tanhf(cn);
    c1[ci] = cn;
    X2c[(size_t)bb * KX + dl] = __hip_bfloat16(hn);
    X1n[(size_t)bb * KX + 512 + dl] = __hip_bfloat16(hn);
}

__global__ __launch_bounds__(256) void fb_lstm1_kernel(
    const __hip_bfloat16* __restrict__ W2, const __hip_bfloat16* __restrict__ X2c,
    __hip_bfloat16* X2n, __hip_bfloat16* scb, float* __restrict__ c2,
    const float* __restrict__ b2v, int t)
{
    __shared__ __hip_bfloat16 Wlds[32 * 512];
    const int bid = blockIdx.x, tid = threadIdx.x;
    const int lane = tid & 63, w = tid >> 6;
    const int mr = lane & 15, quad = lane >> 4;
    {
        const bf8* src = (const bf8*)(W2 + (size_t)(bid * 16 + mr) * KX) + quad;
        bf8* dstl = (bf8*)Wlds;
        for (int ko = w; ko < 32; ko += 4) dstl[ko * 64 + lane] = src[ko * 4];
    }
    __syncthreads();
    const bf8* Wl = (const bf8*)Wlds + lane;
    const int dl = bid * 4 + quad, bb = w * 16 + mr;
    const bf8* Bq = (const bf8*)(X2c + (size_t)bb * KX) + quad;
    f4 acc = {0, 0, 0, 0};
#pragma unroll
    for (int ko = 0; ko < 32; ++ko) acc = MFMA16(Wl[ko * 64], Bq[ko * 4], acc);
    f4 bv = ((const f4*)b2v)[dl];
    acc.x += bv.x; acc.y += bv.y; acc.z += bv.z; acc.w += bv.w;
    int ci = dl * 64 + bb;
    float cn = sigm(acc.y) * c2[ci] + sigm(acc.x) * tanhf(acc.z);
    float hn = sigm(acc.w) * tanhf(cn);
    c2[ci] = cn;
    X2n[(size_t)bb * KX + 512 + dl] = __hip_bfloat16(hn);
    scb[((size_t)bb * NS + t) * 1024 + dl] = __hip_bfloat16(hn);
}

__global__ __launch_bounds__(256) void fb_attn_kernel(
    const __hip_bfloat16* __restrict__ X2n, const __hip_bfloat16* __restrict__ Wphib,
    const float* __restrict__ bphi, const __hip_bfloat16* __restrict__ psib,
    const __hip_bfloat16* __restrict__ hT,
    __hip_bfloat16* X1n, __hip_bfloat16* scb, int t)
{
    __shared__ float h2s[512], phis[128], es[512], red[256];
    int b = blockIdx.x >> 2, dch = blockIdx.x & 3;
    int tid = threadIdx.x;
    if (tid < 64) {
        bf8 v = *((const bf8*)(X2n + (size_t)b * KX + 512) + tid);
#pragma unroll
        for (int j = 0; j < 8; ++j) h2s[tid * 8 + j] = b2f(v[j]);
    }
    __syncthreads();
    {
        int al = tid & 3;
#pragma unroll
        for (int pass = 0; pass < 2; ++pass) {
            int a = pass * 64 + (tid >> 2);
            const bf8* wr = (const bf8*)(Wphib + (size_t)a * 512) + al;
            float acc = 0.f;
#pragma unroll
            for (int i = 0; i < 16; ++i) {
                bf8 wv = wr[i * 4];
                const float* hp2 = h2s + i * 32 + al * 8;
#pragma unroll
                for (int j = 0; j < 8; ++j) acc += hp2[j] * b2f(wv[j]);
            }
            acc += __shfl_xor(acc, 1);
            acc += __shfl_xor(acc, 2);
            if (al == 0) phis[a] = acc + bphi[a];
        }
    }
    __syncthreads();
    {
        int al = tid & 3;
#pragma unroll
        for (int pass = 0; pass < 8; ++pass) {
            int tt = pass * 64 + (tid >> 2);
            const bf8* pr = (const bf8*)(psib + ((size_t)b * TT + tt) * 128) + al;
            float acc = 0.f;
#pragma unroll
            for (int i = 0; i < 4; ++i) {
                bf8 pv = pr[i * 4];
                const float* ph = phis + i * 32 + al * 8;
#pragma unroll
                for (int j = 0; j < 8; ++j) acc += ph[j] * b2f(pv[j]);
            }
            acc += __shfl_xor(acc, 1);
            acc += __shfl_xor(acc, 2);
            if (al == 0) es[tt] = acc;
        }
    }
    __syncthreads();
    red[tid] = fmaxf(es[tid], es[tid + 256]);
    __syncthreads();
    for (int st = 128; st > 0; st >>= 1) {
        if (tid < st) red[tid] = fmaxf(red[tid], red[tid + st]);
        __syncthreads();
    }
    float mx = red[0];
    __syncthreads();
    float e0 = expf(es[tid] - mx), e1 = expf(es[tid + 256] - mx);
    es[tid] = e0; es[tid + 256] = e1;
    red[tid] = e0 + e1;
    __syncthreads();
    for (int st = 128; st > 0; st >>= 1) {
        if (tid < st) red[tid] += red[tid + st];
        __syncthreads();
    }
    float inv = 1.0f / red[0];
    __syncthreads();
    {
        int d = dch * 128 + (tid & 127), th = tid >> 7;
        const bf8* hp = (const bf8*)hT + ((size_t)b * SD + d) * 64 + th * 32;
        const float* ep = es + th * 256;
        float a0 = 0.f, a1 = 0.f, a2 = 0.f, a3 = 0.f;
#pragma unroll
        for (int i = 0; i < 32; i += 4) {
            bf8 v0 = hp[i], v1 = hp[i + 1], v2 = hp[i + 2], v3 = hp[i + 3];
#pragma unroll
            for (int j = 0; j < 8; ++j) {
                a0 += ep[i * 8 + j]      * b2f(v0[j]);
                a1 += ep[i * 8 + 8 + j]  * b2f(v1[j]);
                a2 += ep[i * 8 + 16 + j] * b2f(v2[j]);
                a3 += ep[i * 8 + 24 + j] * b2f(v3[j]);
            }
        }
        float acc = (a0 + a1) + (a2 + a3);
        red[tid] = acc;
        __syncthreads();
        if (th == 0) {
            float v = (acc + red[tid + 128]) * inv;
            X1n[(size_t)b * KX + d] = __hip_bfloat16(v);
            scb[((size_t)b * NS + t) * 1024 + 512 + d] = __hip_bfloat16(v);
        }
    }
}

// ---------------- psi GEMM: psibf[b*512+t][128] = hbf @ Wpsi^T + bpsi ----------------
__global__ __launch_bounds__(256) void psi_gemm_kernel(
    const __hip_bfloat16* __restrict__ A,   // hbf [32768][512]
    const __hip_bfloat16* __restrict__ Bw,  // Wpsibf [128][512]
    const float* __restrict__ bias,
    __hip_bfloat16* __restrict__ C)         // [32768][128]
{
    int lane = threadIdx.x & 63, wave = threadIdx.x >> 6;
    int m0 = (blockIdx.x * 4 + wave) * 16;
    int mr = lane & 15, quad = lane >> 4;
    const bf8* Ar = (const bf8*)(A + (size_t)(m0 + mr) * 512 + quad * 8);
    f4 acc[8] = {};
    for (int k0 = 0; k0 < 512; k0 += 32) {
        int ko = k0 >> 3;
        bf8 a = Ar[ko];
#pragma unroll
        for (int nf = 0; nf < 8; ++nf) {
            const bf8* Br = (const bf8*)(Bw + (size_t)(nf * 16 + mr) * 512 + quad * 8);
            acc[nf] = MFMA16(a, Br[ko], acc[nf]);
        }
    }
#pragma unroll
    for (int nf = 0; nf < 8; ++nf) {
        int n = nf * 16 + mr;
        float bs = bias[n];
#pragma unroll
        for (int r = 0; r < 4; ++r) {
            int m = m0 + quad * 4 + r;
            C[(size_t)m * 128 + n] = __hip_bfloat16(acc[nf][r] + bs);
        }
    }
}

// ---------------- final projection: out[b*128+t][64] = scbf @ Wcd^T + bcd ----------------
__global__ __launch_bounds__(256) void out_gemm_kernel(
    const __hip_bfloat16* __restrict__ A,   // scbf [8192][1024]
    const __hip_bfloat16* __restrict__ Bw,  // Wcdbf [64][1024]
    const float* __restrict__ bias,
    float* __restrict__ C)                  // [8192][64]
{
    int lane = threadIdx.x & 63, wave = threadIdx.x >> 6;
    int m0 = (blockIdx.x * 4 + wave) * 16;
    int mr = lane & 15, quad = lane >> 4;
    const bf8* Ar = (const bf8*)(A + (size_t)(m0 + mr) * 1024 + quad * 8);
    f4 acc[4] = {};
    for (int k0 = 0; k0 < 1024; k0 += 32) {
        int ko = k0 >> 3;
        bf8 a = Ar[ko];
#pragma unroll
        for (int nf = 0; nf < 4; ++nf) {
            const bf8* Br = (const bf8*)(Bw + (size_t)(nf * 16 + mr) * 1024 + quad * 8);
            acc[nf] = MFMA16(a, Br[ko], acc[nf]);
        }
    }
#pragma unroll
    for (int nf = 0; nf < 4; ++nf) {
        int n = nf * 16 + mr;
        float bs = bias[n];
#pragma unroll
        for (int r = 0; r < 4; ++r) {
            int m = m0 + quad * 4 + r;
            C[(size_t)m * 64 + n] = acc[nf][r] + bs;
        }
    }
}

extern "C" void kernel_launch(void* const* d_in, const int* in_sizes, int n_in,
                              void* d_out, int out_size, void* d_ws, size_t ws_size,
                              hipStream_t stream)
{
    const int*   x    = (const int*)  d_in[0];
    const float* h    = (const float*)d_in[1];
    const float* Wih0 = (const float*)d_in[2];
    const float* Whh0 = (const float*)d_in[3];
    const float* bih0 = (const float*)d_in[4];
    const float* bhh0 = (const float*)d_in[5];
    const float* Wih1 = (const float*)d_in[6];
    const float* Whh1 = (const float*)d_in[7];
    const float* bih1 = (const float*)d_in[8];
    const float* bhh1 = (const float*)d_in[9];
    const float* Wphi = (const float*)d_in[10];
    const float* bphi = (const float*)d_in[11];
    const float* Wpsi = (const float*)d_in[12];
    const float* bpsi = (const float*)d_in[13];
    const float* Wcd  = (const float*)d_in[14];
    const float* bcd  = (const float*)d_in[15];
    float* out = (float*)d_out;

    char* p = (char*)d_ws;
    __hip_bfloat16* hbf    = (__hip_bfloat16*)p; p += (size_t)BB * TT * SD * 2;   // 32 MB (hbf, then hT)
    __hip_bfloat16* psibf  = (__hip_bfloat16*)p; p += (size_t)BB * TT * ATT * 2;  // 8 MB
    __hip_bfloat16* scbf   = (__hip_bfloat16*)p; p += (size_t)BB * NS * 1024 * 2; // 16 MB
    __hip_bfloat16* W1aug  = (__hip_bfloat16*)p; p += (size_t)2048 * KX * 2;      // 4 MB
    __hip_bfloat16* W2aug  = (__hip_bfloat16*)p; p += (size_t)2048 * KX * 2;      // 4 MB
    __hip_bfloat16* Wphib  = (__hip_bfloat16*)p; p += (size_t)ATT * SD * 2;
    __hip_bfloat16* Wpsib  = (__hip_bfloat16*)p; p += (size_t)ATT * SD * 2;
    __hip_bfloat16* Wcdb   = (__hip_bfloat16*)p; p += (size_t)NC * 1024 * 2;
    // per-step X buffers: fresh addresses each step => L2-cacheable reads
    __hip_bfloat16* X1base = (__hip_bfloat16*)p; p += (size_t)(NS + 1) * BB * KX * 2;  // 16.5 MB
    __hip_bfloat16* X2base = (__hip_bfloat16*)p; p += (size_t)(NS + 1) * BB * KX * 2;  // 16.5 MB
    float* b1v = (float*)p; p += 512 * 4 * 4;
    float* b2v = (float*)p; p += 512 * 4 * 4;
    float* woh = (float*)p; p += (size_t)64 * 512 * 4 * 4;   // 512 KB
    float* c1  = (float*)p; p += (size_t)SD * BB * 4;
    float* c2  = (float*)p; p += (size_t)SD * BB * 4;
    unsigned* bar = (unsigned*)p; p += 512 * 4;              // 8 striped counters

    // ---- one-time prep ----
    f2b_kernel<<<16384, 256, 0, stream>>>(h, hbf, BB * TT * SD);
    f2b_kernel<<<64, 256, 0, stream>>>(Wphi, Wphib, ATT * SD);
    f2b_kernel<<<64, 256, 0, stream>>>(Wpsi, Wpsib, ATT * SD);
    f2b_kernel<<<64, 256, 0, stream>>>(Wcd, Wcdb, NC * 1024);
    prep_w1_kernel<<<(2048 * KX + 255) / 256, 256, 0, stream>>>(Wih0, Whh0, W1aug);
    prep_w2_kernel<<<(2048 * KX + 255) / 256, 256, 0, stream>>>(Wih1, Whh1, W2aug);
    prep_misc_kernel<<<(64 * 512 + 255) / 256, 256, 0, stream>>>(Wih0, bih0, bhh0, bih1, bhh1,
                                                                 b1v, b2v, woh);
    init_kernel<<<(64 * KX + 255) / 256, 256, 0, stream>>>(h, X1base, X2base, c1, c2, bar);
    psi_gemm_kernel<<<512, 256, 0, stream>>>(hbf, Wpsib, bpsi, psibf);
    transpose_h_kernel<<<4096, 256, 0, stream>>>(h, hbf);   // overwrite hbf with hT [b][d][t]
    __hip_bfloat16* hT = hbf;

    // ---- persistent decode ----
    const __hip_bfloat16 *a0 = W1aug, *a1 = W2aug, *a2 = Wphib;
    const float* a3 = bphi;
    const __hip_bfloat16 *a4 = psibf, *a5 = hT;
    __hip_bfloat16 *a6 = X1base, *a7 = X2base, *a8 = scbf;
    const int* a9 = x;
    const float *a10 = b1v, *a11 = b2v, *a12 = woh;
    unsigned* a13 = bar;
    void* args[14] = {&a0, &a1, &a2, &a3, &a4, &a5, &a6, &a7,
                      &a8, &a9, &a10, &a11, &a12, &a13};
    hipError_t ce = hipLaunchCooperativeKernel((const void*)decode_kernel,
                                               dim3(256), dim3(256), args, 0, stream);
    if (ce != hipSuccess) {
        (void)hipGetLastError();
        for (int t = 0; t < NS; ++t) {
            __hip_bfloat16* X1c = X1base + (size_t)t * BB * KX;
            __hip_bfloat16* X1n = X1c + (size_t)BB * KX;
            __hip_bfloat16* X2c = X2base + (size_t)t * BB * KX;
            __hip_bfloat16* X2n = X2c + (size_t)BB * KX;
            fb_lstm0_kernel<<<128, 256, 0, stream>>>(W1aug, X1c, X1n, X2c, c1, b1v, woh, x, t);
            fb_lstm1_kernel<<<128, 256, 0, stream>>>(W2aug, X2c, X2n, scbf, c2, b2v, t);
            fb_attn_kernel<<<256, 256, 0, stream>>>(X2n, Wphib, bphi, psibf, hT, X1n, scbf, t);
        }
    }
    // output projection
    out_gemm_kernel<<<128, 256, 0, stream>>>(scbf, Wcdb, bcd, out);
}

// Round 5
// 2693.552 us; speedup vs baseline: 9.9575x; 1.4388x over previous
//
#include <hip/hip_runtime.h>
#include <hip/hip_bf16.h>
#include <math.h>

#define BB 64      // batch
#define TT 512     // encoder time
#define NS 128     // decode steps
#define SD 512     // lstm hidden
#define ATT 128
#define NC 64      // num classes
#define KX 1024    // X row: 512 ctx/h1 + 512 rec

typedef __attribute__((ext_vector_type(8))) short bf8;   // 8 bf16 (4 VGPRs)
typedef __attribute__((ext_vector_type(4))) float f4;

__device__ __forceinline__ float sigm(float x) { return 1.0f / (1.0f + expf(-x)); }
__device__ __forceinline__ float b2f(short s) {
    union { unsigned u; float f; } c; c.u = ((unsigned)(unsigned short)s) << 16; return c.f;
}
#define MFMA16(a, b, c) __builtin_amdgcn_mfma_f32_16x16x32_bf16((a), (b), (c), 0, 0, 0)

// ---- coherent (L3-point) helpers: sc0 sc1 stores write through to L3; sc loads
// bypass L1/L2. X data uses per-step fresh buffers so X READS are normal cached. ----
__device__ __forceinline__ void st_sc(__hip_bfloat16* p, float val) {
    __hip_bfloat16 hb(val);
    unsigned short bits; __builtin_memcpy(&bits, &hb, 2);
    unsigned v = bits;
    asm volatile("global_store_short %0, %1, off sc0 sc1" :: "v"(p), "v"(v) : "memory");
}
__device__ __forceinline__ void st_u32_sc(unsigned* p, unsigned v) {
    asm volatile("global_store_dword %0, %1, off sc0 sc1" :: "v"(p), "v"(v) : "memory");
}
__device__ __forceinline__ unsigned ld_u32_sc(const unsigned* p) {
    unsigned v;
    asm volatile("global_load_dword %0, %1, off sc0 sc1\ns_waitcnt vmcnt(0)"
                 : "=v"(v) : "v"(p) : "memory");
    return v;
}

// ---- contention-free grid barrier ----
// arrival: each block writes its OWN 128B line (no atomics, no shared polling).
// block 0: 256 threads poll 256 DISTINCT lines, then release via 8 striped lines
// (32 pollers/line). All flags monotonic tickets; __syncthreads drains vmcnt
// (data write-through acks) before arrival is published.
__device__ __forceinline__ void gsync(unsigned* arrv, unsigned* rel, unsigned tk)
{
    __syncthreads();
    if (blockIdx.x == 0) {
        if (threadIdx.x > 0 && threadIdx.x < 256) {
            while (ld_u32_sc(arrv + threadIdx.x * 32) < tk)
                __builtin_amdgcn_s_sleep(2);
        }
        __syncthreads();
        if (threadIdx.x < 8)
            st_u32_sc(rel + threadIdx.x * 32, tk);
    } else {
        if (threadIdx.x == 0) {
            st_u32_sc(arrv + blockIdx.x * 32, tk);
            while (ld_u32_sc(rel + (blockIdx.x & 7) * 32) < tk)
                __builtin_amdgcn_s_sleep(2);
        }
        __syncthreads();
    }
}

// 16-chunk MFMA GEMM over one X row; NORMAL cached loads (per-step-fresh
// addresses guarantee coherence); W fragments from registers.
template<int BASE>
__device__ __forceinline__ f4 gemm16r(const __hip_bfloat16* Xrow, int quad,
                                      const bf8 (&wreg)[32], f4 acc)
{
    const bf8* Bq = (const bf8*)Xrow + quad;
    bf8 r[16];
#pragma unroll
    for (int i = 0; i < 16; ++i) r[i] = Bq[(BASE + i) * 4];
#pragma unroll
    for (int i = 0; i < 16; ++i) acc = MFMA16(wreg[BASE + i], r[i], acc);
    return acc;
}

// ---------------- fp32 -> bf16 convert (vec4) ----------------
__global__ void f2b_kernel(const float* __restrict__ src, __hip_bfloat16* __restrict__ dst, int n)
{
    int i = (blockIdx.x * blockDim.x + threadIdx.x) * 4;
    if (i < n) {
        float4 v = *(const float4*)(src + i);
        dst[i]     = __hip_bfloat16(v.x);
        dst[i + 1] = __hip_bfloat16(v.y);
        dst[i + 2] = __hip_bfloat16(v.z);
        dst[i + 3] = __hip_bfloat16(v.w);
    }
}

// ---------------- transpose h: [b][t][d] f32 -> hT [b][d][t] bf16 ----------------
__global__ __launch_bounds__(256) void transpose_h_kernel(const float* __restrict__ h,
                                                          __hip_bfloat16* __restrict__ hT)
{
    int bidx = blockIdx.x;
    int b = bidx >> 6, tt0 = ((bidx >> 3) & 7) * 64, dd0 = (bidx & 7) * 64;
    __shared__ __hip_bfloat16 tile[64][65];
    int dd = threadIdx.x & 63, r4 = threadIdx.x >> 6;
#pragma unroll
    for (int i = 0; i < 64; i += 4) {
        int tl = i + r4;
        tile[tl][dd] = __hip_bfloat16(h[((size_t)b * TT + tt0 + tl) * SD + dd0 + dd]);
    }
    __syncthreads();
#pragma unroll
    for (int i = 0; i < 64; i += 4) {
        int dl = i + r4;
        hT[((size_t)b * SD + dd0 + dl) * TT + tt0 + dd] = tile[dd][dl];
    }
}

// ---------------- LSTM0 weights [2048][1024]: ctx cols | rec cols ----------------
__global__ void prep_w1_kernel(const float* __restrict__ Wih, const float* __restrict__ Whh,
                               __hip_bfloat16* __restrict__ W)
{
    int idx = blockIdx.x * blockDim.x + threadIdx.x;   // 2048*1024
    if (idx >= 2048 * KX) return;
    int np = idx >> 10, kk = idx & 1023;
    int q = np & 3, d = np >> 2, j = q * 512 + d;
    float v = (kk < 512) ? Wih[j * 576 + 64 + kk] : Whh[j * 512 + kk - 512];
    W[idx] = __hip_bfloat16(v);
}

// ---------------- LSTM1 weights [2048][1024] ----------------
__global__ void prep_w2_kernel(const float* __restrict__ Wih, const float* __restrict__ Whh,
                               __hip_bfloat16* __restrict__ W)
{
    int idx = blockIdx.x * blockDim.x + threadIdx.x;
    if (idx >= 2048 * KX) return;
    int np = idx >> 10, kk = idx & 1023;
    int q = np & 3, d = np >> 2, j = q * 512 + d;
    float v = (kk < 512) ? Wih[j * 512 + kk] : Whh[j * 512 + kk - 512];
    W[idx] = __hip_bfloat16(v);
}

// ---------------- biases (gate-interleaved f4) + per-token Wih0 column gather ----------------
__global__ void prep_misc_kernel(const float* __restrict__ Wih0,
                                 const float* __restrict__ bih0, const float* __restrict__ bhh0,
                                 const float* __restrict__ bih1, const float* __restrict__ bhh1,
                                 float* __restrict__ b1v, float* __restrict__ b2v,
                                 float* __restrict__ woh)   // [64 tok][512 d] f4
{
    int idx = blockIdx.x * blockDim.x + threadIdx.x;   // 64*512
    if (idx >= 64 * 512) return;
    int tok = idx >> 9, d = idx & 511;
    float4 w;
    w.x = Wih0[(0 * 512 + d) * 576 + tok];
    w.y = Wih0[(1 * 512 + d) * 576 + tok];
    w.z = Wih0[(2 * 512 + d) * 576 + tok];
    w.w = Wih0[(3 * 512 + d) * 576 + tok];
    ((float4*)woh)[idx] = w;
    if (tok == 0) {
        float4 b1, b2;
        b1.x = bih0[d] + bhh0[d];             b1.y = bih0[512 + d] + bhh0[512 + d];
        b1.z = bih0[1024 + d] + bhh0[1024 + d]; b1.w = bih0[1536 + d] + bhh0[1536 + d];
        b2.x = bih1[d] + bhh1[d];             b2.y = bih1[512 + d] + bhh1[512 + d];
        b2.z = bih1[1024 + d] + bhh1[1024 + d]; b2.w = bih1[1536 + d] + bhh1[1536 + d];
        ((float4*)b1v)[d] = b1;
        ((float4*)b2v)[d] = b2;
    }
}

// ---------------- init: step-0 X buffers, c states, barrier flags ----------------
__global__ void init_kernel(const float* __restrict__ h,
                            __hip_bfloat16* __restrict__ X1_0,
                            __hip_bfloat16* __restrict__ X2_0,
                            float* __restrict__ c1, float* __restrict__ c2,
                            unsigned* __restrict__ bar)
{
    int idx = blockIdx.x * blockDim.x + threadIdx.x;   // 64*1024
    if (idx >= 64 * KX) return;
    int b = idx >> 10, col = idx & 1023;
    __hip_bfloat16 z(0.0f);
    X1_0[idx] = (col < 512) ? __hip_bfloat16(h[(size_t)b * TT * SD + col]) : z;  // ctx0 | h1(-1)=0
    X2_0[idx] = z;                                                               // h2(-1)=0
    if (idx < 512 * 64) { c1[idx] = 0.f; c2[idx] = 0.f; }
    if (idx < 16384) bar[idx] = 0u;
}

// ---------------- persistent decode kernel ----------------
// 256 blocks x 512 threads. Waves 0-3: LSTM role (blocks 0..127: LSTM0 rows,
// 128..255: LSTM1 rows; W tile in registers, cell state in registers).
// All 8 waves: attention slot (phi 1 pass, e 4 passes, shfl softmax, ctx 16 bf8/thread
// from 128 KB LDS-resident swizzled hT slice). Per-step X buffers => cached X reads.
// 3 contention-free grid syncs per step.
__global__ __launch_bounds__(512, 1) void decode_kernel(
    const __hip_bfloat16* __restrict__ W1, const __hip_bfloat16* __restrict__ W2,
    const __hip_bfloat16* __restrict__ Wphib, const float* __restrict__ bphi,
    const __hip_bfloat16* __restrict__ psib, const __hip_bfloat16* __restrict__ hT,
    __hip_bfloat16* X1base, __hip_bfloat16* X2base,
    __hip_bfloat16* scb, const int* __restrict__ xtok,
    const float* __restrict__ b1v, const float* __restrict__ b2v,
    const float* __restrict__ woh, unsigned* __restrict__ bar)
{
    __shared__ bf8 hTl[128 * 64];                        // 128 KB swizzled hT slice
    __shared__ float h2s[512], phis[128], es[512], red[512], wred[16];

    const int bid = blockIdx.x, tid = threadIdx.x;
    const int lane = tid & 63, w = tid >> 6;
    const int mr = lane & 15, quad = lane >> 4;
    const bool isA = bid < 128;
    // attention role: co-locate the 4 dch blocks of one ab on one XCD (bid%8)
    const int ab = (bid & 7) * 8 + ((bid >> 3) & 7), dch = bid >> 6;

    unsigned* arrv = bar;
    unsigned* rel  = bar + 256 * 32;

    // ---- prologue: W rows -> registers (LSTM waves only) ----
    bf8 wreg[32];
    if (tid < 256) {
        const __hip_bfloat16* Wg = isA ? W1 : W2;
        const int m0 = (bid & 127) * 16;
        const bf8* src = (const bf8*)(Wg + (size_t)(m0 + mr) * KX) + quad;
#pragma unroll
        for (int ko = 0; ko < 32; ++ko) wreg[ko] = src[ko * 4];
    }
    // ---- prologue: hT slice -> LDS (swizzled) ----
    {
        const bf8* src = (const bf8*)hT + ((size_t)ab * SD + dch * 128) * 64;
        for (int it = 0; it < 16; ++it) {
            int gidx = it * 512 + tid;                   // 0..8191
            int d = gidx >> 6, g = gidx & 63;
            hTl[d * 64 + (g ^ (d & 7))] = src[gidx];
        }
    }
    __syncthreads();

    const int dl = (bid & 127) * 4 + quad;   // this thread's hidden index d
    const int bb = w * 16 + mr;              // this thread's batch (tid<256)
    const f4 biasv = isA ? ((const f4*)b1v)[dl & 511] : ((const f4*)b2v)[dl & 511];
    const int* xrow = xtok + (bb & 63) * NS;

    float cr = 0.f;                          // persistent cell state
    f4 accP = {0, 0, 0, 0};                  // recurrent partial; h1(-1)=0 => 0
    unsigned tk = 0;

    for (int t = 0; t < NS; ++t) {
        __hip_bfloat16* X1c = X1base + (size_t)t * BB * KX;
        __hip_bfloat16* X1n = X1c + (size_t)BB * KX;
        __hip_bfloat16* X2c = X2base + (size_t)t * BB * KX;
        __hip_bfloat16* X2n = X2c + (size_t)BB * KX;

        // ---- slot 1: LSTM0 finish / LSTM1 recurrent prefetch ----
        if (tid < 256) {
            if (isA) {
                f4 wo = ((const f4*)woh)[(size_t)xrow[t] * 512 + dl];   // onehot column
                f4 acc = gemm16r<0>(X1c + (size_t)bb * KX, quad, wreg, accP);
                acc.x += biasv.x + wo.x; acc.y += biasv.y + wo.y;
                acc.z += biasv.z + wo.z; acc.w += biasv.w + wo.w;
                float cn = sigm(acc.y) * cr + sigm(acc.x) * tanhf(acc.z);
                float hn = sigm(acc.w) * tanhf(cn);
                cr = cn;
                st_sc(X2c + (size_t)bb * KX + dl, hn);          // h1 -> LSTM1 input
                st_sc(X1n + (size_t)bb * KX + 512 + dl, hn);    // h1 -> next recurrent
            } else {
                f4 z = {0, 0, 0, 0};
                accP = gemm16r<16>(X2c + (size_t)bb * KX, quad, wreg, z);  // h2(t-1) part
            }
        }
        gsync(arrv, rel, ++tk);

        // ---- slot 2: LSTM1 finish / LSTM0 recurrent prefetch ----
        if (tid < 256) {
            if (isA) {
                f4 z = {0, 0, 0, 0};
                accP = gemm16r<16>(X1n + (size_t)bb * KX, quad, wreg, z);  // h1(t) for t+1
            } else {
                f4 acc = gemm16r<0>(X2c + (size_t)bb * KX, quad, wreg, accP);
                acc.x += biasv.x; acc.y += biasv.y; acc.z += biasv.z; acc.w += biasv.w;
                float cn = sigm(acc.y) * cr + sigm(acc.x) * tanhf(acc.z);
                float hn = sigm(acc.w) * tanhf(cn);
                cr = cn;
                st_sc(X2n + (size_t)bb * KX + 512 + dl, hn);                 // h2 recurrent
                scb[((size_t)bb * NS + t) * 1024 + dl] = __hip_bfloat16(hn); // projection in
            }
        }
        gsync(arrv, rel, ++tk);

        // ---- slot 3: attention, 512 threads (all blocks as (ab, dch)) ----
        {
            if (tid < 64) {                 // h2(t): fresh-address normal load
                bf8 v = *((const bf8*)(X2n + (size_t)ab * KX + 512) + tid);
#pragma unroll
                for (int j = 0; j < 8; ++j) h2s[tid * 8 + j] = b2f(v[j]);
            }
            __syncthreads();

            // phi[a] = h2 . Wphi[a] + bphi[a];  4 lanes/row, 1 pass (512 threads)
            {
                int al = tid & 3, a = tid >> 2;
                const bf8* wr = (const bf8*)(Wphib + (size_t)a * 512) + al;
                float acc = 0.f;
#pragma unroll
                for (int i = 0; i < 16; ++i) {
                    bf8 wv = wr[i * 4];
                    const float* hp2 = h2s + i * 32 + al * 8;
#pragma unroll
                    for (int j = 0; j < 8; ++j) acc += hp2[j] * b2f(wv[j]);
                }
                acc += __shfl_xor(acc, 1);
                acc += __shfl_xor(acc, 2);
                if (al == 0) phis[a] = acc + bphi[a];
            }
            __syncthreads();

            // e[t'] = phi . psi[b][t'];  4 passes (512 threads)
            {
                int al = tid & 3;
#pragma unroll
                for (int pass = 0; pass < 4; ++pass) {
                    int tt = pass * 128 + (tid >> 2);
                    const bf8* pr = (const bf8*)(psib + ((size_t)ab * TT + tt) * 128) + al;
                    float acc = 0.f;
#pragma unroll
                    for (int i = 0; i < 4; ++i) {
                        bf8 pv = pr[i * 4];
                        const float* ph = phis + i * 32 + al * 8;
#pragma unroll
                        for (int j = 0; j < 8; ++j) acc += ph[j] * b2f(pv[j]);
                    }
                    acc += __shfl_xor(acc, 1);
                    acc += __shfl_xor(acc, 2);
                    if (al == 0) es[tt] = acc;
                }
            }
            __syncthreads();

            // softmax via wave shfl reduction (3 syncs total)
            float m = es[tid];
#pragma unroll
            for (int s = 1; s < 64; s <<= 1) m = fmaxf(m, __shfl_xor(m, s));
            if (lane == 0) wred[w] = m;
            __syncthreads();
            float mx = wred[0];
#pragma unroll
            for (int i = 1; i < 8; ++i) mx = fmaxf(mx, wred[i]);
            float e0 = expf(es[tid] - mx);
            es[tid] = e0;
            float s0 = e0;
#pragma unroll
            for (int s = 1; s < 64; s <<= 1) s0 += __shfl_xor(s0, s);
            if (lane == 0) wred[8 + w] = s0;
            __syncthreads();                // also publishes es[] = exp values
            float sum = wred[8];
#pragma unroll
            for (int i = 1; i < 8; ++i) sum += wred[8 + i];
            float inv = 1.0f / sum;

            // ctx[d] from LDS-resident hT slice; 4 partials per d (512 threads)
            {
                int d = tid & 127, th = tid >> 7;
                const float* ep = es + th * 128;
                const int rb = d * 64, g0 = th * 16, sw = d & 7;
                float a0 = 0.f, a1 = 0.f, a2 = 0.f, a3 = 0.f;
#pragma unroll
                for (int i = 0; i < 16; i += 4) {
                    bf8 v0 = hTl[rb + ((g0 + i)     ^ sw)];
                    bf8 v1 = hTl[rb + ((g0 + i + 1) ^ sw)];
                    bf8 v2 = hTl[rb + ((g0 + i + 2) ^ sw)];
                    bf8 v3 = hTl[rb + ((g0 + i + 3) ^ sw)];
#pragma unroll
                    for (int j = 0; j < 8; ++j) {
                        a0 += ep[i * 8 + j]      * b2f(v0[j]);
                        a1 += ep[i * 8 + 8 + j]  * b2f(v1[j]);
                        a2 += ep[i * 8 + 16 + j] * b2f(v2[j]);
                        a3 += ep[i * 8 + 24 + j] * b2f(v3[j]);
                    }
                }
                red[tid] = (a0 + a1) + (a2 + a3);
                __syncthreads();
                if (th == 0) {
                    float v = (red[d] + red[d + 128] + red[d + 256] + red[d + 384]) * inv;
                    st_sc(X1n + (size_t)ab * KX + dch * 128 + d, v);
                    scb[((size_t)ab * NS + t) * 1024 + 512 + dch * 128 + d] = __hip_bfloat16(v);
                }
            }
        }
        gsync(arrv, rel, ++tk);
    }
}

// ---------------- fallback per-step kernels (plain mem ops; kernel-boundary
// coherence). Only used if cooperative launch is rejected. ----------------
__global__ __launch_bounds__(256) void fb_lstm0_kernel(
    const __hip_bfloat16* __restrict__ W1, const __hip_bfloat16* __restrict__ X1c,
    __hip_bfloat16* X1n, __hip_bfloat16* X2c, float* __restrict__ c1,
    const float* __restrict__ b1v, const float* __restrict__ woh,
    const int* __restrict__ xtok, int t)
{
    __shared__ __hip_bfloat16 Wlds[32 * 512];
    const int bid = blockIdx.x, tid = threadIdx.x;
    const int lane = tid & 63, w = tid >> 6;
    const int mr = lane & 15, quad = lane >> 4;
    {
        const bf8* src = (const bf8*)(W1 + (size_t)(bid * 16 + mr) * KX) + quad;
        bf8* dstl = (bf8*)Wlds;
        for (int ko = w; ko < 32; ko += 4) dstl[ko * 64 + lane] = src[ko * 4];
    }
    __syncthreads();
    const bf8* Wl = (const bf8*)Wlds + lane;
    const int dl = bid * 4 + quad, bb = w * 16 + mr;
    const bf8* Bq = (const bf8*)(X1c + (size_t)bb * KX) + quad;
    f4 acc = {0, 0, 0, 0};
#pragma unroll
    for (int ko = 0; ko < 32; ++ko) acc = MFMA16(Wl[ko * 64], Bq[ko * 4], acc);
    f4 bv = ((const f4*)b1v)[dl];
    f4 wo = ((const f4*)woh)[(size_t)xtok[bb * NS + t] * 512 + dl];
    acc.x += bv.x + wo.x; acc.y += bv.y + wo.y; acc.z += bv.z + wo.z; acc.w += bv.w + wo.w;
    int ci = dl * 64 + bb;
    float cn = sigm(acc.y) * c1[ci] + sigm(acc.x) * tanhf(acc.z);
    float hn = sigm(acc.w) * tanhf(cn);
    c1[ci] = cn;
    X2c[(size_t)bb * KX + dl] = __hip_bfloat16(hn);
    X1n[(size_t)bb * KX + 512 + dl] = __hip_bfloat16(hn);
}

__global__ __launch_bounds__(256) void fb_lstm1_kernel(
    const __hip_bfloat16* __restrict__ W2, const __hip_bfloat16* __restrict__ X2c,
    __hip_bfloat16* X2n, __hip_bfloat16* scb, float* __restrict__ c2,
    const float* __restrict__ b2v, int t)
{
    __shared__ __hip_bfloat16 Wlds[32 * 512];
    const int bid = blockIdx.x, tid = threadIdx.x;
    const int lane = tid & 63, w = tid >> 6;
    const int mr = lane & 15, quad = lane >> 4;
    {
        const bf8* src = (const bf8*)(W2 + (size_t)(bid * 16 + mr) * KX) + quad;
        bf8* dstl = (bf8*)Wlds;
        for (int ko = w; ko < 32; ko += 4) dstl[ko * 64 + lane] = src[ko * 4];
    }
    __syncthreads();
    const bf8* Wl = (const bf8*)Wlds + lane;
    const int dl = bid * 4 + quad, bb = w * 16 + mr;
    const bf8* Bq = (const bf8*)(X2c + (size_t)bb * KX) + quad;
    f4 acc = {0, 0, 0, 0};
#pragma unroll
    for (int ko = 0; ko < 32; ++ko) acc = MFMA16(Wl[ko * 64], Bq[ko * 4], acc);
    f4 bv = ((const f4*)b2v)[dl];
    acc.x += bv.x; acc.y += bv.y; acc.z += bv.z; acc.w += bv.w;
    int ci = dl * 64 + bb;
    float cn = sigm(acc.y) * c2[ci] + sigm(acc.x) * tanhf(acc.z);
    float hn = sigm(acc.w) * tanhf(cn);
    c2[ci] = cn;
    X2n[(size_t)bb * KX + 512 + dl] = __hip_bfloat16(hn);
    scb[((size_t)bb * NS + t) * 1024 + dl] = __hip_bfloat16(hn);
}

__global__ __launch_bounds__(256) void fb_attn_kernel(
    const __hip_bfloat16* __restrict__ X2n, const __hip_bfloat16* __restrict__ Wphib,
    const float* __restrict__ bphi, const __hip_bfloat16* __restrict__ psib,
    const __hip_bfloat16* __restrict__ hT,
    __hip_bfloat16* X1n, __hip_bfloat16* scb, int t)
{
    __shared__ float h2s[512], phis[128], es[512], red[256];
    int b = blockIdx.x >> 2, dch = blockIdx.x & 3;
    int tid = threadIdx.x;
    if (tid < 64) {
        bf8 v = *((const bf8*)(X2n + (size_t)b * KX + 512) + tid);
#pragma unroll
        for (int j = 0; j < 8; ++j) h2s[tid * 8 + j] = b2f(v[j]);
    }
    __syncthreads();
    {
        int al = tid & 3;
#pragma unroll
        for (int pass = 0; pass < 2; ++pass) {
            int a = pass * 64 + (tid >> 2);
            const bf8* wr = (const bf8*)(Wphib + (size_t)a * 512) + al;
            float acc = 0.f;
#pragma unroll
            for (int i = 0; i < 16; ++i) {
                bf8 wv = wr[i * 4];
                const float* hp2 = h2s + i * 32 + al * 8;
#pragma unroll
                for (int j = 0; j < 8; ++j) acc += hp2[j] * b2f(wv[j]);
            }
            acc += __shfl_xor(acc, 1);
            acc += __shfl_xor(acc, 2);
            if (al == 0) phis[a] = acc + bphi[a];
        }
    }
    __syncthreads();
    {
        int al = tid & 3;
#pragma unroll
        for (int pass = 0; pass < 8; ++pass) {
            int tt = pass * 64 + (tid >> 2);
            const bf8* pr = (const bf8*)(psib + ((size_t)b * TT + tt) * 128) + al;
            float acc = 0.f;
#pragma unroll
            for (int i = 0; i < 4; ++i) {
                bf8 pv = pr[i * 4];
                const float* ph = phis + i * 32 + al * 8;
#pragma unroll
                for (int j = 0; j < 8; ++j) acc += ph[j] * b2f(pv[j]);
            }
            acc += __shfl_xor(acc, 1);
            acc += __shfl_xor(acc, 2);
            if (al == 0) es[tt] = acc;
        }
    }
    __syncthreads();
    red[tid] = fmaxf(es[tid], es[tid + 256]);
    __syncthreads();
    for (int st = 128; st > 0; st >>= 1) {
        if (tid < st) red[tid] = fmaxf(red[tid], red[tid + st]);
        __syncthreads();
    }
    float mx = red[0];
    __syncthreads();
    float e0 = expf(es[tid] - mx), e1 = expf(es[tid + 256] - mx);
    es[tid] = e0; es[tid + 256] = e1;
    red[tid] = e0 + e1;
    __syncthreads();
    for (int st = 128; st > 0; st >>= 1) {
        if (tid < st) red[tid] += red[tid + st];
        __syncthreads();
    }
    float inv = 1.0f / red[0];
    __syncthreads();
    {
        int d = dch * 128 + (tid & 127), th = tid >> 7;
        const bf8* hp = (const bf8*)hT + ((size_t)b * SD + d) * 64 + th * 32;
        const float* ep = es + th * 256;
        float a0 = 0.f, a1 = 0.f, a2 = 0.f, a3 = 0.f;
#pragma unroll
        for (int i = 0; i < 32; i += 4) {
            bf8 v0 = hp[i], v1 = hp[i + 1], v2 = hp[i + 2], v3 = hp[i + 3];
#pragma unroll
            for (int j = 0; j < 8; ++j) {
                a0 += ep[i * 8 + j]      * b2f(v0[j]);
                a1 += ep[i * 8 + 8 + j]  * b2f(v1[j]);
                a2 += ep[i * 8 + 16 + j] * b2f(v2[j]);
                a3 += ep[i * 8 + 24 + j] * b2f(v3[j]);
            }
        }
        float acc = (a0 + a1) + (a2 + a3);
        red[tid] = acc;
        __syncthreads();
        if (th == 0) {
            float v = (acc + red[tid + 128]) * inv;
            X1n[(size_t)b * KX + d] = __hip_bfloat16(v);
            scb[((size_t)b * NS + t) * 1024 + 512 + d] = __hip_bfloat16(v);
        }
    }
}

// ---------------- psi GEMM: psibf[b*512+t][128] = hbf @ Wpsi^T + bpsi ----------------
__global__ __launch_bounds__(256) void psi_gemm_kernel(
    const __hip_bfloat16* __restrict__ A,   // hbf [32768][512]
    const __hip_bfloat16* __restrict__ Bw,  // Wpsibf [128][512]
    const float* __restrict__ bias,
    __hip_bfloat16* __restrict__ C)         // [32768][128]
{
    int lane = threadIdx.x & 63, wave = threadIdx.x >> 6;
    int m0 = (blockIdx.x * 4 + wave) * 16;
    int mr = lane & 15, quad = lane >> 4;
    const bf8* Ar = (const bf8*)(A + (size_t)(m0 + mr) * 512 + quad * 8);
    f4 acc[8] = {};
    for (int k0 = 0; k0 < 512; k0 += 32) {
        int ko = k0 >> 3;
        bf8 a = Ar[ko];
#pragma unroll
        for (int nf = 0; nf < 8; ++nf) {
            const bf8* Br = (const bf8*)(Bw + (size_t)(nf * 16 + mr) * 512 + quad * 8);
            acc[nf] = MFMA16(a, Br[ko], acc[nf]);
        }
    }
#pragma unroll
    for (int nf = 0; nf < 8; ++nf) {
        int n = nf * 16 + mr;
        float bs = bias[n];
#pragma unroll
        for (int r = 0; r < 4; ++r) {
            int m = m0 + quad * 4 + r;
            C[(size_t)m * 128 + n] = __hip_bfloat16(acc[nf][r] + bs);
        }
    }
}

// ---------------- final projection: out[b*128+t][64] = scbf @ Wcd^T + bcd ----------------
__global__ __launch_bounds__(256) void out_gemm_kernel(
    const __hip_bfloat16* __restrict__ A,   // scbf [8192][1024]
    const __hip_bfloat16* __restrict__ Bw,  // Wcdbf [64][1024]
    const float* __restrict__ bias,
    float* __restrict__ C)                  // [8192][64]
{
    int lane = threadIdx.x & 63, wave = threadIdx.x >> 6;
    int m0 = (blockIdx.x * 4 + wave) * 16;
    int mr = lane & 15, quad = lane >> 4;
    const bf8* Ar = (const bf8*)(A + (size_t)(m0 + mr) * 1024 + quad * 8);
    f4 acc[4] = {};
    for (int k0 = 0; k0 < 1024; k0 += 32) {
        int ko = k0 >> 3;
        bf8 a = Ar[ko];
#pragma unroll
        for (int nf = 0; nf < 4; ++nf) {
            const bf8* Br = (const bf8*)(Bw + (size_t)(nf * 16 + mr) * 1024 + quad * 8);
            acc[nf] = MFMA16(a, Br[ko], acc[nf]);
        }
    }
#pragma unroll
    for (int nf = 0; nf < 4; ++nf) {
        int n = nf * 16 + mr;
        float bs = bias[n];
#pragma unroll
        for (int r = 0; r < 4; ++r) {
            int m = m0 + quad * 4 + r;
            C[(size_t)m * 64 + n] = acc[nf][r] + bs;
        }
    }
}

extern "C" void kernel_launch(void* const* d_in, const int* in_sizes, int n_in,
                              void* d_out, int out_size, void* d_ws, size_t ws_size,
                              hipStream_t stream)
{
    const int*   x    = (const int*)  d_in[0];
    const float* h    = (const float*)d_in[1];
    const float* Wih0 = (const float*)d_in[2];
    const float* Whh0 = (const float*)d_in[3];
    const float* bih0 = (const float*)d_in[4];
    const float* bhh0 = (const float*)d_in[5];
    const float* bih1 = (const float*)d_in[8];
    const float* Wih1 = (const float*)d_in[6];
    const float* Whh1 = (const float*)d_in[7];
    const float* bhh1 = (const float*)d_in[9];
    const float* Wphi = (const float*)d_in[10];
    const float* bphi = (const float*)d_in[11];
    const float* Wpsi = (const float*)d_in[12];
    const float* bpsi = (const float*)d_in[13];
    const float* Wcd  = (const float*)d_in[14];
    const float* bcd  = (const float*)d_in[15];
    float* out = (float*)d_out;

    char* p = (char*)d_ws;
    __hip_bfloat16* hbf    = (__hip_bfloat16*)p; p += (size_t)BB * TT * SD * 2;   // 32 MB (hbf, then hT)
    __hip_bfloat16* psibf  = (__hip_bfloat16*)p; p += (size_t)BB * TT * ATT * 2;  // 8 MB
    __hip_bfloat16* scbf   = (__hip_bfloat16*)p; p += (size_t)BB * NS * 1024 * 2; // 16 MB
    __hip_bfloat16* W1aug  = (__hip_bfloat16*)p; p += (size_t)2048 * KX * 2;      // 4 MB
    __hip_bfloat16* W2aug  = (__hip_bfloat16*)p; p += (size_t)2048 * KX * 2;      // 4 MB
    __hip_bfloat16* Wphib  = (__hip_bfloat16*)p; p += (size_t)ATT * SD * 2;
    __hip_bfloat16* Wpsib  = (__hip_bfloat16*)p; p += (size_t)ATT * SD * 2;
    __hip_bfloat16* Wcdb   = (__hip_bfloat16*)p; p += (size_t)NC * 1024 * 2;
    // per-step X buffers: fresh addresses each step => L2-cacheable reads
    __hip_bfloat16* X1base = (__hip_bfloat16*)p; p += (size_t)(NS + 1) * BB * KX * 2;  // 16.5 MB
    __hip_bfloat16* X2base = (__hip_bfloat16*)p; p += (size_t)(NS + 1) * BB * KX * 2;  // 16.5 MB
    float* b1v = (float*)p; p += 512 * 4 * 4;
    float* b2v = (float*)p; p += 512 * 4 * 4;
    float* woh = (float*)p; p += (size_t)64 * 512 * 4 * 4;   // 512 KB
    float* c1  = (float*)p; p += (size_t)SD * BB * 4;
    float* c2  = (float*)p; p += (size_t)SD * BB * 4;
    unsigned* bar = (unsigned*)p; p += 16384 * 4;            // arrival + release flags

    // ---- one-time prep ----
    f2b_kernel<<<16384, 256, 0, stream>>>(h, hbf, BB * TT * SD);
    f2b_kernel<<<64, 256, 0, stream>>>(Wphi, Wphib, ATT * SD);
    f2b_kernel<<<64, 256, 0, stream>>>(Wpsi, Wpsib, ATT * SD);
    f2b_kernel<<<64, 256, 0, stream>>>(Wcd, Wcdb, NC * 1024);
    prep_w1_kernel<<<(2048 * KX + 255) / 256, 256, 0, stream>>>(Wih0, Whh0, W1aug);
    prep_w2_kernel<<<(2048 * KX + 255) / 256, 256, 0, stream>>>(Wih1, Whh1, W2aug);
    prep_misc_kernel<<<(64 * 512 + 255) / 256, 256, 0, stream>>>(Wih0, bih0, bhh0, bih1, bhh1,
                                                                 b1v, b2v, woh);
    init_kernel<<<(64 * KX + 255) / 256, 256, 0, stream>>>(h, X1base, X2base, c1, c2, bar);
    psi_gemm_kernel<<<512, 256, 0, stream>>>(hbf, Wpsib, bpsi, psibf);
    transpose_h_kernel<<<4096, 256, 0, stream>>>(h, hbf);   // overwrite hbf with hT [b][d][t]
    __hip_bfloat16* hT = hbf;

    // ---- persistent decode ----
    const __hip_bfloat16 *a0 = W1aug, *a1 = W2aug, *a2 = Wphib;
    const float* a3 = bphi;
    const __hip_bfloat16 *a4 = psibf, *a5 = hT;
    __hip_bfloat16 *a6 = X1base, *a7 = X2base, *a8 = scbf;
    const int* a9 = x;
    const float *a10 = b1v, *a11 = b2v, *a12 = woh;
    unsigned* a13 = bar;
    void* args[14] = {&a0, &a1, &a2, &a3, &a4, &a5, &a6, &a7,
                      &a8, &a9, &a10, &a11, &a12, &a13};
    hipError_t ce = hipLaunchCooperativeKernel((const void*)decode_kernel,
                                               dim3(256), dim3(512), args, 0, stream);
    if (ce != hipSuccess) {
        (void)hipGetLastError();
        for (int t = 0; t < NS; ++t) {
            __hip_bfloat16* X1c = X1base + (size_t)t * BB * KX;
            __hip_bfloat16* X1n = X1c + (size_t)BB * KX;
            __hip_bfloat16* X2c = X2base + (size_t)t * BB * KX;
            __hip_bfloat16* X2n = X2c + (size_t)BB * KX;
            fb_lstm0_kernel<<<128, 256, 0, stream>>>(W1aug, X1c, X1n, X2c, c1, b1v, woh, x, t);
            fb_lstm1_kernel<<<128, 256, 0, stream>>>(W2aug, X2c, X2n, scbf, c2, b2v, t);
            fb_attn_kernel<<<256, 256, 0, stream>>>(X2n, Wphib, bphi, psibf, hT, X1n, scbf, t);
        }
    }
    // output projection
    out_gemm_kernel<<<128, 256, 0, stream>>>(scbf, Wcdb, bcd, out);
}

// Round 6
// 2639.434 us; speedup vs baseline: 10.1617x; 1.0205x over previous
//
#include <hip/hip_runtime.h>
#include <hip/hip_bf16.h>
#include <math.h>

#define BB 64      // batch
#define TT 512     // encoder time
#define NS 128     // decode steps
#define SD 512     // lstm hidden
#define ATT 128
#define NC 64      // num classes
#define KX 1024    // X row: 512 ctx/h1 + 512 rec

typedef __attribute__((ext_vector_type(8))) short bf8;   // 8 bf16 (4 VGPRs)
typedef __attribute__((ext_vector_type(4))) float f4;

__device__ __forceinline__ float sigm(float x) { return 1.0f / (1.0f + expf(-x)); }
__device__ __forceinline__ float b2f(short s) {
    union { unsigned u; float f; } c; c.u = ((unsigned)(unsigned short)s) << 16; return c.f;
}
#define MFMA16(a, b, c) __builtin_amdgcn_mfma_f32_16x16x32_bf16((a), (b), (c), 0, 0, 0)

// ---- coherent (L3-point) helpers: sc0 sc1 stores write through to L3; sc loads
// bypass L1/L2. X data uses per-step fresh buffers so X READS are normal cached. ----
__device__ __forceinline__ void st_sc(__hip_bfloat16* p, float val) {
    __hip_bfloat16 hb(val);
    unsigned short bits; __builtin_memcpy(&bits, &hb, 2);
    unsigned v = bits;
    asm volatile("global_store_short %0, %1, off sc0 sc1" :: "v"(p), "v"(v) : "memory");
}
__device__ __forceinline__ void st_u32_sc(unsigned* p, unsigned v) {
    asm volatile("global_store_dword %0, %1, off sc0 sc1" :: "v"(p), "v"(v) : "memory");
}
__device__ __forceinline__ unsigned ld_u32_sc(const unsigned* p) {
    unsigned v;
    asm volatile("global_load_dword %0, %1, off sc0 sc1\ns_waitcnt vmcnt(0)"
                 : "=v"(v) : "v"(p) : "memory");
    return v;
}

// ---- single-hop dataflow sync ----
// Producer block: per-thread vmcnt drain (data stores ack'd into L3), block sync,
// thread 0 posts the block's monotonic step ticket on its OWN 128B line.
__device__ __forceinline__ void post_flag(unsigned* flag, unsigned tk)
{
    asm volatile("s_waitcnt vmcnt(0)" ::: "memory");
    __syncthreads();
    if (threadIdx.x == 0) st_u32_sc(flag, tk);
}
// Consumer block: threads 0..n-1 each poll ONE producer line until >= tk.
// One L3 visibility round trip; no aggregation, no release hop.
__device__ __forceinline__ void wait_flags(const unsigned* f, int n, unsigned tk)
{
    if ((int)threadIdx.x < n) {
        while (ld_u32_sc(f + threadIdx.x * 32) < tk)
            __builtin_amdgcn_s_sleep(1);
    }
    __syncthreads();
}

// 16-chunk MFMA GEMM over one X row; NORMAL cached loads (per-step-fresh
// addresses guarantee coherence); W fragments from registers.
template<int BASE>
__device__ __forceinline__ f4 gemm16r(const __hip_bfloat16* Xrow, int quad,
                                      const bf8 (&wreg)[32], f4 acc)
{
    const bf8* Bq = (const bf8*)Xrow + quad;
    bf8 r[16];
#pragma unroll
    for (int i = 0; i < 16; ++i) r[i] = Bq[(BASE + i) * 4];
#pragma unroll
    for (int i = 0; i < 16; ++i) acc = MFMA16(wreg[BASE + i], r[i], acc);
    return acc;
}

// ---------------- fp32 -> bf16 convert (vec4) ----------------
__global__ void f2b_kernel(const float* __restrict__ src, __hip_bfloat16* __restrict__ dst, int n)
{
    int i = (blockIdx.x * blockDim.x + threadIdx.x) * 4;
    if (i < n) {
        float4 v = *(const float4*)(src + i);
        dst[i]     = __hip_bfloat16(v.x);
        dst[i + 1] = __hip_bfloat16(v.y);
        dst[i + 2] = __hip_bfloat16(v.z);
        dst[i + 3] = __hip_bfloat16(v.w);
    }
}

// ---------------- transpose h: [b][t][d] f32 -> hT [b][d][t] bf16 ----------------
__global__ __launch_bounds__(256) void transpose_h_kernel(const float* __restrict__ h,
                                                          __hip_bfloat16* __restrict__ hT)
{
    int bidx = blockIdx.x;
    int b = bidx >> 6, tt0 = ((bidx >> 3) & 7) * 64, dd0 = (bidx & 7) * 64;
    __shared__ __hip_bfloat16 tile[64][65];
    int dd = threadIdx.x & 63, r4 = threadIdx.x >> 6;
#pragma unroll
    for (int i = 0; i < 64; i += 4) {
        int tl = i + r4;
        tile[tl][dd] = __hip_bfloat16(h[((size_t)b * TT + tt0 + tl) * SD + dd0 + dd]);
    }
    __syncthreads();
#pragma unroll
    for (int i = 0; i < 64; i += 4) {
        int dl = i + r4;
        hT[((size_t)b * SD + dd0 + dl) * TT + tt0 + dd] = tile[dd][dl];
    }
}

// ---------------- LSTM0 weights [2048][1024]: ctx cols | rec cols ----------------
__global__ void prep_w1_kernel(const float* __restrict__ Wih, const float* __restrict__ Whh,
                               __hip_bfloat16* __restrict__ W)
{
    int idx = blockIdx.x * blockDim.x + threadIdx.x;   // 2048*1024
    if (idx >= 2048 * KX) return;
    int np = idx >> 10, kk = idx & 1023;
    int q = np & 3, d = np >> 2, j = q * 512 + d;
    float v = (kk < 512) ? Wih[j * 576 + 64 + kk] : Whh[j * 512 + kk - 512];
    W[idx] = __hip_bfloat16(v);
}

// ---------------- LSTM1 weights [2048][1024] ----------------
__global__ void prep_w2_kernel(const float* __restrict__ Wih, const float* __restrict__ Whh,
                               __hip_bfloat16* __restrict__ W)
{
    int idx = blockIdx.x * blockDim.x + threadIdx.x;
    if (idx >= 2048 * KX) return;
    int np = idx >> 10, kk = idx & 1023;
    int q = np & 3, d = np >> 2, j = q * 512 + d;
    float v = (kk < 512) ? Wih[j * 512 + kk] : Whh[j * 512 + kk - 512];
    W[idx] = __hip_bfloat16(v);
}

// ---------------- biases (gate-interleaved f4) + per-token Wih0 column gather ----------------
__global__ void prep_misc_kernel(const float* __restrict__ Wih0,
                                 const float* __restrict__ bih0, const float* __restrict__ bhh0,
                                 const float* __restrict__ bih1, const float* __restrict__ bhh1,
                                 float* __restrict__ b1v, float* __restrict__ b2v,
                                 float* __restrict__ woh)   // [64 tok][512 d] f4
{
    int idx = blockIdx.x * blockDim.x + threadIdx.x;   // 64*512
    if (idx >= 64 * 512) return;
    int tok = idx >> 9, d = idx & 511;
    float4 w;
    w.x = Wih0[(0 * 512 + d) * 576 + tok];
    w.y = Wih0[(1 * 512 + d) * 576 + tok];
    w.z = Wih0[(2 * 512 + d) * 576 + tok];
    w.w = Wih0[(3 * 512 + d) * 576 + tok];
    ((float4*)woh)[idx] = w;
    if (tok == 0) {
        float4 b1, b2;
        b1.x = bih0[d] + bhh0[d];             b1.y = bih0[512 + d] + bhh0[512 + d];
        b1.z = bih0[1024 + d] + bhh0[1024 + d]; b1.w = bih0[1536 + d] + bhh0[1536 + d];
        b2.x = bih1[d] + bhh1[d];             b2.y = bih1[512 + d] + bhh1[512 + d];
        b2.z = bih1[1024 + d] + bhh1[1024 + d]; b2.w = bih1[1536 + d] + bhh1[1536 + d];
        ((float4*)b1v)[d] = b1;
        ((float4*)b2v)[d] = b2;
    }
}

// ---------------- init: step-0 X buffers, c states, flags ----------------
__global__ void init_kernel(const float* __restrict__ h,
                            __hip_bfloat16* __restrict__ X1_0,
                            __hip_bfloat16* __restrict__ X2_0,
                            float* __restrict__ c1, float* __restrict__ c2,
                            unsigned* __restrict__ bar)
{
    int idx = blockIdx.x * blockDim.x + threadIdx.x;   // 64*1024
    if (idx >= 64 * KX) return;
    int b = idx >> 10, col = idx & 1023;
    __hip_bfloat16 z(0.0f);
    X1_0[idx] = (col < 512) ? __hip_bfloat16(h[(size_t)b * TT * SD + col]) : z;  // ctx0 | h1(-1)=0
    X2_0[idx] = z;                                                               // h2(-1)=0
    if (idx < 512 * 64) { c1[idx] = 0.f; c2[idx] = 0.f; }
    if (idx < 16384) bar[idx] = 0u;
}

// ---------------- persistent decode kernel ----------------
// 256 blocks x 512 threads, 1 block/CU. Blocks 0..127 ("A"): LSTM0 rows;
// 128..255 ("B"): LSTM1 rows. W tiles in registers, cell state in registers,
// hT slice (ab,dch) 128 KB LDS-resident (swizzled). Per-step X buffers =>
// cached X reads. Synchronization is DATAFLOW FLAGS (single-hop), not a global
// barrier: fC(t-1) -> A slot1 -> fA -> B finish -> fB -> attention -> fC.
// B's recurrent prefetch needs no wait; A's prefetch overlaps B's finish.
__global__ __launch_bounds__(512, 1) void decode_kernel(
    const __hip_bfloat16* __restrict__ W1, const __hip_bfloat16* __restrict__ W2,
    const __hip_bfloat16* __restrict__ Wphib, const float* __restrict__ bphi,
    const __hip_bfloat16* __restrict__ psib, const __hip_bfloat16* __restrict__ hT,
    __hip_bfloat16* X1base, __hip_bfloat16* X2base,
    __hip_bfloat16* scb, const int* __restrict__ xtok,
    const float* __restrict__ b1v, const float* __restrict__ b2v,
    const float* __restrict__ woh, unsigned* __restrict__ bar)
{
    __shared__ bf8 hTl[128 * 64];                        // 128 KB swizzled hT slice
    __shared__ float h2s[512], phis[128], es[512], red[512], wred[16];

    const int bid = blockIdx.x, tid = threadIdx.x;
    const int lane = tid & 63, w = tid >> 6;
    const int mr = lane & 15, quad = lane >> 4;
    const bool isA = bid < 128;
    // attention role: co-locate the 4 dch blocks of one ab on one XCD (bid%8)
    const int ab = (bid & 7) * 8 + ((bid >> 3) & 7), dch = bid >> 6;

    unsigned* fA = bar;                  // 128 x 32 words (128B lines)
    unsigned* fB = bar + 128 * 32;       // 128 x 32
    unsigned* fC = bar + 256 * 32;       // 256 x 32

    // ---- prologue: W rows -> registers (LSTM waves only) ----
    bf8 wreg[32];
    if (tid < 256) {
        const __hip_bfloat16* Wg = isA ? W1 : W2;
        const int m0 = (bid & 127) * 16;
        const bf8* src = (const bf8*)(Wg + (size_t)(m0 + mr) * KX) + quad;
#pragma unroll
        for (int ko = 0; ko < 32; ++ko) wreg[ko] = src[ko * 4];
    }
    // ---- prologue: hT slice -> LDS (swizzled) ----
    {
        const bf8* src = (const bf8*)hT + ((size_t)ab * SD + dch * 128) * 64;
        for (int it = 0; it < 16; ++it) {
            int gidx = it * 512 + tid;                   // 0..8191
            int d = gidx >> 6, g = gidx & 63;
            hTl[d * 64 + (g ^ (d & 7))] = src[gidx];
        }
    }
    __syncthreads();

    const int dl = (bid & 127) * 4 + quad;   // this thread's hidden index d
    const int bb = w * 16 + mr;              // this thread's batch (tid<256)
    const f4 biasv = isA ? ((const f4*)b1v)[dl & 511] : ((const f4*)b2v)[dl & 511];
    const int* xrow = xtok + (bb & 63) * NS;

    float cr = 0.f;                          // persistent cell state
    f4 accP = {0, 0, 0, 0};                  // A: recurrent partial; h1(-1)=0 => 0

    for (int t = 0; t < NS; ++t) {
        __hip_bfloat16* X1c = X1base + (size_t)t * BB * KX;
        __hip_bfloat16* X1n = X1c + (size_t)BB * KX;
        __hip_bfloat16* X2c = X2base + (size_t)t * BB * KX;
        __hip_bfloat16* X2n = X2c + (size_t)BB * KX;

        if (isA) {
            // issue token-column gather early (independent of ctx)
            f4 wo = {0, 0, 0, 0};
            if (tid < 256) wo = ((const f4*)woh)[(size_t)xrow[t] * 512 + dl];
            // wait ctx(t-1) from all 256 attention blocks (t=0: trivially 0)
            wait_flags(fC, 256, (unsigned)t);
            if (tid < 256) {
                f4 acc = gemm16r<0>(X1c + (size_t)bb * KX, quad, wreg, accP);
                acc.x += biasv.x + wo.x; acc.y += biasv.y + wo.y;
                acc.z += biasv.z + wo.z; acc.w += biasv.w + wo.w;
                float cn = sigm(acc.y) * cr + sigm(acc.x) * tanhf(acc.z);
                float hn = sigm(acc.w) * tanhf(cn);
                cr = cn;
                st_sc(X2c + (size_t)bb * KX + dl, hn);          // h1 -> LSTM1 input
                st_sc(X1n + (size_t)bb * KX + 512 + dl, hn);    // h1 -> next recurrent
            }
            post_flag(fA + bid * 32, (unsigned)(t + 1));
            // recurrent prefetch for t+1 (needs ALL A's h1)
            wait_flags(fA, 128, (unsigned)(t + 1));
            if (tid < 256) {
                f4 z = {0, 0, 0, 0};
                accP = gemm16r<16>(X1n + (size_t)bb * KX, quad, wreg, z);
            }
        } else {
            // recurrent prefetch over h2(t-1): already ordered by own attn(t-1)'s
            // wait on fB(t) -- no wait needed
            f4 pre = {0, 0, 0, 0};
            if (tid < 256) {
                f4 z = {0, 0, 0, 0};
                pre = gemm16r<16>(X2c + (size_t)bb * KX, quad, wreg, z);
            }
            // finish needs h1(t) from all A blocks
            wait_flags(fA, 128, (unsigned)(t + 1));
            float hnv = 0.f;
            if (tid < 256) {
                f4 acc = gemm16r<0>(X2c + (size_t)bb * KX, quad, wreg, pre);
                acc.x += biasv.x; acc.y += biasv.y; acc.z += biasv.z; acc.w += biasv.w;
                float cn = sigm(acc.y) * cr + sigm(acc.x) * tanhf(acc.z);
                hnv = sigm(acc.w) * tanhf(cn);
                cr = cn;
                st_sc(X2n + (size_t)bb * KX + 512 + dl, hnv);   // h2 recurrent (coherent)
            }
            post_flag(fB + (bid & 127) * 32, (unsigned)(t + 1));
            if (tid < 256)                                       // off critical path
                scb[((size_t)bb * NS + t) * 1024 + dl] = __hip_bfloat16(hnv);
        }

        // ---- attention (all 256 blocks as (ab, dch)); needs all h2(t) ----
        wait_flags(fB, 128, (unsigned)(t + 1));
        {
            if (tid < 64) {                 // h2(t): fresh-address normal load
                bf8 v = *((const bf8*)(X2n + (size_t)ab * KX + 512) + tid);
#pragma unroll
                for (int j = 0; j < 8; ++j) h2s[tid * 8 + j] = b2f(v[j]);
            }
            __syncthreads();

            // phi[a] = h2 . Wphi[a] + bphi[a];  4 lanes/row, 1 pass (512 threads)
            {
                int al = tid & 3, a = tid >> 2;
                const bf8* wr = (const bf8*)(Wphib + (size_t)a * 512) + al;
                float acc = 0.f;
#pragma unroll
                for (int i = 0; i < 16; ++i) {
                    bf8 wv = wr[i * 4];
                    const float* hp2 = h2s + i * 32 + al * 8;
#pragma unroll
                    for (int j = 0; j < 8; ++j) acc += hp2[j] * b2f(wv[j]);
                }
                acc += __shfl_xor(acc, 1);
                acc += __shfl_xor(acc, 2);
                if (al == 0) phis[a] = acc + bphi[a];
            }
            __syncthreads();

            // e[t'] = phi . psi[b][t'];  4 passes (512 threads)
            {
                int al = tid & 3;
#pragma unroll
                for (int pass = 0; pass < 4; ++pass) {
                    int tt = pass * 128 + (tid >> 2);
                    const bf8* pr = (const bf8*)(psib + ((size_t)ab * TT + tt) * 128) + al;
                    float acc = 0.f;
#pragma unroll
                    for (int i = 0; i < 4; ++i) {
                        bf8 pv = pr[i * 4];
                        const float* ph = phis + i * 32 + al * 8;
#pragma unroll
                        for (int j = 0; j < 8; ++j) acc += ph[j] * b2f(pv[j]);
                    }
                    acc += __shfl_xor(acc, 1);
                    acc += __shfl_xor(acc, 2);
                    if (al == 0) es[tt] = acc;
                }
            }
            __syncthreads();

            // softmax via wave shfl reduction
            float m = es[tid];
#pragma unroll
            for (int s = 1; s < 64; s <<= 1) m = fmaxf(m, __shfl_xor(m, s));
            if (lane == 0) wred[w] = m;
            __syncthreads();
            float mx = wred[0];
#pragma unroll
            for (int i = 1; i < 8; ++i) mx = fmaxf(mx, wred[i]);
            float e0 = expf(es[tid] - mx);
            es[tid] = e0;
            float s0 = e0;
#pragma unroll
            for (int s = 1; s < 64; s <<= 1) s0 += __shfl_xor(s0, s);
            if (lane == 0) wred[8 + w] = s0;
            __syncthreads();                // also publishes es[] = exp values
            float sum = wred[8];
#pragma unroll
            for (int i = 1; i < 8; ++i) sum += wred[8 + i];
            float inv = 1.0f / sum;

            // ctx[d] from LDS-resident hT slice; 4 partials per d (512 threads)
            {
                int d = tid & 127, th = tid >> 7;
                const float* ep = es + th * 128;
                const int rb = d * 64, g0 = th * 16, sw = d & 7;
                float a0 = 0.f, a1 = 0.f, a2 = 0.f, a3 = 0.f;
#pragma unroll
                for (int i = 0; i < 16; i += 4) {
                    bf8 v0 = hTl[rb + ((g0 + i)     ^ sw)];
                    bf8 v1 = hTl[rb + ((g0 + i + 1) ^ sw)];
                    bf8 v2 = hTl[rb + ((g0 + i + 2) ^ sw)];
                    bf8 v3 = hTl[rb + ((g0 + i + 3) ^ sw)];
#pragma unroll
                    for (int j = 0; j < 8; ++j) {
                        a0 += ep[i * 8 + j]      * b2f(v0[j]);
                        a1 += ep[i * 8 + 8 + j]  * b2f(v1[j]);
                        a2 += ep[i * 8 + 16 + j] * b2f(v2[j]);
                        a3 += ep[i * 8 + 24 + j] * b2f(v3[j]);
                    }
                }
                red[tid] = (a0 + a1) + (a2 + a3);
                __syncthreads();
                float v = 0.f;
                if (th == 0) {
                    v = (red[d] + red[d + 128] + red[d + 256] + red[d + 384]) * inv;
                    st_sc(X1n + (size_t)ab * KX + dch * 128 + d, v);   // ctx (coherent)
                }
                post_flag(fC + bid * 32, (unsigned)(t + 1));
                if (th == 0)                                            // off critical path
                    scb[((size_t)ab * NS + t) * 1024 + 512 + dch * 128 + d] = __hip_bfloat16(v);
            }
        }
    }
}

// ---------------- fallback per-step kernels (plain mem ops; kernel-boundary
// coherence). Only used if cooperative launch is rejected. ----------------
__global__ __launch_bounds__(256) void fb_lstm0_kernel(
    const __hip_bfloat16* __restrict__ W1, const __hip_bfloat16* __restrict__ X1c,
    __hip_bfloat16* X1n, __hip_bfloat16* X2c, float* __restrict__ c1,
    const float* __restrict__ b1v, const float* __restrict__ woh,
    const int* __restrict__ xtok, int t)
{
    __shared__ __hip_bfloat16 Wlds[32 * 512];
    const int bid = blockIdx.x, tid = threadIdx.x;
    const int lane = tid & 63, w = tid >> 6;
    const int mr = lane & 15, quad = lane >> 4;
    {
        const bf8* src = (const bf8*)(W1 + (size_t)(bid * 16 + mr) * KX) + quad;
        bf8* dstl = (bf8*)Wlds;
        for (int ko = w; ko < 32; ko += 4) dstl[ko * 64 + lane] = src[ko * 4];
    }
    __syncthreads();
    const bf8* Wl = (const bf8*)Wlds + lane;
    const int dl = bid * 4 + quad, bb = w * 16 + mr;
    const bf8* Bq = (const bf8*)(X1c + (size_t)bb * KX) + quad;
    f4 acc = {0, 0, 0, 0};
#pragma unroll
    for (int ko = 0; ko < 32; ++ko) acc = MFMA16(Wl[ko * 64], Bq[ko * 4], acc);
    f4 bv = ((const f4*)b1v)[dl];
    f4 wo = ((const f4*)woh)[(size_t)xtok[bb * NS + t] * 512 + dl];
    acc.x += bv.x + wo.x; acc.y += bv.y + wo.y; acc.z += bv.z + wo.z; acc.w += bv.w + wo.w;
    int ci = dl * 64 + bb;
    float cn = sigm(acc.y) * c1[ci] + sigm(acc.x) * tanhf(acc.z);
    float hn = sigm(acc.w) * tanhf(cn);
    c1[ci] = cn;
    X2c[(size_t)bb * KX + dl] = __hip_bfloat16(hn);
    X1n[(size_t)bb * KX + 512 + dl] = __hip_bfloat16(hn);
}

__global__ __launch_bounds__(256) void fb_lstm1_kernel(
    const __hip_bfloat16* __restrict__ W2, const __hip_bfloat16* __restrict__ X2c,
    __hip_bfloat16* X2n, __hip_bfloat16* scb, float* __restrict__ c2,
    const float* __restrict__ b2v, int t)
{
    __shared__ __hip_bfloat16 Wlds[32 * 512];
    const int bid = blockIdx.x, tid = threadIdx.x;
    const int lane = tid & 63, w = tid >> 6;
    const int mr = lane & 15, quad = lane >> 4;
    {
        const bf8* src = (const bf8*)(W2 + (size_t)(bid * 16 + mr) * KX) + quad;
        bf8* dstl = (bf8*)Wlds;
        for (int ko = w; ko < 32; ko += 4) dstl[ko * 64 + lane] = src[ko * 4];
    }
    __syncthreads();
    const bf8* Wl = (const bf8*)Wlds + lane;
    const int dl = bid * 4 + quad, bb = w * 16 + mr;
    const bf8* Bq = (const bf8*)(X2c + (size_t)bb * KX) + quad;
    f4 acc = {0, 0, 0, 0};
#pragma unroll
    for (int ko = 0; ko < 32; ++ko) acc = MFMA16(Wl[ko * 64], Bq[ko * 4], acc);
    f4 bv = ((const f4*)b2v)[dl];
    acc.x += bv.x; acc.y += bv.y; acc.z += bv.z; acc.w += bv.w;
    int ci = dl * 64 + bb;
    float cn = sigm(acc.y) * c2[ci] + sigm(acc.x) * tanhf(acc.z);
    float hn = sigm(acc.w) * tanhf(cn);
    c2[ci] = cn;
    X2n[(size_t)bb * KX + 512 + dl] = __hip_bfloat16(hn);
    scb[((size_t)bb * NS + t) * 1024 + dl] = __hip_bfloat16(hn);
}

__global__ __launch_bounds__(256) void fb_attn_kernel(
    const __hip_bfloat16* __restrict__ X2n, const __hip_bfloat16* __restrict__ Wphib,
    const float* __restrict__ bphi, const __hip_bfloat16* __restrict__ psib,
    const __hip_bfloat16* __restrict__ hT,
    __hip_bfloat16* X1n, __hip_bfloat16* scb, int t)
{
    __shared__ float h2s[512], phis[128], es[512], red[256];
    int b = blockIdx.x >> 2, dch = blockIdx.x & 3;
    int tid = threadIdx.x;
    if (tid < 64) {
        bf8 v = *((const bf8*)(X2n + (size_t)b * KX + 512) + tid);
#pragma unroll
        for (int j = 0; j < 8; ++j) h2s[tid * 8 + j] = b2f(v[j]);
    }
    __syncthreads();
    {
        int al = tid & 3;
#pragma unroll
        for (int pass = 0; pass < 2; ++pass) {
            int a = pass * 64 + (tid >> 2);
            const bf8* wr = (const bf8*)(Wphib + (size_t)a * 512) + al;
            float acc = 0.f;
#pragma unroll
            for (int i = 0; i < 16; ++i) {
                bf8 wv = wr[i * 4];
                const float* hp2 = h2s + i * 32 + al * 8;
#pragma unroll
                for (int j = 0; j < 8; ++j) acc += hp2[j] * b2f(wv[j]);
            }
            acc += __shfl_xor(acc, 1);
            acc += __shfl_xor(acc, 2);
            if (al == 0) phis[a] = acc + bphi[a];
        }
    }
    __syncthreads();
    {
        int al = tid & 3;
#pragma unroll
        for (int pass = 0; pass < 8; ++pass) {
            int tt = pass * 64 + (tid >> 2);
            const bf8* pr = (const bf8*)(psib + ((size_t)b * TT + tt) * 128) + al;
            float acc = 0.f;
#pragma unroll
            for (int i = 0; i < 4; ++i) {
                bf8 pv = pr[i * 4];
                const float* ph = phis + i * 32 + al * 8;
#pragma unroll
                for (int j = 0; j < 8; ++j) acc += ph[j] * b2f(pv[j]);
            }
            acc += __shfl_xor(acc, 1);
            acc += __shfl_xor(acc, 2);
            if (al == 0) es[tt] = acc;
        }
    }
    __syncthreads();
    red[tid] = fmaxf(es[tid], es[tid + 256]);
    __syncthreads();
    for (int st = 128; st > 0; st >>= 1) {
        if (tid < st) red[tid] = fmaxf(red[tid], red[tid + st]);
        __syncthreads();
    }
    float mx = red[0];
    __syncthreads();
    float e0 = expf(es[tid] - mx), e1 = expf(es[tid + 256] - mx);
    es[tid] = e0; es[tid + 256] = e1;
    red[tid] = e0 + e1;
    __syncthreads();
    for (int st = 128; st > 0; st >>= 1) {
        if (tid < st) red[tid] += red[tid + st];
        __syncthreads();
    }
    float inv = 1.0f / red[0];
    __syncthreads();
    {
        int d = dch * 128 + (tid & 127), th = tid >> 7;
        const bf8* hp = (const bf8*)hT + ((size_t)b * SD + d) * 64 + th * 32;
        const float* ep = es + th * 256;
        float a0 = 0.f, a1 = 0.f, a2 = 0.f, a3 = 0.f;
#pragma unroll
        for (int i = 0; i < 32; i += 4) {
            bf8 v0 = hp[i], v1 = hp[i + 1], v2 = hp[i + 2], v3 = hp[i + 3];
#pragma unroll
            for (int j = 0; j < 8; ++j) {
                a0 += ep[i * 8 + j]      * b2f(v0[j]);
                a1 += ep[i * 8 + 8 + j]  * b2f(v1[j]);
                a2 += ep[i * 8 + 16 + j] * b2f(v2[j]);
                a3 += ep[i * 8 + 24 + j] * b2f(v3[j]);
            }
        }
        float acc = (a0 + a1) + (a2 + a3);
        red[tid] = acc;
        __syncthreads();
        if (th == 0) {
            float v = (acc + red[tid + 128]) * inv;
            X1n[(size_t)b * KX + d] = __hip_bfloat16(v);
            scb[((size_t)b * NS + t) * 1024 + 512 + d] = __hip_bfloat16(v);
        }
    }
}

// ---------------- psi GEMM: psibf[b*512+t][128] = hbf @ Wpsi^T + bpsi ----------------
__global__ __launch_bounds__(256) void psi_gemm_kernel(
    const __hip_bfloat16* __restrict__ A,   // hbf [32768][512]
    const __hip_bfloat16* __restrict__ Bw,  // Wpsibf [128][512]
    const float* __restrict__ bias,
    __hip_bfloat16* __restrict__ C)         // [32768][128]
{
    int lane = threadIdx.x & 63, wave = threadIdx.x >> 6;
    int m0 = (blockIdx.x * 4 + wave) * 16;
    int mr = lane & 15, quad = lane >> 4;
    const bf8* Ar = (const bf8*)(A + (size_t)(m0 + mr) * 512 + quad * 8);
    f4 acc[8] = {};
    for (int k0 = 0; k0 < 512; k0 += 32) {
        int ko = k0 >> 3;
        bf8 a = Ar[ko];
#pragma unroll
        for (int nf = 0; nf < 8; ++nf) {
            const bf8* Br = (const bf8*)(Bw + (size_t)(nf * 16 + mr) * 512 + quad * 8);
            acc[nf] = MFMA16(a, Br[ko], acc[nf]);
        }
    }
#pragma unroll
    for (int nf = 0; nf < 8; ++nf) {
        int n = nf * 16 + mr;
        float bs = bias[n];
#pragma unroll
        for (int r = 0; r < 4; ++r) {
            int m = m0 + quad * 4 + r;
            C[(size_t)m * 128 + n] = __hip_bfloat16(acc[nf][r] + bs);
        }
    }
}

// ---------------- final projection: out[b*128+t][64] = scbf @ Wcd^T + bcd ----------------
__global__ __launch_bounds__(256) void out_gemm_kernel(
    const __hip_bfloat16* __restrict__ A,   // scbf [8192][1024]
    const __hip_bfloat16* __restrict__ Bw,  // Wcdbf [64][1024]
    const float* __restrict__ bias,
    float* __restrict__ C)                  // [8192][64]
{
    int lane = threadIdx.x & 63, wave = threadIdx.x >> 6;
    int m0 = (blockIdx.x * 4 + wave) * 16;
    int mr = lane & 15, quad = lane >> 4;
    const bf8* Ar = (const bf8*)(A + (size_t)(m0 + mr) * 1024 + quad * 8);
    f4 acc[4] = {};
    for (int k0 = 0; k0 < 1024; k0 += 32) {
        int ko = k0 >> 3;
        bf8 a = Ar[ko];
#pragma unroll
        for (int nf = 0; nf < 4; ++nf) {
            const bf8* Br = (const bf8*)(Bw + (size_t)(nf * 16 + mr) * 1024 + quad * 8);
            acc[nf] = MFMA16(a, Br[ko], acc[nf]);
        }
    }
#pragma unroll
    for (int nf = 0; nf < 4; ++nf) {
        int n = nf * 16 + mr;
        float bs = bias[n];
#pragma unroll
        for (int r = 0; r < 4; ++r) {
            int m = m0 + quad * 4 + r;
            C[(size_t)m * 64 + n] = acc[nf][r] + bs;
        }
    }
}

extern "C" void kernel_launch(void* const* d_in, const int* in_sizes, int n_in,
                              void* d_out, int out_size, void* d_ws, size_t ws_size,
                              hipStream_t stream)
{
    const int*   x    = (const int*)  d_in[0];
    const float* h    = (const float*)d_in[1];
    const float* Wih0 = (const float*)d_in[2];
    const float* Whh0 = (const float*)d_in[3];
    const float* bih0 = (const float*)d_in[4];
    const float* bhh0 = (const float*)d_in[5];
    const float* Wih1 = (const float*)d_in[6];
    const float* Whh1 = (const float*)d_in[7];
    const float* bih1 = (const float*)d_in[8];
    const float* bhh1 = (const float*)d_in[9];
    const float* Wphi = (const float*)d_in[10];
    const float* bphi = (const float*)d_in[11];
    const float* Wpsi = (const float*)d_in[12];
    const float* bpsi = (const float*)d_in[13];
    const float* Wcd  = (const float*)d_in[14];
    const float* bcd  = (const float*)d_in[15];
    float* out = (float*)d_out;

    char* p = (char*)d_ws;
    __hip_bfloat16* hbf    = (__hip_bfloat16*)p; p += (size_t)BB * TT * SD * 2;   // 32 MB (hbf, then hT)
    __hip_bfloat16* psibf  = (__hip_bfloat16*)p; p += (size_t)BB * TT * ATT * 2;  // 8 MB
    __hip_bfloat16* scbf   = (__hip_bfloat16*)p; p += (size_t)BB * NS * 1024 * 2; // 16 MB
    __hip_bfloat16* W1aug  = (__hip_bfloat16*)p; p += (size_t)2048 * KX * 2;      // 4 MB
    __hip_bfloat16* W2aug  = (__hip_bfloat16*)p; p += (size_t)2048 * KX * 2;      // 4 MB
    __hip_bfloat16* Wphib  = (__hip_bfloat16*)p; p += (size_t)ATT * SD * 2;
    __hip_bfloat16* Wpsib  = (__hip_bfloat16*)p; p += (size_t)ATT * SD * 2;
    __hip_bfloat16* Wcdb   = (__hip_bfloat16*)p; p += (size_t)NC * 1024 * 2;
    // per-step X buffers: fresh addresses each step => L2-cacheable reads
    __hip_bfloat16* X1base = (__hip_bfloat16*)p; p += (size_t)(NS + 1) * BB * KX * 2;  // 16.5 MB
    __hip_bfloat16* X2base = (__hip_bfloat16*)p; p += (size_t)(NS + 1) * BB * KX * 2;  // 16.5 MB
    float* b1v = (float*)p; p += 512 * 4 * 4;
    float* b2v = (float*)p; p += 512 * 4 * 4;
    float* woh = (float*)p; p += (size_t)64 * 512 * 4 * 4;   // 512 KB
    float* c1  = (float*)p; p += (size_t)SD * BB * 4;
    float* c2  = (float*)p; p += (size_t)SD * BB * 4;
    unsigned* bar = (unsigned*)p; p += 16384 * 4;            // fA/fB/fC flag lines

    // ---- one-time prep ----
    f2b_kernel<<<16384, 256, 0, stream>>>(h, hbf, BB * TT * SD);
    f2b_kernel<<<64, 256, 0, stream>>>(Wphi, Wphib, ATT * SD);
    f2b_kernel<<<64, 256, 0, stream>>>(Wpsi, Wpsib, ATT * SD);
    f2b_kernel<<<64, 256, 0, stream>>>(Wcd, Wcdb, NC * 1024);
    prep_w1_kernel<<<(2048 * KX + 255) / 256, 256, 0, stream>>>(Wih0, Whh0, W1aug);
    prep_w2_kernel<<<(2048 * KX + 255) / 256, 256, 0, stream>>>(Wih1, Whh1, W2aug);
    prep_misc_kernel<<<(64 * 512 + 255) / 256, 256, 0, stream>>>(Wih0, bih0, bhh0, bih1, bhh1,
                                                                 b1v, b2v, woh);
    init_kernel<<<(64 * KX + 255) / 256, 256, 0, stream>>>(h, X1base, X2base, c1, c2, bar);
    psi_gemm_kernel<<<512, 256, 0, stream>>>(hbf, Wpsib, bpsi, psibf);
    transpose_h_kernel<<<4096, 256, 0, stream>>>(h, hbf);   // overwrite hbf with hT [b][d][t]
    __hip_bfloat16* hT = hbf;

    // ---- persistent decode ----
    const __hip_bfloat16 *a0 = W1aug, *a1 = W2aug, *a2 = Wphib;
    const float* a3 = bphi;
    const __hip_bfloat16 *a4 = psibf, *a5 = hT;
    __hip_bfloat16 *a6 = X1base, *a7 = X2base, *a8 = scbf;
    const int* a9 = x;
    const float *a10 = b1v, *a11 = b2v, *a12 = woh;
    unsigned* a13 = bar;
    void* args[14] = {&a0, &a1, &a2, &a3, &a4, &a5, &a6, &a7,
                      &a8, &a9, &a10, &a11, &a12, &a13};
    hipError_t ce = hipLaunchCooperativeKernel((const void*)decode_kernel,
                                               dim3(256), dim3(512), args, 0, stream);
    if (ce != hipSuccess) {
        (void)hipGetLastError();
        for (int t = 0; t < NS; ++t) {
            __hip_bfloat16* X1c = X1base + (size_t)t * BB * KX;
            __hip_bfloat16* X1n = X1c + (size_t)BB * KX;
            __hip_bfloat16* X2c = X2base + (size_t)t * BB * KX;
            __hip_bfloat16* X2n = X2c + (size_t)BB * KX;
            fb_lstm0_kernel<<<128, 256, 0, stream>>>(W1aug, X1c, X1n, X2c, c1, b1v, woh, x, t);
            fb_lstm1_kernel<<<128, 256, 0, stream>>>(W2aug, X2c, X2n, scbf, c2, b2v, t);
            fb_attn_kernel<<<256, 256, 0, stream>>>(X2n, Wphib, bphi, psibf, hT, X1n, scbf, t);
        }
    }
    // output projection
    out_gemm_kernel<<<128, 256, 0, stream>>>(scbf, Wcdb, bcd, out);
}